// Round 3
// baseline (541.132 us; speedup 1.0000x reference)
//
#include <hip/hip_runtime.h>
#include <hip/hip_bf16.h>
#include <math.h>

#define D 256
#define H 8
#define C 32
#define DE 64
#define DF 1024

static inline size_t align_up(size_t x, size_t a) { return (x + a - 1) / a * a; }

typedef __attribute__((ext_vector_type(8))) short short8;
typedef __attribute__((ext_vector_type(4))) float f32x4;

__device__ inline unsigned short f2b(float x) {
    __hip_bfloat16 h = __float2bfloat16(x);
    return *reinterpret_cast<unsigned short*>(&h);
}
__device__ inline float b2f(unsigned short u) {
    return __uint_as_float(((unsigned int)u) << 16);
}

// ---------------- CSR build ----------------
__global__ void deg_kernel(const int* __restrict__ dst, int* __restrict__ deg, int E) {
    int e = blockIdx.x * 256 + threadIdx.x;
    if (e < E) atomicAdd(&deg[dst[e]], 1);
}

__global__ void partial_sum_kernel(const int* __restrict__ deg, int* __restrict__ part, int n) {
    int i = blockIdx.x * 256 + threadIdx.x;
    int v = (i < n) ? deg[i] : 0;
    for (int o = 1; o < 64; o <<= 1) v += __shfl_xor(v, o);
    __shared__ int w4[4];
    if ((threadIdx.x & 63) == 0) w4[threadIdx.x >> 6] = v;
    __syncthreads();
    if (threadIdx.x == 0) part[blockIdx.x] = w4[0] + w4[1] + w4[2] + w4[3];
}

__global__ void scan_part_kernel(int* __restrict__ part, int nb) {
    __shared__ int buf[256];
    int t = threadIdx.x;
    buf[t] = (t < nb) ? part[t] : 0;
    __syncthreads();
    for (int s = 1; s < 256; s <<= 1) {
        int v = (t >= s) ? buf[t - s] : 0;
        __syncthreads();
        buf[t] += v;
        __syncthreads();
    }
    int excl = (t == 0) ? 0 : buf[t - 1];
    if (t < nb) part[t] = excl;
}

__global__ void scan_final_kernel(const int* __restrict__ deg, const int* __restrict__ part,
                                  int* __restrict__ off, int n) {
    int b = blockIdx.x, t = threadIdx.x, i = b * 256 + t;
    __shared__ int buf[256];
    int v = (i < n) ? deg[i] : 0;
    buf[t] = v;
    __syncthreads();
    for (int s = 1; s < 256; s <<= 1) {
        int x = (t >= s) ? buf[t - s] : 0;
        __syncthreads();
        buf[t] += x;
        __syncthreads();
    }
    int excl = part[b] + buf[t] - v;
    if (i < n) off[i] = excl;
    if (i == n - 1) off[n] = excl + v;
}

__global__ void copy_int_kernel(const int* __restrict__ a, int* __restrict__ b, int n) {
    int i = blockIdx.x * 256 + threadIdx.x;
    if (i < n) b[i] = a[i];
}

// writes pos[e] (CSR slot of edge e) and src_csr[p] (source node of slot p)
__global__ void fill_kernel(const int* __restrict__ src, const int* __restrict__ dst,
                            int* __restrict__ cursor, int* __restrict__ pos,
                            int* __restrict__ src_csr, int E) {
    int e = blockIdx.x * 256 + threadIdx.x;
    if (e < E) {
        int p = atomicAdd(&cursor[dst[e]], 1);
        pos[e] = p;
        src_csr[p] = src[e];
    }
}

// ---------------- bf16 conversion / transpose ----------------
__global__ void convert_bf16x8_kernel(const float* __restrict__ in, unsigned short* __restrict__ out,
                                      size_t n_valid, size_t n_total) {
    size_t i = ((size_t)blockIdx.x * 256 + threadIdx.x) * 8;
    if (i >= n_total) return;
    ushort4 o0, o1;
    if (i < n_valid) {  // n_valid is a multiple of 8
        float4 a = *(const float4*)&in[i];
        float4 b = *(const float4*)&in[i + 4];
        o0.x = f2b(a.x); o0.y = f2b(a.y); o0.z = f2b(a.z); o0.w = f2b(a.w);
        o1.x = f2b(b.x); o1.y = f2b(b.y); o1.z = f2b(b.z); o1.w = f2b(b.w);
    } else {
        o0.x = o0.y = o0.z = o0.w = 0;
        o1 = o0;
    }
    *(ushort4*)&out[i] = o0;
    *(ushort4*)&out[i + 4] = o1;
}

// in: [K][N] fp32  ->  out: [N][K] bf16
__global__ void transpose_bf16_kernel(const float* __restrict__ in, unsigned short* __restrict__ out,
                                      int K, int N) {
    __shared__ float tile[32][33];
    int bn = blockIdx.x * 32, bk = blockIdx.y * 32;
    int tx = threadIdx.x & 31, ty = threadIdx.x >> 5;
    for (int i = ty; i < 32; i += 8) {
        int k = bk + i, n = bn + tx;
        tile[i][tx] = (k < K && n < N) ? in[(size_t)k * N + n] : 0.f;
    }
    __syncthreads();
    for (int i = ty; i < 32; i += 8) {
        int n = bn + i, k = bk + tx;
        if (n < N && k < K) out[(size_t)n * K + k] = f2b(tile[tx][i]);
    }
}

// ---------------- bf16 MFMA GEMM: C = A[MxK] @ BT[NxK]^T (+bias)(+relu) ----------------
__global__ __launch_bounds__(256) void mfma_gemm_kernel(
    const unsigned short* __restrict__ A, const unsigned short* __restrict__ BT,
    const float* __restrict__ bias, float* __restrict__ Cf, unsigned short* __restrict__ Cb,
    int M, int Nc, int K, int relu) {
    __shared__ unsigned short As[128 * 64];
    __shared__ unsigned short Bs[128 * 64];
    int t = threadIdx.x;
    int lane = t & 63, w = t >> 6;
    int gm0 = blockIdx.x * 128, gn0 = blockIdx.y * 128;
    f32x4 acc[4][4] = {};
    int srow = lane >> 3, scol = (lane & 7) * 8;
    int wm = (w >> 1) * 64, wn = (w & 1) * 64;
    int fr = lane & 15, fk = (lane >> 4) * 8;

    for (int k0 = 0; k0 < K; k0 += 64) {
        __syncthreads();
#pragma unroll
        for (int i = 0; i < 4; ++i) {
            int rb = w * 32 + i * 8;
            const unsigned short* ga = A + (size_t)(gm0 + rb + srow) * K + k0 + scol;
            __builtin_amdgcn_global_load_lds(
                (const __attribute__((address_space(1))) unsigned int*)ga,
                (__attribute__((address_space(3))) unsigned int*)&As[rb * 64], 16, 0, 0);
            const unsigned short* gb = BT + (size_t)(gn0 + rb + srow) * K + k0 + scol;
            __builtin_amdgcn_global_load_lds(
                (const __attribute__((address_space(1))) unsigned int*)gb,
                (__attribute__((address_space(3))) unsigned int*)&Bs[rb * 64], 16, 0, 0);
        }
        __syncthreads();
#pragma unroll
        for (int kk = 0; kk < 64; kk += 32) {
            short8 a[4], b[4];
#pragma unroll
            for (int m = 0; m < 4; ++m)
                a[m] = *(const short8*)&As[(wm + m * 16 + fr) * 64 + kk + fk];
#pragma unroll
            for (int n = 0; n < 4; ++n)
                b[n] = *(const short8*)&Bs[(wn + n * 16 + fr) * 64 + kk + fk];
#pragma unroll
            for (int m = 0; m < 4; ++m)
#pragma unroll
                for (int n = 0; n < 4; ++n)
                    acc[m][n] = __builtin_amdgcn_mfma_f32_16x16x32_bf16(a[m], b[n], acc[m][n], 0, 0, 0);
        }
    }
    int fcol = lane & 15, frow4 = (lane >> 4) * 4;
#pragma unroll
    for (int m = 0; m < 4; ++m) {
#pragma unroll
        for (int i = 0; i < 4; ++i) {
            int gr = gm0 + wm + m * 16 + frow4 + i;
            if (gr >= M) continue;
#pragma unroll
            for (int n = 0; n < 4; ++n) {
                int gc = gn0 + wn + n * 16 + fcol;
                float v = acc[m][n][i];
                if (bias) v += bias[gc];
                if (relu) v = fmaxf(v, 0.f);
                if (Cb) Cb[(size_t)gr * Nc + gc] = f2b(v);
                else    Cf[(size_t)gr * Nc + gc] = v;
            }
        }
    }
}

// ---------------- edge-attention projection ----------------
__global__ void me_kernel(const float* __restrict__ We, const float* __restrict__ ae,
                          float* __restrict__ Me) {
    int t = threadIdx.x;  // 512 threads
    int d = t >> 3, h = t & 7;
    float s = 0.f;
    for (int c = 0; c < C; ++c) s += We[d * (H * C) + h * C + c] * ae[h * C + c];
    Me[d * H + h] = s;
}

// one thread per edge; writes eA in CSR order via pos[e]; atomically accumulates sA by dst
__global__ void ealpha_kernel(const float* __restrict__ ew, const int* __restrict__ dst,
                              const int* __restrict__ pos,
                              const float* __restrict__ Me1, const float* __restrict__ Me2,
                              float* __restrict__ eA1c, float* __restrict__ eA2c,
                              float* __restrict__ sA1, float* __restrict__ sA2, int E) {
    __shared__ float M1[DE * H], M2[DE * H];
    int t = threadIdx.x;
    for (int i = t; i < DE * H; i += 256) { M1[i] = Me1[i]; M2[i] = Me2[i]; }
    __syncthreads();
    int e = blockIdx.x * 256 + t;
    if (e >= E) return;
    float a1[8] = {}, a2[8] = {};
    const float* row = ew + (size_t)e * DE;
#pragma unroll
    for (int i = 0; i < 16; ++i) {
        float4 rv = *(const float4*)&row[i * 4];
#pragma unroll
        for (int j = 0; j < 4; ++j) {
            float v = ((const float*)&rv)[j];
            int d = i * 4 + j;
#pragma unroll
            for (int hh = 0; hh < 8; ++hh) {
                a1[hh] = fmaf(v, M1[d * 8 + hh], a1[hh]);
                a2[hh] = fmaf(v, M2[d * 8 + hh], a2[hh]);
            }
        }
    }
    int p = pos[e], dn = dst[e];
#pragma unroll
    for (int hh = 0; hh < 8; ++hh) {
        eA1c[(size_t)p * 8 + hh] = a1[hh];
        eA2c[(size_t)p * 8 + hh] = a2[hh];
        atomicAdd(&sA1[dn * 8 + hh], a1[hh]);
        atomicAdd(&sA2[dn * 8 + hh], a2[hh]);
    }
}

// asrc/adst from bf16 xs
__global__ void attnparam_kernel(const unsigned short* __restrict__ xsb,
                                 const float* __restrict__ a_s, const float* __restrict__ a_d,
                                 float* __restrict__ asrc, float* __restrict__ adst, int N) {
    __shared__ float AS[D], AD[D];
    int t = threadIdx.x;
    AS[t] = a_s[t]; AD[t] = a_d[t];
    __syncthreads();
    int idx = blockIdx.x * 256 + t;
    int n = idx >> 3, hh = idx & 7;
    if (n < N) {
        const unsigned short* rowp = xsb + (size_t)n * D + hh * C;
        float s1 = 0.f, s2 = 0.f;
#pragma unroll
        for (int i = 0; i < 8; ++i) {
            ushort4 u = *(const ushort4*)&rowp[i * 4];
            float v0 = b2f(u.x), v1 = b2f(u.y), v2 = b2f(u.z), v3 = b2f(u.w);
            s1 += v0 * AS[hh * C + i * 4] + v1 * AS[hh * C + i * 4 + 1] +
                  v2 * AS[hh * C + i * 4 + 2] + v3 * AS[hh * C + i * 4 + 3];
            s2 += v0 * AD[hh * C + i * 4] + v1 * AD[hh * C + i * 4 + 1] +
                  v2 * AD[hh * C + i * 4 + 2] + v3 * AD[hh * C + i * 4 + 3];
        }
        asrc[idx] = s1; adst[idx] = s2;
    }
}

// ---------------- GAT: wave-per-node gather + softmax + fused LN/leaky/residual ----------------
// 4 nodes/block (1 wave each). Lane owns features lane*4..lane*4+3 (head hw=lane>>3).
// Producer role: slot k=lane>>3, head h=lane&7. No LDS, no __syncthreads.
__global__ __launch_bounds__(256) void gat_node_kernel(
    const int* __restrict__ off, const int* __restrict__ src_csr,
    const float* __restrict__ eAc, const float* __restrict__ sA,
    const float* __restrict__ asrc, const float* __restrict__ adst,
    const unsigned short* __restrict__ xsb, const float* __restrict__ nf_in,
    const float* __restrict__ bias, const float* __restrict__ gamma,
    const float* __restrict__ beta, float* __restrict__ nf_out,
    unsigned short* __restrict__ nf_out_b, int N) {
    int lane = threadIdx.x & 63;
    int n = blockIdx.x * 4 + (threadIdx.x >> 6);
    if (n >= N) return;
    int e0 = off[n], e1 = off[n + 1], deg = e1 - e0;
    int h = lane & 7;   // producer head
    int hw = lane >> 3; // k-slot / owner head

    float adstn = adst[n * 8 + h];
    float sa = sA[n * 8 + h] / (float)(deg > 0 ? deg : 1);
    float als = asrc[n * 8 + h] + adstn + sa;
    als = als > 0.f ? als : 0.2f * als;
    float exSelf = expf(als);

    float acc0 = 0.f, acc1 = 0.f, acc2 = 0.f, acc3 = 0.f;
    float den0 = 0.f;
    int nfull = deg >> 3, rem = deg & 7;
    int p = e0 + hw;
    for (int it = 0; it < nfull; ++it, p += 8) {
        int s = src_csr[p];
        float al = asrc[s * 8 + h] + adstn + eAc[(size_t)p * 8 + h];
        al = al > 0.f ? al : 0.2f * al;
        float ex = expf(al);
        den0 += ex;
#pragma unroll
        for (int kk = 0; kk < 8; ++kk) {
            int sl = kk * 8 + hw;
            float exk = __shfl(ex, sl);
            int sk = __shfl(s, sl);
            ushort4 u = *(const ushort4*)&xsb[(size_t)sk * D + lane * 4];
            acc0 = fmaf(exk, b2f(u.x), acc0);
            acc1 = fmaf(exk, b2f(u.y), acc1);
            acc2 = fmaf(exk, b2f(u.z), acc2);
            acc3 = fmaf(exk, b2f(u.w), acc3);
        }
    }
    if (rem) {
        float ex = 0.f; int s = 0;
        if (hw < rem) {
            s = src_csr[p];
            float al = asrc[s * 8 + h] + adstn + eAc[(size_t)p * 8 + h];
            al = al > 0.f ? al : 0.2f * al;
            ex = expf(al);
            den0 += ex;
        }
        for (int kk = 0; kk < rem; ++kk) {
            int sl = kk * 8 + hw;
            float exk = __shfl(ex, sl);
            int sk = __shfl(s, sl);
            ushort4 u = *(const ushort4*)&xsb[(size_t)sk * D + lane * 4];
            acc0 = fmaf(exk, b2f(u.x), acc0);
            acc1 = fmaf(exk, b2f(u.y), acc1);
            acc2 = fmaf(exk, b2f(u.z), acc2);
            acc3 = fmaf(exk, b2f(u.w), acc3);
        }
    }
    {   // self loop
        float exs = __shfl(exSelf, hw);
        ushort4 u = *(const ushort4*)&xsb[(size_t)n * D + lane * 4];
        acc0 = fmaf(exs, b2f(u.x), acc0);
        acc1 = fmaf(exs, b2f(u.y), acc1);
        acc2 = fmaf(exs, b2f(u.z), acc2);
        acc3 = fmaf(exs, b2f(u.w), acc3);
    }
    den0 += __shfl_xor(den0, 8);
    den0 += __shfl_xor(den0, 16);
    den0 += __shfl_xor(den0, 32);
    den0 += exSelf;
    float denOwn = __shfl(den0, hw);
    float inv = 1.f / (denOwn + 1e-16f);

    int t0 = lane * 4;
    float4 bi = *(const float4*)&bias[t0];
    float o0 = acc0 * inv + bi.x;
    float o1 = acc1 * inv + bi.y;
    float o2 = acc2 * inv + bi.z;
    float o3 = acc3 * inv + bi.w;

    float s1 = o0 + o1 + o2 + o3;
    float s2 = o0 * o0 + o1 * o1 + o2 * o2 + o3 * o3;
    for (int o = 1; o < 64; o <<= 1) { s1 += __shfl_xor(s1, o); s2 += __shfl_xor(s2, o); }
    float mu = s1 / 256.f;
    float var = fmaxf((s2 - 256.f * mu * mu) / 255.f, 0.f);
    float sdv = sqrtf(var) + 1e-6f;
    float4 ga = *(const float4*)&gamma[t0];
    float4 be = *(const float4*)&beta[t0];
    float4 nin = *(const float4*)&nf_in[(size_t)n * D + t0];
    float y0 = ga.x * (o0 - mu) / sdv + be.x; y0 = y0 > 0.f ? y0 : 0.01f * y0;
    float y1 = ga.y * (o1 - mu) / sdv + be.y; y1 = y1 > 0.f ? y1 : 0.01f * y1;
    float y2 = ga.z * (o2 - mu) / sdv + be.z; y2 = y2 > 0.f ? y2 : 0.01f * y2;
    float y3 = ga.w * (o3 - mu) / sdv + be.w; y3 = y3 > 0.f ? y3 : 0.01f * y3;
    float r0 = nin.x + y0, r1 = nin.y + y1, r2 = nin.z + y2, r3 = nin.w + y3;
    float4 outv; outv.x = r0; outv.y = r1; outv.z = r2; outv.w = r3;
    *(float4*)&nf_out[(size_t)n * D + t0] = outv;
    ushort4 ob; ob.x = f2b(r0); ob.y = f2b(r1); ob.z = f2b(r2); ob.w = f2b(r3);
    *(ushort4*)&nf_out_b[(size_t)n * D + t0] = ob;
}

// ---------------- FFN epilogue: LN + leaky + residual ----------------
__global__ void ln_residual_kernel(const float* __restrict__ hin, const float* __restrict__ nf_in,
                                   const float* __restrict__ gamma, const float* __restrict__ beta,
                                   float* __restrict__ out) {
    int n = blockIdx.x, t = threadIdx.x;
    float v = hin[(size_t)n * D + t];
    float s1 = v, s2 = v * v;
    for (int o = 1; o < 64; o <<= 1) { s1 += __shfl_xor(s1, o); s2 += __shfl_xor(s2, o); }
    __shared__ float r1[4], r2[4];
    int w = t >> 6;
    if ((t & 63) == 0) { r1[w] = s1; r2[w] = s2; }
    __syncthreads();
    float tot1 = r1[0] + r1[1] + r1[2] + r1[3];
    float tot2 = r2[0] + r2[1] + r2[2] + r2[3];
    float mu = tot1 / (float)D;
    float var = fmaxf((tot2 - (float)D * mu * mu) / (float)(D - 1), 0.f);
    float sd = sqrtf(var) + 1e-6f;
    float y = gamma[t] * (v - mu) / sd + beta[t];
    y = y > 0.f ? y : 0.01f * y;
    out[(size_t)n * D + t] = nf_in[(size_t)n * D + t] + y;
}

extern "C" void kernel_launch(void* const* d_in, const int* in_sizes, int n_in,
                              void* d_out, int out_size, void* d_ws, size_t ws_size,
                              hipStream_t stream) {
    const float* nf0    = (const float*)d_in[0];
    const int*   ei     = (const int*)d_in[1];
    const float* ew     = (const float*)d_in[2];
    const float* lin1   = (const float*)d_in[3];
    const float* le1    = (const float*)d_in[4];
    const float* asrc1w = (const float*)d_in[5];
    const float* adst1w = (const float*)d_in[6];
    const float* aedge1 = (const float*)d_in[7];
    const float* b1     = (const float*)d_in[8];
    const float* lin2   = (const float*)d_in[9];
    const float* le2    = (const float*)d_in[10];
    const float* asrc2w = (const float*)d_in[11];
    const float* adst2w = (const float*)d_in[12];
    const float* aedge2 = (const float*)d_in[13];
    const float* b2     = (const float*)d_in[14];
    const float* g1     = (const float*)d_in[15];
    const float* be1    = (const float*)d_in[16];
    const float* g2     = (const float*)d_in[17];
    const float* be2    = (const float*)d_in[18];
    const float* g3     = (const float*)d_in[19];
    const float* be3    = (const float*)d_in[20];
    const float* w1     = (const float*)d_in[21];
    const float* fb1    = (const float*)d_in[22];
    const float* w2     = (const float*)d_in[23];
    const float* fb2    = (const float*)d_in[24];

    const int N = in_sizes[0] / D;
    const int E = in_sizes[1] / 2;
    const int Mpad = ((N + 127) / 128) * 128;
    const int* srcI = ei;
    const int* dstI = ei + E;

    char* ws = (char*)d_ws;
    size_t ob = 0;
    auto alloc = [&](size_t bytes) { void* p = ws + ob; ob = align_up(ob + bytes, 256); return p; };
    // --- arena0: dead after GAT layer 2; reused as FFN hidden (bf16, Mpad*DF*2 = 20.7MB) ---
    int*   deg     = (int*)alloc((size_t)N * 4);
    int*   csr_off = (int*)alloc((size_t)(N + 1) * 4);
    int*   cursor  = (int*)alloc((size_t)N * 4);
    int*   part    = (int*)alloc(1024);
    int*   pos     = (int*)alloc((size_t)E * 4);
    int*   src_csr = (int*)alloc((size_t)E * 4);
    float* Me1     = (float*)alloc(DE * H * 4);
    float* Me2     = (float*)alloc(DE * H * 4);
    float* sA1     = (float*)alloc((size_t)N * H * 4);
    float* sA2     = (float*)alloc((size_t)N * H * 4);
    float* asrcB   = (float*)alloc((size_t)N * H * 4);
    float* adstB   = (float*)alloc((size_t)N * H * 4);
    float* eA1c    = (float*)alloc((size_t)E * H * 4);
    float* eA2c    = (float*)alloc((size_t)E * H * 4);
    // --- persistent ---
    float* xsf     = (float*)alloc((size_t)Mpad * D * 4);  // FFN output (fp32)
    float* nfw     = (float*)alloc((size_t)N * D * 4);
    unsigned short* xs_b  = (unsigned short*)alloc((size_t)Mpad * D * 2);
    unsigned short* Abf   = (unsigned short*)alloc((size_t)Mpad * D * 2);
    unsigned short* lin1T = (unsigned short*)alloc((size_t)D * D * 2);
    unsigned short* lin2T = (unsigned short*)alloc((size_t)D * D * 2);
    unsigned short* w1T   = (unsigned short*)alloc((size_t)DF * D * 2);
    unsigned short* w2T   = (unsigned short*)alloc((size_t)D * DF * 2);
    unsigned short* hidden = (unsigned short*)ws;  // aliases arena0 (~25MB > 20.7MB)
    (void)ws_size;
    float* out = (float*)d_out;

    hipMemsetAsync(deg, 0, (size_t)N * 4, stream);
    hipMemsetAsync(sA1, 0, (size_t)N * H * 4, stream);
    hipMemsetAsync(sA2, 0, (size_t)N * H * 4, stream);

    int eb = (E + 255) / 256;
    int nb = (N + 255) / 256;
    deg_kernel<<<eb, 256, 0, stream>>>(dstI, deg, E);
    partial_sum_kernel<<<nb, 256, 0, stream>>>(deg, part, N);
    scan_part_kernel<<<1, 256, 0, stream>>>(part, nb);
    scan_final_kernel<<<nb, 256, 0, stream>>>(deg, part, csr_off, N);
    copy_int_kernel<<<nb, 256, 0, stream>>>(csr_off, cursor, N);
    fill_kernel<<<eb, 256, 0, stream>>>(srcI, dstI, cursor, pos, src_csr, E);

    me_kernel<<<1, 512, 0, stream>>>(le1, aedge1, Me1);
    me_kernel<<<1, 512, 0, stream>>>(le2, aedge2, Me2);
    ealpha_kernel<<<eb, 256, 0, stream>>>(ew, dstI, pos, Me1, Me2, eA1c, eA2c, sA1, sA2, E);

    transpose_bf16_kernel<<<dim3(D / 32, D / 32), 256, 0, stream>>>(lin1, lin1T, D, D);
    transpose_bf16_kernel<<<dim3(D / 32, D / 32), 256, 0, stream>>>(lin2, lin2T, D, D);
    transpose_bf16_kernel<<<dim3(DF / 32, D / 32), 256, 0, stream>>>(w1, w1T, D, DF);
    transpose_bf16_kernel<<<dim3(D / 32, DF / 32), 256, 0, stream>>>(w2, w2T, DF, D);

    const size_t nvalid = (size_t)N * D, ntot = (size_t)Mpad * D;
    int cb = (int)((ntot / 8 + 255) / 256);
    int gatb = (N + 3) / 4;

    // ---- GAT layer 1 ----
    convert_bf16x8_kernel<<<cb, 256, 0, stream>>>(nf0, Abf, nvalid, ntot);
    mfma_gemm_kernel<<<dim3(Mpad / 128, D / 128), 256, 0, stream>>>(
        Abf, lin1T, nullptr, nullptr, xs_b, N, D, D, 0);
    attnparam_kernel<<<(N * H + 255) / 256, 256, 0, stream>>>(xs_b, asrc1w, adst1w, asrcB, adstB, N);
    gat_node_kernel<<<gatb, 256, 0, stream>>>(csr_off, src_csr, eA1c, sA1, asrcB, adstB,
                                              xs_b, nf0, b1, g1, be1, nfw, Abf, N);
    // ---- GAT layer 2 ----
    mfma_gemm_kernel<<<dim3(Mpad / 128, D / 128), 256, 0, stream>>>(
        Abf, lin2T, nullptr, nullptr, xs_b, N, D, D, 0);
    attnparam_kernel<<<(N * H + 255) / 256, 256, 0, stream>>>(xs_b, asrc2w, adst2w, asrcB, adstB, N);
    gat_node_kernel<<<gatb, 256, 0, stream>>>(csr_off, src_csr, eA2c, sA2, asrcB, adstB,
                                              xs_b, nfw, b2, g2, be2, nfw, Abf, N);
    // ---- FFN ----
    mfma_gemm_kernel<<<dim3(Mpad / 128, DF / 128), 256, 0, stream>>>(
        Abf, w1T, fb1, nullptr, hidden, N, DF, D, 1);
    mfma_gemm_kernel<<<dim3(Mpad / 128, D / 128), 256, 0, stream>>>(
        hidden, w2T, fb2, xsf, nullptr, N, D, DF, 0);
    ln_residual_kernel<<<N, 256, 0, stream>>>(xsf, nfw, g3, be3, out);
}

// Round 4
// 280.468 us; speedup vs baseline: 1.9294x; 1.9294x over previous
//
#include <hip/hip_runtime.h>
#include <hip/hip_bf16.h>
#include <math.h>

#define D 256
#define H 8
#define C 32
#define DE 64
#define DF 1024

static inline size_t align_up(size_t x, size_t a) { return (x + a - 1) / a * a; }

typedef __attribute__((ext_vector_type(8))) short short8;
typedef __attribute__((ext_vector_type(4))) float f32x4;

__device__ inline unsigned short f2b(float x) {
    __hip_bfloat16 h = __float2bfloat16(x);
    return *reinterpret_cast<unsigned short*>(&h);
}
__device__ inline float b2f(unsigned short u) {
    return __uint_as_float(((unsigned int)u) << 16);
}

// ---------------- CSR build ----------------
__global__ void deg_kernel(const int* __restrict__ dst, int* __restrict__ deg, int E) {
    int e = blockIdx.x * 256 + threadIdx.x;
    if (e < E) atomicAdd(&deg[dst[e]], 1);
}

__global__ void partial_sum_kernel(const int* __restrict__ deg, int* __restrict__ part, int n) {
    int i = blockIdx.x * 256 + threadIdx.x;
    int v = (i < n) ? deg[i] : 0;
    for (int o = 1; o < 64; o <<= 1) v += __shfl_xor(v, o);
    __shared__ int w4[4];
    if ((threadIdx.x & 63) == 0) w4[threadIdx.x >> 6] = v;
    __syncthreads();
    if (threadIdx.x == 0) part[blockIdx.x] = w4[0] + w4[1] + w4[2] + w4[3];
}

__global__ void scan_part_kernel(int* __restrict__ part, int nb) {
    __shared__ int buf[256];
    int t = threadIdx.x;
    buf[t] = (t < nb) ? part[t] : 0;
    __syncthreads();
    for (int s = 1; s < 256; s <<= 1) {
        int v = (t >= s) ? buf[t - s] : 0;
        __syncthreads();
        buf[t] += v;
        __syncthreads();
    }
    int excl = (t == 0) ? 0 : buf[t - 1];
    if (t < nb) part[t] = excl;
}

__global__ void scan_final_kernel(const int* __restrict__ deg, const int* __restrict__ part,
                                  int* __restrict__ off, int n) {
    int b = blockIdx.x, t = threadIdx.x, i = b * 256 + t;
    __shared__ int buf[256];
    int v = (i < n) ? deg[i] : 0;
    buf[t] = v;
    __syncthreads();
    for (int s = 1; s < 256; s <<= 1) {
        int x = (t >= s) ? buf[t - s] : 0;
        __syncthreads();
        buf[t] += x;
        __syncthreads();
    }
    int excl = part[b] + buf[t] - v;
    if (i < n) off[i] = excl;
    if (i == n - 1) off[n] = excl + v;
}

__global__ void copy_int_kernel(const int* __restrict__ a, int* __restrict__ b, int n) {
    int i = blockIdx.x * 256 + threadIdx.x;
    if (i < n) b[i] = a[i];
}

// writes eid[p] (edge at CSR slot p) and src_csr[p] (source node of slot p)
__global__ void fill_kernel(const int* __restrict__ src, const int* __restrict__ dst,
                            int* __restrict__ cursor, int* __restrict__ eid,
                            int* __restrict__ src_csr, int E) {
    int e = blockIdx.x * 256 + threadIdx.x;
    if (e < E) {
        int p = atomicAdd(&cursor[dst[e]], 1);
        eid[p] = e;
        src_csr[p] = src[e];
    }
}

// ---------------- bf16 conversion / transpose ----------------
__global__ void convert_bf16x8_kernel(const float* __restrict__ in, unsigned short* __restrict__ out,
                                      size_t n_valid, size_t n_total) {
    size_t i = ((size_t)blockIdx.x * 256 + threadIdx.x) * 8;
    if (i >= n_total) return;
    ushort4 o0, o1;
    if (i < n_valid) {  // n_valid is a multiple of 8
        float4 a = *(const float4*)&in[i];
        float4 b = *(const float4*)&in[i + 4];
        o0.x = f2b(a.x); o0.y = f2b(a.y); o0.z = f2b(a.z); o0.w = f2b(a.w);
        o1.x = f2b(b.x); o1.y = f2b(b.y); o1.z = f2b(b.z); o1.w = f2b(b.w);
    } else {
        o0.x = o0.y = o0.z = o0.w = 0;
        o1 = o0;
    }
    *(ushort4*)&out[i] = o0;
    *(ushort4*)&out[i + 4] = o1;
}

// in: [K][N] fp32  ->  out: [N][K] bf16
__global__ void transpose_bf16_kernel(const float* __restrict__ in, unsigned short* __restrict__ out,
                                      int K, int N) {
    __shared__ float tile[32][33];
    int bn = blockIdx.x * 32, bk = blockIdx.y * 32;
    int tx = threadIdx.x & 31, ty = threadIdx.x >> 5;
    for (int i = ty; i < 32; i += 8) {
        int k = bk + i, n = bn + tx;
        tile[i][tx] = (k < K && n < N) ? in[(size_t)k * N + n] : 0.f;
    }
    __syncthreads();
    for (int i = ty; i < 32; i += 8) {
        int n = bn + i, k = bk + tx;
        if (n < N && k < K) out[(size_t)n * K + k] = f2b(tile[tx][i]);
    }
}

// ---------------- bf16 MFMA GEMM: C = A[MxK] @ BT[NxK]^T (+bias)(+relu) ----------------
__global__ __launch_bounds__(256) void mfma_gemm_kernel(
    const unsigned short* __restrict__ A, const unsigned short* __restrict__ BT,
    const float* __restrict__ bias, float* __restrict__ Cf, unsigned short* __restrict__ Cb,
    int M, int Nc, int K, int relu) {
    __shared__ unsigned short As[128 * 64];
    __shared__ unsigned short Bs[128 * 64];
    int t = threadIdx.x;
    int lane = t & 63, w = t >> 6;
    int gm0 = blockIdx.x * 128, gn0 = blockIdx.y * 128;
    f32x4 acc[4][4] = {};
    int srow = lane >> 3, scol = (lane & 7) * 8;
    int wm = (w >> 1) * 64, wn = (w & 1) * 64;
    int fr = lane & 15, fk = (lane >> 4) * 8;

    for (int k0 = 0; k0 < K; k0 += 64) {
        __syncthreads();
#pragma unroll
        for (int i = 0; i < 4; ++i) {
            int rb = w * 32 + i * 8;
            const unsigned short* ga = A + (size_t)(gm0 + rb + srow) * K + k0 + scol;
            __builtin_amdgcn_global_load_lds(
                (const __attribute__((address_space(1))) unsigned int*)ga,
                (__attribute__((address_space(3))) unsigned int*)&As[rb * 64], 16, 0, 0);
            const unsigned short* gb = BT + (size_t)(gn0 + rb + srow) * K + k0 + scol;
            __builtin_amdgcn_global_load_lds(
                (const __attribute__((address_space(1))) unsigned int*)gb,
                (__attribute__((address_space(3))) unsigned int*)&Bs[rb * 64], 16, 0, 0);
        }
        __syncthreads();
#pragma unroll
        for (int kk = 0; kk < 64; kk += 32) {
            short8 a[4], b[4];
#pragma unroll
            for (int m = 0; m < 4; ++m)
                a[m] = *(const short8*)&As[(wm + m * 16 + fr) * 64 + kk + fk];
#pragma unroll
            for (int n = 0; n < 4; ++n)
                b[n] = *(const short8*)&Bs[(wn + n * 16 + fr) * 64 + kk + fk];
#pragma unroll
            for (int m = 0; m < 4; ++m)
#pragma unroll
                for (int n = 0; n < 4; ++n)
                    acc[m][n] = __builtin_amdgcn_mfma_f32_16x16x32_bf16(a[m], b[n], acc[m][n], 0, 0, 0);
        }
    }
    int fcol = lane & 15, frow4 = (lane >> 4) * 4;
#pragma unroll
    for (int m = 0; m < 4; ++m) {
#pragma unroll
        for (int i = 0; i < 4; ++i) {
            int gr = gm0 + wm + m * 16 + frow4 + i;
            if (gr >= M) continue;
#pragma unroll
            for (int n = 0; n < 4; ++n) {
                int gc = gn0 + wn + n * 16 + fcol;
                float v = acc[m][n][i];
                if (bias) v += bias[gc];
                if (relu) v = fmaxf(v, 0.f);
                if (Cb) Cb[(size_t)gr * Nc + gc] = f2b(v);
                else    Cf[(size_t)gr * Nc + gc] = v;
            }
        }
    }
}

// ---------------- edge-attention projection ----------------
__global__ void me_kernel(const float* __restrict__ We, const float* __restrict__ ae,
                          float* __restrict__ Me) {
    int t = threadIdx.x;  // 512 threads
    int d = t >> 3, h = t & 7;
    float s = 0.f;
    for (int c = 0; c < C; ++c) s += We[d * (H * C) + h * C + c] * ae[h * C + c];
    Me[d * H + h] = s;
}

// thread per CSR slot p: gather ew row of edge eid[p] (random 256B read, exactly once),
// write eA1c/eA2c coalesced in CSR order. No atomics, no sA.
__global__ void ealpha_csr_kernel(const float* __restrict__ ew, const int* __restrict__ eid,
                                  const float* __restrict__ Me1, const float* __restrict__ Me2,
                                  float* __restrict__ eA1c, float* __restrict__ eA2c, int E) {
    __shared__ float M1[DE * H], M2[DE * H];
    int t = threadIdx.x;
    for (int i = t; i < DE * H; i += 256) { M1[i] = Me1[i]; M2[i] = Me2[i]; }
    __syncthreads();
    int p = blockIdx.x * 256 + t;
    if (p >= E) return;
    int e = eid[p];
    const float* row = ew + (size_t)e * DE;
    float a1[8] = {}, a2[8] = {};
#pragma unroll
    for (int i = 0; i < 16; ++i) {
        float4 rv = *(const float4*)&row[i * 4];
#pragma unroll
        for (int j = 0; j < 4; ++j) {
            float v = ((const float*)&rv)[j];
            int d = i * 4 + j;
#pragma unroll
            for (int hh = 0; hh < 8; ++hh) {
                a1[hh] = fmaf(v, M1[d * 8 + hh], a1[hh]);
                a2[hh] = fmaf(v, M2[d * 8 + hh], a2[hh]);
            }
        }
    }
#pragma unroll
    for (int hh = 0; hh < 8; ++hh) {
        eA1c[(size_t)p * 8 + hh] = a1[hh];
        eA2c[(size_t)p * 8 + hh] = a2[hh];
    }
}

// asrc/adst from bf16 xs
__global__ void attnparam_kernel(const unsigned short* __restrict__ xsb,
                                 const float* __restrict__ a_s, const float* __restrict__ a_d,
                                 float* __restrict__ asrc, float* __restrict__ adst, int N) {
    __shared__ float AS[D], AD[D];
    int t = threadIdx.x;
    AS[t] = a_s[t]; AD[t] = a_d[t];
    __syncthreads();
    int idx = blockIdx.x * 256 + t;
    int n = idx >> 3, hh = idx & 7;
    if (n < N) {
        const unsigned short* rowp = xsb + (size_t)n * D + hh * C;
        float s1 = 0.f, s2 = 0.f;
#pragma unroll
        for (int i = 0; i < 8; ++i) {
            ushort4 u = *(const ushort4*)&rowp[i * 4];
            float v0 = b2f(u.x), v1 = b2f(u.y), v2 = b2f(u.z), v3 = b2f(u.w);
            s1 += v0 * AS[hh * C + i * 4] + v1 * AS[hh * C + i * 4 + 1] +
                  v2 * AS[hh * C + i * 4 + 2] + v3 * AS[hh * C + i * 4 + 3];
            s2 += v0 * AD[hh * C + i * 4] + v1 * AD[hh * C + i * 4 + 1] +
                  v2 * AD[hh * C + i * 4 + 2] + v3 * AD[hh * C + i * 4 + 3];
        }
        asrc[idx] = s1; adst[idx] = s2;
    }
}

// ---------------- GAT: wave-per-node gather + softmax + fused LN/leaky/residual ----------------
// 4 nodes/block (1 wave each). Lane owns features lane*4..lane*4+3.
// Producer role: slot k=lane>>3 (hw), head h=lane&7. Self-loop attr derived from
// easum (running sum of eA over incoming slots) -> no sA array needed.
__global__ __launch_bounds__(256) void gat_node_kernel(
    const int* __restrict__ off, const int* __restrict__ src_csr,
    const float* __restrict__ eAc,
    const float* __restrict__ asrc, const float* __restrict__ adst,
    const unsigned short* __restrict__ xsb, const float* __restrict__ nf_in,
    const float* __restrict__ bias, const float* __restrict__ gamma,
    const float* __restrict__ beta, float* __restrict__ nf_out,
    unsigned short* __restrict__ nf_out_b, int N) {
    int lane = threadIdx.x & 63;
    int n = blockIdx.x * 4 + (threadIdx.x >> 6);
    if (n >= N) return;
    int e0 = off[n], e1 = off[n + 1], deg = e1 - e0;
    int h = lane & 7;   // producer head
    int hw = lane >> 3; // k-slot / owner head

    float adstn = adst[n * 8 + h];

    float acc0 = 0.f, acc1 = 0.f, acc2 = 0.f, acc3 = 0.f;
    float den0 = 0.f, easum = 0.f;
    int nfull = deg >> 3, rem = deg & 7;
    int p = e0 + hw;
    for (int it = 0; it < nfull; ++it, p += 8) {
        int s = src_csr[p];
        float ea = eAc[(size_t)p * 8 + h];
        float al = asrc[s * 8 + h] + adstn + ea;
        al = al > 0.f ? al : 0.2f * al;
        float ex = expf(al);
        den0 += ex;
        easum += ea;
#pragma unroll
        for (int kk = 0; kk < 8; ++kk) {
            int sl = kk * 8 + hw;
            float exk = __shfl(ex, sl);
            int sk = __shfl(s, sl);
            ushort4 u = *(const ushort4*)&xsb[(size_t)sk * D + lane * 4];
            acc0 = fmaf(exk, b2f(u.x), acc0);
            acc1 = fmaf(exk, b2f(u.y), acc1);
            acc2 = fmaf(exk, b2f(u.z), acc2);
            acc3 = fmaf(exk, b2f(u.w), acc3);
        }
    }
    if (rem) {
        float ex = 0.f; int s = 0;
        if (hw < rem) {
            s = src_csr[p];
            float ea = eAc[(size_t)p * 8 + h];
            float al = asrc[s * 8 + h] + adstn + ea;
            al = al > 0.f ? al : 0.2f * al;
            ex = expf(al);
            den0 += ex;
            easum += ea;
        }
        for (int kk = 0; kk < rem; ++kk) {
            int sl = kk * 8 + hw;
            float exk = __shfl(ex, sl);
            int sk = __shfl(s, sl);
            ushort4 u = *(const ushort4*)&xsb[(size_t)sk * D + lane * 4];
            acc0 = fmaf(exk, b2f(u.x), acc0);
            acc1 = fmaf(exk, b2f(u.y), acc1);
            acc2 = fmaf(exk, b2f(u.z), acc2);
            acc3 = fmaf(exk, b2f(u.w), acc3);
        }
    }
    // reduce den and easum across k-slot groups (bits 3..5 of lane)
    den0  += __shfl_xor(den0, 8);
    den0  += __shfl_xor(den0, 16);
    den0  += __shfl_xor(den0, 32);
    easum += __shfl_xor(easum, 8);
    easum += __shfl_xor(easum, 16);
    easum += __shfl_xor(easum, 32);
    // self loop: loop_attr@Me = easum/deg
    float sa = easum / (float)(deg > 0 ? deg : 1);
    float als = asrc[n * 8 + h] + adstn + sa;
    als = als > 0.f ? als : 0.2f * als;
    float exSelf = expf(als);
    {
        float exs = __shfl(exSelf, hw);
        ushort4 u = *(const ushort4*)&xsb[(size_t)n * D + lane * 4];
        acc0 = fmaf(exs, b2f(u.x), acc0);
        acc1 = fmaf(exs, b2f(u.y), acc1);
        acc2 = fmaf(exs, b2f(u.z), acc2);
        acc3 = fmaf(exs, b2f(u.w), acc3);
    }
    den0 += exSelf;
    float denOwn = __shfl(den0, hw);
    float inv = 1.f / (denOwn + 1e-16f);

    int t0 = lane * 4;
    float4 bi = *(const float4*)&bias[t0];
    float o0 = acc0 * inv + bi.x;
    float o1 = acc1 * inv + bi.y;
    float o2 = acc2 * inv + bi.z;
    float o3 = acc3 * inv + bi.w;

    float s1 = o0 + o1 + o2 + o3;
    float s2 = o0 * o0 + o1 * o1 + o2 * o2 + o3 * o3;
    for (int o = 1; o < 64; o <<= 1) { s1 += __shfl_xor(s1, o); s2 += __shfl_xor(s2, o); }
    float mu = s1 / 256.f;
    float var = fmaxf((s2 - 256.f * mu * mu) / 255.f, 0.f);
    float sdv = sqrtf(var) + 1e-6f;
    float4 ga = *(const float4*)&gamma[t0];
    float4 be = *(const float4*)&beta[t0];
    float4 nin = *(const float4*)&nf_in[(size_t)n * D + t0];
    float y0 = ga.x * (o0 - mu) / sdv + be.x; y0 = y0 > 0.f ? y0 : 0.01f * y0;
    float y1 = ga.y * (o1 - mu) / sdv + be.y; y1 = y1 > 0.f ? y1 : 0.01f * y1;
    float y2 = ga.z * (o2 - mu) / sdv + be.z; y2 = y2 > 0.f ? y2 : 0.01f * y2;
    float y3 = ga.w * (o3 - mu) / sdv + be.w; y3 = y3 > 0.f ? y3 : 0.01f * y3;
    float r0 = nin.x + y0, r1 = nin.y + y1, r2 = nin.z + y2, r3 = nin.w + y3;
    float4 outv; outv.x = r0; outv.y = r1; outv.z = r2; outv.w = r3;
    *(float4*)&nf_out[(size_t)n * D + t0] = outv;
    ushort4 ob; ob.x = f2b(r0); ob.y = f2b(r1); ob.z = f2b(r2); ob.w = f2b(r3);
    *(ushort4*)&nf_out_b[(size_t)n * D + t0] = ob;
}

// ---------------- FFN epilogue: LN + leaky + residual ----------------
__global__ void ln_residual_kernel(const float* __restrict__ hin, const float* __restrict__ nf_in,
                                   const float* __restrict__ gamma, const float* __restrict__ beta,
                                   float* __restrict__ out) {
    int n = blockIdx.x, t = threadIdx.x;
    float v = hin[(size_t)n * D + t];
    float s1 = v, s2 = v * v;
    for (int o = 1; o < 64; o <<= 1) { s1 += __shfl_xor(s1, o); s2 += __shfl_xor(s2, o); }
    __shared__ float r1[4], r2[4];
    int w = t >> 6;
    if ((t & 63) == 0) { r1[w] = s1; r2[w] = s2; }
    __syncthreads();
    float tot1 = r1[0] + r1[1] + r1[2] + r1[3];
    float tot2 = r2[0] + r2[1] + r2[2] + r2[3];
    float mu = tot1 / (float)D;
    float var = fmaxf((tot2 - (float)D * mu * mu) / (float)(D - 1), 0.f);
    float sd = sqrtf(var) + 1e-6f;
    float y = gamma[t] * (v - mu) / sd + beta[t];
    y = y > 0.f ? y : 0.01f * y;
    out[(size_t)n * D + t] = nf_in[(size_t)n * D + t] + y;
}

extern "C" void kernel_launch(void* const* d_in, const int* in_sizes, int n_in,
                              void* d_out, int out_size, void* d_ws, size_t ws_size,
                              hipStream_t stream) {
    const float* nf0    = (const float*)d_in[0];
    const int*   ei     = (const int*)d_in[1];
    const float* ew     = (const float*)d_in[2];
    const float* lin1   = (const float*)d_in[3];
    const float* le1    = (const float*)d_in[4];
    const float* asrc1w = (const float*)d_in[5];
    const float* adst1w = (const float*)d_in[6];
    const float* aedge1 = (const float*)d_in[7];
    const float* b1     = (const float*)d_in[8];
    const float* lin2   = (const float*)d_in[9];
    const float* le2    = (const float*)d_in[10];
    const float* asrc2w = (const float*)d_in[11];
    const float* adst2w = (const float*)d_in[12];
    const float* aedge2 = (const float*)d_in[13];
    const float* b2     = (const float*)d_in[14];
    const float* g1     = (const float*)d_in[15];
    const float* be1    = (const float*)d_in[16];
    const float* g2     = (const float*)d_in[17];
    const float* be2    = (const float*)d_in[18];
    const float* g3     = (const float*)d_in[19];
    const float* be3    = (const float*)d_in[20];
    const float* w1     = (const float*)d_in[21];
    const float* fb1    = (const float*)d_in[22];
    const float* w2     = (const float*)d_in[23];
    const float* fb2    = (const float*)d_in[24];

    const int N = in_sizes[0] / D;
    const int E = in_sizes[1] / 2;
    const int Mpad = ((N + 127) / 128) * 128;
    const int* srcI = ei;
    const int* dstI = ei + E;

    char* ws = (char*)d_ws;
    size_t ob = 0;
    auto alloc = [&](size_t bytes) { void* p = ws + ob; ob = align_up(ob + bytes, 256); return p; };
    // --- arena0: dead after GAT layer 2; reused as FFN hidden (bf16, Mpad*DF*2 = 20.7MB) ---
    int*   deg     = (int*)alloc((size_t)N * 4);
    int*   csr_off = (int*)alloc((size_t)(N + 1) * 4);
    int*   cursor  = (int*)alloc((size_t)N * 4);
    int*   part    = (int*)alloc(1024);
    int*   eid     = (int*)alloc((size_t)E * 4);
    int*   src_csr = (int*)alloc((size_t)E * 4);
    float* Me1     = (float*)alloc(DE * H * 4);
    float* Me2     = (float*)alloc(DE * H * 4);
    float* asrcB   = (float*)alloc((size_t)N * H * 4);
    float* adstB   = (float*)alloc((size_t)N * H * 4);
    float* eA1c    = (float*)alloc((size_t)E * H * 4);
    float* eA2c    = (float*)alloc((size_t)E * H * 4);
    // --- persistent ---
    float* xsf     = (float*)alloc((size_t)Mpad * D * 4);  // FFN output (fp32)
    float* nfw     = (float*)alloc((size_t)N * D * 4);
    unsigned short* xs_b  = (unsigned short*)alloc((size_t)Mpad * D * 2);
    unsigned short* Abf   = (unsigned short*)alloc((size_t)Mpad * D * 2);
    unsigned short* lin1T = (unsigned short*)alloc((size_t)D * D * 2);
    unsigned short* lin2T = (unsigned short*)alloc((size_t)D * D * 2);
    unsigned short* w1T   = (unsigned short*)alloc((size_t)DF * D * 2);
    unsigned short* w2T   = (unsigned short*)alloc((size_t)D * DF * 2);
    unsigned short* hidden = (unsigned short*)ws;  // aliases arena0 (~25MB > 20.7MB)
    (void)ws_size;
    float* out = (float*)d_out;

    hipMemsetAsync(deg, 0, (size_t)N * 4, stream);

    int eb = (E + 255) / 256;
    int nb = (N + 255) / 256;
    deg_kernel<<<eb, 256, 0, stream>>>(dstI, deg, E);
    partial_sum_kernel<<<nb, 256, 0, stream>>>(deg, part, N);
    scan_part_kernel<<<1, 256, 0, stream>>>(part, nb);
    scan_final_kernel<<<nb, 256, 0, stream>>>(deg, part, csr_off, N);
    copy_int_kernel<<<nb, 256, 0, stream>>>(csr_off, cursor, N);
    fill_kernel<<<eb, 256, 0, stream>>>(srcI, dstI, cursor, eid, src_csr, E);

    me_kernel<<<1, 512, 0, stream>>>(le1, aedge1, Me1);
    me_kernel<<<1, 512, 0, stream>>>(le2, aedge2, Me2);
    ealpha_csr_kernel<<<eb, 256, 0, stream>>>(ew, eid, Me1, Me2, eA1c, eA2c, E);

    transpose_bf16_kernel<<<dim3(D / 32, D / 32), 256, 0, stream>>>(lin1, lin1T, D, D);
    transpose_bf16_kernel<<<dim3(D / 32, D / 32), 256, 0, stream>>>(lin2, lin2T, D, D);
    transpose_bf16_kernel<<<dim3(DF / 32, D / 32), 256, 0, stream>>>(w1, w1T, D, DF);
    transpose_bf16_kernel<<<dim3(D / 32, DF / 32), 256, 0, stream>>>(w2, w2T, DF, D);

    const size_t nvalid = (size_t)N * D, ntot = (size_t)Mpad * D;
    int cb = (int)((ntot / 8 + 255) / 256);
    int gatb = (N + 3) / 4;

    // ---- GAT layer 1 ----
    convert_bf16x8_kernel<<<cb, 256, 0, stream>>>(nf0, Abf, nvalid, ntot);
    mfma_gemm_kernel<<<dim3(Mpad / 128, D / 128), 256, 0, stream>>>(
        Abf, lin1T, nullptr, nullptr, xs_b, N, D, D, 0);
    attnparam_kernel<<<(N * H + 255) / 256, 256, 0, stream>>>(xs_b, asrc1w, adst1w, asrcB, adstB, N);
    gat_node_kernel<<<gatb, 256, 0, stream>>>(csr_off, src_csr, eA1c, asrcB, adstB,
                                              xs_b, nf0, b1, g1, be1, nfw, Abf, N);
    // ---- GAT layer 2 ----
    mfma_gemm_kernel<<<dim3(Mpad / 128, D / 128), 256, 0, stream>>>(
        Abf, lin2T, nullptr, nullptr, xs_b, N, D, D, 0);
    attnparam_kernel<<<(N * H + 255) / 256, 256, 0, stream>>>(xs_b, asrc2w, adst2w, asrcB, adstB, N);
    gat_node_kernel<<<gatb, 256, 0, stream>>>(csr_off, src_csr, eA2c, asrcB, adstB,
                                              xs_b, nfw, b2, g2, be2, nfw, Abf, N);
    // ---- FFN ----
    mfma_gemm_kernel<<<dim3(Mpad / 128, DF / 128), 256, 0, stream>>>(
        Abf, w1T, fb1, nullptr, hidden, N, DF, D, 1);
    mfma_gemm_kernel<<<dim3(Mpad / 128, D / 128), 256, 0, stream>>>(
        hidden, w2T, fb2, xsf, nullptr, N, D, DF, 0);
    ln_residual_kernel<<<N, 256, 0, stream>>>(xsf, nfw, g3, be3, out);
}

// Round 5
// 263.068 us; speedup vs baseline: 2.0570x; 1.0661x over previous
//
#include <hip/hip_runtime.h>
#include <hip/hip_bf16.h>
#include <math.h>

#define D 256
#define H 8
#define C 32
#define DE 64
#define DF 1024

static inline size_t align_up(size_t x, size_t a) { return (x + a - 1) / a * a; }

typedef __attribute__((ext_vector_type(8))) short short8;
typedef __attribute__((ext_vector_type(4))) float f32x4;

__device__ inline unsigned short f2b(float x) {
    __hip_bfloat16 h = __float2bfloat16(x);
    return *reinterpret_cast<unsigned short*>(&h);
}
__device__ inline float b2f(unsigned short u) {
    return __uint_as_float(((unsigned int)u) << 16);
}

// ---------------- CSR build ----------------
__global__ void deg_kernel(const int* __restrict__ dst, int* __restrict__ deg, int E) {
    int e = blockIdx.x * 256 + threadIdx.x;
    if (e < E) atomicAdd(&deg[dst[e]], 1);
}

__global__ void partial_sum_kernel(const int* __restrict__ deg, int* __restrict__ part, int n) {
    int i = blockIdx.x * 256 + threadIdx.x;
    int v = (i < n) ? deg[i] : 0;
    for (int o = 1; o < 64; o <<= 1) v += __shfl_xor(v, o);
    __shared__ int w4[4];
    if ((threadIdx.x & 63) == 0) w4[threadIdx.x >> 6] = v;
    __syncthreads();
    if (threadIdx.x == 0) part[blockIdx.x] = w4[0] + w4[1] + w4[2] + w4[3];
}

__global__ void scan_part_kernel(int* __restrict__ part, int nb) {
    __shared__ int buf[256];
    int t = threadIdx.x;
    buf[t] = (t < nb) ? part[t] : 0;
    __syncthreads();
    for (int s = 1; s < 256; s <<= 1) {
        int v = (t >= s) ? buf[t - s] : 0;
        __syncthreads();
        buf[t] += v;
        __syncthreads();
    }
    int excl = (t == 0) ? 0 : buf[t - 1];
    if (t < nb) part[t] = excl;
}

__global__ void scan_final_kernel(const int* __restrict__ deg, const int* __restrict__ part,
                                  int* __restrict__ off, int* __restrict__ cursor, int n) {
    int b = blockIdx.x, t = threadIdx.x, i = b * 256 + t;
    __shared__ int buf[256];
    int v = (i < n) ? deg[i] : 0;
    buf[t] = v;
    __syncthreads();
    for (int s = 1; s < 256; s <<= 1) {
        int x = (t >= s) ? buf[t - s] : 0;
        __syncthreads();
        buf[t] += x;
        __syncthreads();
    }
    int excl = part[b] + buf[t] - v;
    if (i < n) { off[i] = excl; cursor[i] = excl; }
    if (i == n - 1) off[n] = excl + v;
}

// writes eid[p] (edge at CSR slot p) and src_csr[p] (source node of slot p)
__global__ void fill_kernel(const int* __restrict__ src, const int* __restrict__ dst,
                            int* __restrict__ cursor, int* __restrict__ eid,
                            int* __restrict__ src_csr, int E) {
    int e = blockIdx.x * 256 + threadIdx.x;
    if (e < E) {
        int p = atomicAdd(&cursor[dst[e]], 1);
        eid[p] = e;
        src_csr[p] = src[e];
    }
}

// ---------------- bf16 conversion / transpose ----------------
__global__ void convert_bf16x8_kernel(const float* __restrict__ in, unsigned short* __restrict__ out,
                                      size_t n_valid, size_t n_total) {
    size_t i = ((size_t)blockIdx.x * 256 + threadIdx.x) * 8;
    if (i >= n_total) return;
    ushort4 o0, o1;
    if (i < n_valid) {
        float4 a = *(const float4*)&in[i];
        float4 b = *(const float4*)&in[i + 4];
        o0.x = f2b(a.x); o0.y = f2b(a.y); o0.z = f2b(a.z); o0.w = f2b(a.w);
        o1.x = f2b(b.x); o1.y = f2b(b.y); o1.z = f2b(b.z); o1.w = f2b(b.w);
    } else {
        o0.x = o0.y = o0.z = o0.w = 0;
        o1 = o0;
    }
    *(ushort4*)&out[i] = o0;
    *(ushort4*)&out[i + 4] = o1;
}

// all 4 weight transposes in one dispatch; every dim is a multiple of 32
__global__ void transpose4_bf16_kernel(const float* __restrict__ lin1, const float* __restrict__ lin2,
                                       const float* __restrict__ w1, const float* __restrict__ w2,
                                       unsigned short* __restrict__ lin1T, unsigned short* __restrict__ lin2T,
                                       unsigned short* __restrict__ w1T, unsigned short* __restrict__ w2T) {
    __shared__ float tile[32][33];
    int b = blockIdx.x;
    const float* in; unsigned short* outp; int K, N, tt;
    if (b < 64)       { in = lin1; outp = lin1T; K = D;  N = D;  tt = b; }
    else if (b < 128) { in = lin2; outp = lin2T; K = D;  N = D;  tt = b - 64; }
    else if (b < 384) { in = w1;   outp = w1T;   K = D;  N = DF; tt = b - 128; }
    else              { in = w2;   outp = w2T;   K = DF; N = D;  tt = b - 384; }
    int ntn = N >> 5;
    int bn = (tt % ntn) * 32, bk = (tt / ntn) * 32;
    int tx = threadIdx.x & 31, ty = threadIdx.x >> 5;
    for (int i = ty; i < 32; i += 8)
        tile[i][tx] = in[(size_t)(bk + i) * N + bn + tx];
    __syncthreads();
    for (int i = ty; i < 32; i += 8)
        outp[(size_t)(bn + i) * K + bk + tx] = f2b(tile[tx][i]);
}

// ---------------- bf16 MFMA GEMM: C = A[MxK] @ BT[NxK]^T (+bias)(+relu) ----------------
// BM x 128 tile, BK=64. BM=128: 2x2 waves of 64x64. BM=64: 1x4 waves of 64x32.
// Optional fused per-head attn projections (xs GEMM): asrc/adst written when a_s != null.
template<int BM>
__global__ __launch_bounds__(256) void mfma_gemm_kernel(
    const unsigned short* __restrict__ A, const unsigned short* __restrict__ BT,
    const float* __restrict__ bias, float* __restrict__ Cf, unsigned short* __restrict__ Cb,
    int M, int Nc, int K, int relu,
    const float* __restrict__ a_s, const float* __restrict__ a_d,
    float* __restrict__ asrcO, float* __restrict__ adstO) {
    constexpr int NR = (BM == 128) ? 4 : 2;
    constexpr int AI = BM / 32;
    __shared__ unsigned short As[BM * 64];
    __shared__ unsigned short Bs[128 * 64];
    int t = threadIdx.x;
    int lane = t & 63, w = t >> 6;
    int gm0 = blockIdx.x * BM, gn0 = blockIdx.y * 128;
    f32x4 acc[4][NR] = {};
    int srow = lane >> 3, scol = (lane & 7) * 8;
    int wm = (BM == 128) ? (w >> 1) * 64 : 0;
    int wn = (BM == 128) ? (w & 1) * 64 : w * 32;
    int fr = lane & 15, fk = (lane >> 4) * 8;

    for (int k0 = 0; k0 < K; k0 += 64) {
        __syncthreads();
#pragma unroll
        for (int i = 0; i < AI; ++i) {
            int rb = w * (8 * AI) + i * 8;
            const unsigned short* ga = A + (size_t)(gm0 + rb + srow) * K + k0 + scol;
            __builtin_amdgcn_global_load_lds(
                (const __attribute__((address_space(1))) unsigned int*)ga,
                (__attribute__((address_space(3))) unsigned int*)&As[rb * 64], 16, 0, 0);
        }
#pragma unroll
        for (int i = 0; i < 4; ++i) {
            int rb = w * 32 + i * 8;
            const unsigned short* gb = BT + (size_t)(gn0 + rb + srow) * K + k0 + scol;
            __builtin_amdgcn_global_load_lds(
                (const __attribute__((address_space(1))) unsigned int*)gb,
                (__attribute__((address_space(3))) unsigned int*)&Bs[rb * 64], 16, 0, 0);
        }
        __syncthreads();
#pragma unroll
        for (int kk = 0; kk < 64; kk += 32) {
            short8 a[4], b[NR];
#pragma unroll
            for (int m = 0; m < 4; ++m)
                a[m] = *(const short8*)&As[(wm + m * 16 + fr) * 64 + kk + fk];
#pragma unroll
            for (int n = 0; n < NR; ++n)
                b[n] = *(const short8*)&Bs[(wn + n * 16 + fr) * 64 + kk + fk];
#pragma unroll
            for (int m = 0; m < 4; ++m)
#pragma unroll
                for (int n = 0; n < NR; ++n)
                    acc[m][n] = __builtin_amdgcn_mfma_f32_16x16x32_bf16(a[m], b[n], acc[m][n], 0, 0, 0);
        }
    }
    int fcol = lane & 15, frow4 = (lane >> 4) * 4;
#pragma unroll
    for (int m = 0; m < 4; ++m) {
#pragma unroll
        for (int i = 0; i < 4; ++i) {
            int gr = gm0 + wm + m * 16 + frow4 + i;
            if (gr >= M) continue;
#pragma unroll
            for (int n = 0; n < NR; ++n) {
                int gc = gn0 + wn + n * 16 + fcol;
                float v = acc[m][n][i];
                if (bias) v += bias[gc];
                if (relu) v = fmaxf(v, 0.f);
                if (Cb) Cb[(size_t)gr * Nc + gc] = f2b(v);
                else    Cf[(size_t)gr * Nc + gc] = v;
            }
        }
    }
    if (BM == 64 && a_s) {
        // wave owns 64 rows x 32 cols = one head
        int head = (gn0 >> 5) + w;
        float as0 = a_s[head * 32 + fcol], as1 = a_s[head * 32 + 16 + fcol];
        float ad0 = a_d[head * 32 + fcol], ad1 = a_d[head * 32 + 16 + fcol];
#pragma unroll
        for (int m = 0; m < 4; ++m) {
#pragma unroll
            for (int i = 0; i < 4; ++i) {
                float vs = acc[m][0][i] * as0 + acc[m][1][i] * as1;
                float vd = acc[m][0][i] * ad0 + acc[m][1][i] * ad1;
#pragma unroll
                for (int o = 1; o < 16; o <<= 1) {
                    vs += __shfl_xor(vs, o);
                    vd += __shfl_xor(vd, o);
                }
                int r = gm0 + m * 16 + frow4 + i;
                if (fcol == 0 && r < M) {
                    asrcO[r * 8 + head] = vs;
                    adstO[r * 8 + head] = vd;
                }
            }
        }
    }
}

// ---------------- edge-attention projection ----------------
// MeT[c][d], c in [0,16): c<8 -> layer1 head c; c>=8 -> layer2 head c-8. bf16.
__global__ void meT_kernel(const float* __restrict__ le1, const float* __restrict__ ae1,
                           const float* __restrict__ le2, const float* __restrict__ ae2,
                           unsigned short* __restrict__ MeT) {
    int t = threadIdx.x;  // 512
    int d = t >> 3, h = t & 7;
    float s1 = 0.f, s2 = 0.f;
    for (int c = 0; c < C; ++c) {
        s1 += le1[d * (H * C) + h * C + c] * ae1[h * C + c];
        s2 += le2[d * (H * C) + h * C + c] * ae2[h * C + c];
    }
    MeT[h * 64 + d] = f2b(s1);
    MeT[(8 + h) * 64 + d] = f2b(s2);
}

// eAe[e][16] = ew[e,:] @ MeT^T via MFMA, edge order (coalesced read+write).
// wave = 16 edges; lane holds A row (lane&15), k = (lane>>4)*8 + j (+kk).
__global__ __launch_bounds__(256) void ealpha_mfma_kernel(const float* __restrict__ ew,
                                                          const unsigned short* __restrict__ MeT,
                                                          float* __restrict__ eAe, int E) {
    int t = threadIdx.x;
    int lane = t & 63, w = t >> 6;
    int e0 = blockIdx.x * 64 + w * 16;
    int r = lane & 15, g = lane >> 4;
    int er = e0 + r; if (er > E - 1) er = E - 1;
    const float* rowp = ew + (size_t)er * DE;
    float4 x0 = *(const float4*)&rowp[g * 8];
    float4 x1 = *(const float4*)&rowp[g * 8 + 4];
    float4 y0 = *(const float4*)&rowp[32 + g * 8];
    float4 y1 = *(const float4*)&rowp[32 + g * 8 + 4];
    short8 a0, a1;
    a0[0] = (short)f2b(x0.x); a0[1] = (short)f2b(x0.y); a0[2] = (short)f2b(x0.z); a0[3] = (short)f2b(x0.w);
    a0[4] = (short)f2b(x1.x); a0[5] = (short)f2b(x1.y); a0[6] = (short)f2b(x1.z); a0[7] = (short)f2b(x1.w);
    a1[0] = (short)f2b(y0.x); a1[1] = (short)f2b(y0.y); a1[2] = (short)f2b(y0.z); a1[3] = (short)f2b(y0.w);
    a1[4] = (short)f2b(y1.x); a1[5] = (short)f2b(y1.y); a1[6] = (short)f2b(y1.z); a1[7] = (short)f2b(y1.w);
    short8 b0 = *(const short8*)&MeT[r * 64 + g * 8];
    short8 b1 = *(const short8*)&MeT[r * 64 + 32 + g * 8];
    f32x4 acc = {};
    acc = __builtin_amdgcn_mfma_f32_16x16x32_bf16(a0, b0, acc, 0, 0, 0);
    acc = __builtin_amdgcn_mfma_f32_16x16x32_bf16(a1, b1, acc, 0, 0, 0);
#pragma unroll
    for (int i = 0; i < 4; ++i) {
        int ee = e0 + g * 4 + i;
        if (ee < E) eAe[(size_t)ee * 16 + r] = acc[i];
    }
}

// CSR permute: read eAe[eid[p]] (random 64B from L2/L3), write eA1c/eA2c coalesced
__global__ void permute_ea_kernel(const float* __restrict__ eAe, const int* __restrict__ eid,
                                  float* __restrict__ eA1c, float* __restrict__ eA2c, int E) {
    int p = blockIdx.x * 256 + threadIdx.x;
    if (p >= E) return;
    int e = eid[p];
    const float4* src = (const float4*)&eAe[(size_t)e * 16];
    float4 v0 = src[0], v1 = src[1], v2 = src[2], v3 = src[3];
    float4* d1 = (float4*)&eA1c[(size_t)p * 8];
    float4* d2 = (float4*)&eA2c[(size_t)p * 8];
    d1[0] = v0; d1[1] = v1;
    d2[0] = v2; d2[1] = v3;
}

// ---------------- GAT: wave-per-node gather + softmax + fused LN/leaky/residual ----------------
// 4 nodes/block (1 wave each). Lane owns features lane*4..lane*4+3 (owner head hw=lane>>3).
// Producer role: slot hw, head h=lane&7. Next-batch src/eA/asrc prefetched one batch ahead.
__global__ __launch_bounds__(256) void gat_node_kernel(
    const int* __restrict__ off, const int* __restrict__ src_csr,
    const float* __restrict__ eAc,
    const float* __restrict__ asrc, const float* __restrict__ adst,
    const unsigned short* __restrict__ xsb, const float* __restrict__ nf_in,
    const float* __restrict__ bias, const float* __restrict__ gamma,
    const float* __restrict__ beta, float* __restrict__ nf_out,
    unsigned short* __restrict__ nf_out_b, int N) {
    int lane = threadIdx.x & 63;
    int n = blockIdx.x * 4 + (threadIdx.x >> 6);
    if (n >= N) return;
    int e0 = off[n], e1 = off[n + 1], deg = e1 - e0;
    int h = lane & 7;
    int hw = lane >> 3;

    float adstn = adst[n * 8 + h];

    float acc0 = 0.f, acc1 = 0.f, acc2 = 0.f, acc3 = 0.f;
    float den0 = 0.f, easum = 0.f;
    int nb8 = (deg + 7) >> 3;

    bool act = hw < deg;
    int sp = e0 + hw;
    int s_cur = act ? src_csr[sp] : n;
    float ea_cur = act ? eAc[(size_t)sp * 8 + h] : 0.f;
    float as_cur = act ? asrc[s_cur * 8 + h] : 0.f;

    for (int it = 0; it < nb8; ++it) {
        int base = it * 8;
        // prefetch next batch (2-deep dependent chain hidden under this batch's gather)
        bool actn = (base + 8 + hw) < deg;
        int spn = e0 + base + 8 + hw;
        int s_nx = actn ? src_csr[spn] : n;
        float ea_nx = actn ? eAc[(size_t)spn * 8 + h] : 0.f;
        float as_nx = actn ? asrc[s_nx * 8 + h] : 0.f;

        float al = as_cur + adstn + ea_cur;
        al = al > 0.f ? al : 0.2f * al;
        float ex = act ? expf(al) : 0.f;
        den0 += ex;
        easum += ea_cur;

        int lim = deg - base; if (lim > 8) lim = 8;
        if (lim == 8) {
#pragma unroll
            for (int kk = 0; kk < 8; ++kk) {
                int sl = kk * 8 + hw;
                float exk = __shfl(ex, sl);
                int sk = __shfl(s_cur, sl);
                ushort4 u = *(const ushort4*)&xsb[(size_t)sk * D + lane * 4];
                acc0 = fmaf(exk, b2f(u.x), acc0);
                acc1 = fmaf(exk, b2f(u.y), acc1);
                acc2 = fmaf(exk, b2f(u.z), acc2);
                acc3 = fmaf(exk, b2f(u.w), acc3);
            }
        } else {
            for (int kk = 0; kk < lim; ++kk) {
                int sl = kk * 8 + hw;
                float exk = __shfl(ex, sl);
                int sk = __shfl(s_cur, sl);
                ushort4 u = *(const ushort4*)&xsb[(size_t)sk * D + lane * 4];
                acc0 = fmaf(exk, b2f(u.x), acc0);
                acc1 = fmaf(exk, b2f(u.y), acc1);
                acc2 = fmaf(exk, b2f(u.z), acc2);
                acc3 = fmaf(exk, b2f(u.w), acc3);
            }
        }
        s_cur = s_nx; ea_cur = ea_nx; as_cur = as_nx; act = actn;
    }
    den0  += __shfl_xor(den0, 8);
    den0  += __shfl_xor(den0, 16);
    den0  += __shfl_xor(den0, 32);
    easum += __shfl_xor(easum, 8);
    easum += __shfl_xor(easum, 16);
    easum += __shfl_xor(easum, 32);
    float sa = easum / (float)(deg > 0 ? deg : 1);
    float als = asrc[n * 8 + h] + adstn + sa;
    als = als > 0.f ? als : 0.2f * als;
    float exSelf = expf(als);
    {
        float exs = __shfl(exSelf, hw);
        ushort4 u = *(const ushort4*)&xsb[(size_t)n * D + lane * 4];
        acc0 = fmaf(exs, b2f(u.x), acc0);
        acc1 = fmaf(exs, b2f(u.y), acc1);
        acc2 = fmaf(exs, b2f(u.z), acc2);
        acc3 = fmaf(exs, b2f(u.w), acc3);
    }
    den0 += exSelf;
    float denOwn = __shfl(den0, hw);
    float inv = 1.f / (denOwn + 1e-16f);

    int t0 = lane * 4;
    float4 bi = *(const float4*)&bias[t0];
    float o0 = acc0 * inv + bi.x;
    float o1 = acc1 * inv + bi.y;
    float o2 = acc2 * inv + bi.z;
    float o3 = acc3 * inv + bi.w;

    float s1 = o0 + o1 + o2 + o3;
    float s2 = o0 * o0 + o1 * o1 + o2 * o2 + o3 * o3;
    for (int o = 1; o < 64; o <<= 1) { s1 += __shfl_xor(s1, o); s2 += __shfl_xor(s2, o); }
    float mu = s1 / 256.f;
    float var = fmaxf((s2 - 256.f * mu * mu) / 255.f, 0.f);
    float sdv = sqrtf(var) + 1e-6f;
    float4 ga = *(const float4*)&gamma[t0];
    float4 be = *(const float4*)&beta[t0];
    float4 nin = *(const float4*)&nf_in[(size_t)n * D + t0];
    float y0 = ga.x * (o0 - mu) / sdv + be.x; y0 = y0 > 0.f ? y0 : 0.01f * y0;
    float y1 = ga.y * (o1 - mu) / sdv + be.y; y1 = y1 > 0.f ? y1 : 0.01f * y1;
    float y2 = ga.z * (o2 - mu) / sdv + be.z; y2 = y2 > 0.f ? y2 : 0.01f * y2;
    float y3 = ga.w * (o3 - mu) / sdv + be.w; y3 = y3 > 0.f ? y3 : 0.01f * y3;
    float r0 = nin.x + y0, r1 = nin.y + y1, r2 = nin.z + y2, r3 = nin.w + y3;
    float4 outv; outv.x = r0; outv.y = r1; outv.z = r2; outv.w = r3;
    *(float4*)&nf_out[(size_t)n * D + t0] = outv;
    ushort4 ob; ob.x = f2b(r0); ob.y = f2b(r1); ob.z = f2b(r2); ob.w = f2b(r3);
    *(ushort4*)&nf_out_b[(size_t)n * D + t0] = ob;
}

// ---------------- FFN epilogue: LN + leaky + residual ----------------
__global__ void ln_residual_kernel(const float* __restrict__ hin, const float* __restrict__ nf_in,
                                   const float* __restrict__ gamma, const float* __restrict__ beta,
                                   float* __restrict__ out) {
    int n = blockIdx.x, t = threadIdx.x;
    float v = hin[(size_t)n * D + t];
    float s1 = v, s2 = v * v;
    for (int o = 1; o < 64; o <<= 1) { s1 += __shfl_xor(s1, o); s2 += __shfl_xor(s2, o); }
    __shared__ float r1[4], r2[4];
    int w = t >> 6;
    if ((t & 63) == 0) { r1[w] = s1; r2[w] = s2; }
    __syncthreads();
    float tot1 = r1[0] + r1[1] + r1[2] + r1[3];
    float tot2 = r2[0] + r2[1] + r2[2] + r2[3];
    float mu = tot1 / (float)D;
    float var = fmaxf((tot2 - (float)D * mu * mu) / (float)(D - 1), 0.f);
    float sd = sqrtf(var) + 1e-6f;
    float y = gamma[t] * (v - mu) / sd + beta[t];
    y = y > 0.f ? y : 0.01f * y;
    out[(size_t)n * D + t] = nf_in[(size_t)n * D + t] + y;
}

extern "C" void kernel_launch(void* const* d_in, const int* in_sizes, int n_in,
                              void* d_out, int out_size, void* d_ws, size_t ws_size,
                              hipStream_t stream) {
    const float* nf0    = (const float*)d_in[0];
    const int*   ei     = (const int*)d_in[1];
    const float* ew     = (const float*)d_in[2];
    const float* lin1   = (const float*)d_in[3];
    const float* le1    = (const float*)d_in[4];
    const float* asrc1w = (const float*)d_in[5];
    const float* adst1w = (const float*)d_in[6];
    const float* aedge1 = (const float*)d_in[7];
    const float* b1     = (const float*)d_in[8];
    const float* lin2   = (const float*)d_in[9];
    const float* le2    = (const float*)d_in[10];
    const float* asrc2w = (const float*)d_in[11];
    const float* adst2w = (const float*)d_in[12];
    const float* aedge2 = (const float*)d_in[13];
    const float* b2     = (const float*)d_in[14];
    const float* g1     = (const float*)d_in[15];
    const float* be1    = (const float*)d_in[16];
    const float* g2     = (const float*)d_in[17];
    const float* be2    = (const float*)d_in[18];
    const float* g3     = (const float*)d_in[19];
    const float* be3    = (const float*)d_in[20];
    const float* w1     = (const float*)d_in[21];
    const float* fb1    = (const float*)d_in[22];
    const float* w2     = (const float*)d_in[23];
    const float* fb2    = (const float*)d_in[24];

    const int N = in_sizes[0] / D;
    const int E = in_sizes[1] / 2;
    const int Mpad = ((N + 127) / 128) * 128;
    const int* srcI = ei;
    const int* dstI = ei + E;

    char* ws = (char*)d_ws;
    size_t ob = 0;
    auto alloc = [&](size_t bytes) { void* p = ws + ob; ob = align_up(ob + bytes, 256); return p; };
    // --- arena0: dead after GAT layer 2; start reused as FFN hidden (bf16, Mpad*DF*2 = 20.7MB) ---
    int*   deg     = (int*)alloc((size_t)N * 4);
    int*   csr_off = (int*)alloc((size_t)(N + 1) * 4);
    int*   cursor  = (int*)alloc((size_t)N * 4);
    int*   part    = (int*)alloc(1024);
    int*   eid     = (int*)alloc((size_t)E * 4);
    int*   src_csr = (int*)alloc((size_t)E * 4);
    unsigned short* MeT = (unsigned short*)alloc(16 * 64 * 2);
    float* asrcB   = (float*)alloc((size_t)N * H * 4);
    float* adstB   = (float*)alloc((size_t)N * H * 4);
    float* eAe     = (float*)alloc((size_t)E * 16 * 4);
    float* eA1c    = (float*)alloc((size_t)E * H * 4);
    float* eA2c    = (float*)alloc((size_t)E * H * 4);
    // --- persistent ---
    float* xsf     = (float*)alloc((size_t)Mpad * D * 4);  // FFN output (fp32)
    float* nfw     = (float*)alloc((size_t)N * D * 4);
    unsigned short* xs_b  = (unsigned short*)alloc((size_t)Mpad * D * 2);
    unsigned short* Abf   = (unsigned short*)alloc((size_t)Mpad * D * 2);
    unsigned short* lin1T = (unsigned short*)alloc((size_t)D * D * 2);
    unsigned short* lin2T = (unsigned short*)alloc((size_t)D * D * 2);
    unsigned short* w1T   = (unsigned short*)alloc((size_t)DF * D * 2);
    unsigned short* w2T   = (unsigned short*)alloc((size_t)D * DF * 2);
    unsigned short* hidden = (unsigned short*)ws;  // aliases arena0 (dead by FFN)
    (void)ws_size;
    float* out = (float*)d_out;

    hipMemsetAsync(deg, 0, (size_t)N * 4, stream);

    int eb = (E + 255) / 256;
    int nb = (N + 255) / 256;
    deg_kernel<<<eb, 256, 0, stream>>>(dstI, deg, E);
    partial_sum_kernel<<<nb, 256, 0, stream>>>(deg, part, N);
    scan_part_kernel<<<1, 256, 0, stream>>>(part, nb);
    scan_final_kernel<<<nb, 256, 0, stream>>>(deg, part, csr_off, cursor, N);
    fill_kernel<<<eb, 256, 0, stream>>>(srcI, dstI, cursor, eid, src_csr, E);

    meT_kernel<<<1, 512, 0, stream>>>(le1, aedge1, le2, aedge2, MeT);
    ealpha_mfma_kernel<<<(E + 63) / 64, 256, 0, stream>>>(ew, MeT, eAe, E);
    permute_ea_kernel<<<eb, 256, 0, stream>>>(eAe, eid, eA1c, eA2c, E);

    transpose4_bf16_kernel<<<640, 256, 0, stream>>>(lin1, lin2, w1, w2, lin1T, lin2T, w1T, w2T);

    const size_t nvalid = (size_t)N * D, ntot = (size_t)Mpad * D;
    int cb = (int)((ntot / 8 + 255) / 256);
    int gatb = (N + 3) / 4;

    // ---- GAT layer 1 ----
    convert_bf16x8_kernel<<<cb, 256, 0, stream>>>(nf0, Abf, nvalid, ntot);
    mfma_gemm_kernel<64><<<dim3(Mpad / 64, 2), 256, 0, stream>>>(
        Abf, lin1T, nullptr, nullptr, xs_b, N, D, D, 0, asrc1w, adst1w, asrcB, adstB);
    gat_node_kernel<<<gatb, 256, 0, stream>>>(csr_off, src_csr, eA1c, asrcB, adstB,
                                              xs_b, nf0, b1, g1, be1, nfw, Abf, N);
    // ---- GAT layer 2 ----
    mfma_gemm_kernel<64><<<dim3(Mpad / 64, 2), 256, 0, stream>>>(
        Abf, lin2T, nullptr, nullptr, xs_b, N, D, D, 0, asrc2w, adst2w, asrcB, adstB);
    gat_node_kernel<<<gatb, 256, 0, stream>>>(csr_off, src_csr, eA2c, asrcB, adstB,
                                              xs_b, nfw, b2, g2, be2, nfw, Abf, N);
    // ---- FFN ----
    mfma_gemm_kernel<128><<<dim3(Mpad / 128, 8), 256, 0, stream>>>(
        Abf, w1T, fb1, nullptr, hidden, N, DF, D, 1, nullptr, nullptr, nullptr, nullptr);
    mfma_gemm_kernel<64><<<dim3(Mpad / 64, 2), 256, 0, stream>>>(
        hidden, w2T, fb2, xsf, nullptr, N, D, DF, 0, nullptr, nullptr, nullptr, nullptr);
    ln_residual_kernel<<<N, 256, 0, stream>>>(xsf, nfw, g3, be3, out);
}

// Round 6
// 259.443 us; speedup vs baseline: 2.0857x; 1.0140x over previous
//
#include <hip/hip_runtime.h>
#include <hip/hip_bf16.h>
#include <math.h>

#define D 256
#define H 8
#define C 32
#define DE 64
#define DF 1024

static inline size_t align_up(size_t x, size_t a) { return (x + a - 1) / a * a; }

typedef __attribute__((ext_vector_type(8))) short short8;
typedef __attribute__((ext_vector_type(4))) float f32x4;

__device__ inline unsigned short f2b(float x) {
    __hip_bfloat16 h = __float2bfloat16(x);
    return *reinterpret_cast<unsigned short*>(&h);
}
__device__ inline float b2f(unsigned short u) {
    return __uint_as_float(((unsigned int)u) << 16);
}

// ---------------- CSR build ----------------
__global__ void deg_kernel(const int* __restrict__ dst, int* __restrict__ deg, int E) {
    int e = blockIdx.x * 256 + threadIdx.x;
    if (e < E) atomicAdd(&deg[dst[e]], 1);
}

__global__ void partial_sum_kernel(const int* __restrict__ deg, int* __restrict__ part, int n) {
    int i = blockIdx.x * 256 + threadIdx.x;
    int v = (i < n) ? deg[i] : 0;
    for (int o = 1; o < 64; o <<= 1) v += __shfl_xor(v, o);
    __shared__ int w4[4];
    if ((threadIdx.x & 63) == 0) w4[threadIdx.x >> 6] = v;
    __syncthreads();
    if (threadIdx.x == 0) part[blockIdx.x] = w4[0] + w4[1] + w4[2] + w4[3];
}

__global__ void scan_part_kernel(int* __restrict__ part, int nb) {
    __shared__ int buf[256];
    int t = threadIdx.x;
    buf[t] = (t < nb) ? part[t] : 0;
    __syncthreads();
    for (int s = 1; s < 256; s <<= 1) {
        int v = (t >= s) ? buf[t - s] : 0;
        __syncthreads();
        buf[t] += v;
        __syncthreads();
    }
    int excl = (t == 0) ? 0 : buf[t - 1];
    if (t < nb) part[t] = excl;
}

__global__ void scan_final_kernel(const int* __restrict__ deg, const int* __restrict__ part,
                                  int* __restrict__ off, int* __restrict__ cursor, int n) {
    int b = blockIdx.x, t = threadIdx.x, i = b * 256 + t;
    __shared__ int buf[256];
    int v = (i < n) ? deg[i] : 0;
    buf[t] = v;
    __syncthreads();
    for (int s = 1; s < 256; s <<= 1) {
        int x = (t >= s) ? buf[t - s] : 0;
        __syncthreads();
        buf[t] += x;
        __syncthreads();
    }
    int excl = part[b] + buf[t] - v;
    if (i < n) { off[i] = excl; cursor[i] = excl; }
    if (i == n - 1) off[n] = excl + v;
}

// writes eid[p] (edge at CSR slot p) and src_csr[p] (source node of slot p)
__global__ void fill_kernel(const int* __restrict__ src, const int* __restrict__ dst,
                            int* __restrict__ cursor, int* __restrict__ eid,
                            int* __restrict__ src_csr, int E) {
    int e = blockIdx.x * 256 + threadIdx.x;
    if (e < E) {
        int p = atomicAdd(&cursor[dst[e]], 1);
        eid[p] = e;
        src_csr[p] = src[e];
    }
}

// ---------------- bf16 conversion / transpose ----------------
__global__ void convert_bf16x8_kernel(const float* __restrict__ in, unsigned short* __restrict__ out,
                                      size_t n_valid, size_t n_total) {
    size_t i = ((size_t)blockIdx.x * 256 + threadIdx.x) * 8;
    if (i >= n_total) return;
    ushort4 o0, o1;
    if (i < n_valid) {
        float4 a = *(const float4*)&in[i];
        float4 b = *(const float4*)&in[i + 4];
        o0.x = f2b(a.x); o0.y = f2b(a.y); o0.z = f2b(a.z); o0.w = f2b(a.w);
        o1.x = f2b(b.x); o1.y = f2b(b.y); o1.z = f2b(b.z); o1.w = f2b(b.w);
    } else {
        o0.x = o0.y = o0.z = o0.w = 0;
        o1 = o0;
    }
    *(ushort4*)&out[i] = o0;
    *(ushort4*)&out[i + 4] = o1;
}

// all 4 weight transposes + MeT build in one dispatch
__global__ void transpose4_bf16_kernel(const float* __restrict__ lin1, const float* __restrict__ lin2,
                                       const float* __restrict__ w1, const float* __restrict__ w2,
                                       const float* __restrict__ le1, const float* __restrict__ ae1,
                                       const float* __restrict__ le2, const float* __restrict__ ae2,
                                       unsigned short* __restrict__ lin1T, unsigned short* __restrict__ lin2T,
                                       unsigned short* __restrict__ w1T, unsigned short* __restrict__ w2T,
                                       unsigned short* __restrict__ MeT) {
    int b = blockIdx.x;
    if (b == 640) {  // MeT[c][d]: c<8 -> layer1 head c; c>=8 -> layer2 head c-8
        for (int t = threadIdx.x; t < 512; t += 256) {
            int d = t >> 3, h = t & 7;
            float s1 = 0.f, s2 = 0.f;
            for (int c = 0; c < C; ++c) {
                s1 += le1[d * (H * C) + h * C + c] * ae1[h * C + c];
                s2 += le2[d * (H * C) + h * C + c] * ae2[h * C + c];
            }
            MeT[h * 64 + d] = f2b(s1);
            MeT[(8 + h) * 64 + d] = f2b(s2);
        }
        return;
    }
    __shared__ float tile[32][33];
    const float* in; unsigned short* outp; int K, N, tt;
    if (b < 64)       { in = lin1; outp = lin1T; K = D;  N = D;  tt = b; }
    else if (b < 128) { in = lin2; outp = lin2T; K = D;  N = D;  tt = b - 64; }
    else if (b < 384) { in = w1;   outp = w1T;   K = D;  N = DF; tt = b - 128; }
    else              { in = w2;   outp = w2T;   K = DF; N = D;  tt = b - 384; }
    int ntn = N >> 5;
    int bn = (tt % ntn) * 32, bk = (tt / ntn) * 32;
    int tx = threadIdx.x & 31, ty = threadIdx.x >> 5;
    for (int i = ty; i < 32; i += 8)
        tile[i][tx] = in[(size_t)(bk + i) * N + bn + tx];
    __syncthreads();
    for (int i = ty; i < 32; i += 8)
        outp[(size_t)(bn + i) * K + bk + tx] = f2b(tile[tx][i]);
}

// ---------------- bf16 MFMA GEMM: C = A[MxK] @ BT[NxK]^T (+bias)(+relu) ----------------
// BM x 128 tile, BK=64. BM=128: 2x2 waves of 64x64. BM=64: 1x4 waves of 64x32.
// Optional fused per-head attn projections (xs GEMM): asrc/adst written when a_s != null.
template<int BM>
__global__ __launch_bounds__(256) void mfma_gemm_kernel(
    const unsigned short* __restrict__ A, const unsigned short* __restrict__ BT,
    const float* __restrict__ bias, float* __restrict__ Cf, unsigned short* __restrict__ Cb,
    int M, int Nc, int K, int relu,
    const float* __restrict__ a_s, const float* __restrict__ a_d,
    float* __restrict__ asrcO, float* __restrict__ adstO) {
    constexpr int NR = (BM == 128) ? 4 : 2;
    constexpr int AI = BM / 32;
    __shared__ unsigned short As[BM * 64];
    __shared__ unsigned short Bs[128 * 64];
    int t = threadIdx.x;
    int lane = t & 63, w = t >> 6;
    int gm0 = blockIdx.x * BM, gn0 = blockIdx.y * 128;
    f32x4 acc[4][NR] = {};
    int srow = lane >> 3, scol = (lane & 7) * 8;
    int wm = (BM == 128) ? (w >> 1) * 64 : 0;
    int wn = (BM == 128) ? (w & 1) * 64 : w * 32;
    int fr = lane & 15, fk = (lane >> 4) * 8;

    for (int k0 = 0; k0 < K; k0 += 64) {
        __syncthreads();
#pragma unroll
        for (int i = 0; i < AI; ++i) {
            int rb = w * (8 * AI) + i * 8;
            const unsigned short* ga = A + (size_t)(gm0 + rb + srow) * K + k0 + scol;
            __builtin_amdgcn_global_load_lds(
                (const __attribute__((address_space(1))) unsigned int*)ga,
                (__attribute__((address_space(3))) unsigned int*)&As[rb * 64], 16, 0, 0);
        }
#pragma unroll
        for (int i = 0; i < 4; ++i) {
            int rb = w * 32 + i * 8;
            const unsigned short* gb = BT + (size_t)(gn0 + rb + srow) * K + k0 + scol;
            __builtin_amdgcn_global_load_lds(
                (const __attribute__((address_space(1))) unsigned int*)gb,
                (__attribute__((address_space(3))) unsigned int*)&Bs[rb * 64], 16, 0, 0);
        }
        __syncthreads();
#pragma unroll
        for (int kk = 0; kk < 64; kk += 32) {
            short8 a[4], b[NR];
#pragma unroll
            for (int m = 0; m < 4; ++m)
                a[m] = *(const short8*)&As[(wm + m * 16 + fr) * 64 + kk + fk];
#pragma unroll
            for (int n = 0; n < NR; ++n)
                b[n] = *(const short8*)&Bs[(wn + n * 16 + fr) * 64 + kk + fk];
#pragma unroll
            for (int m = 0; m < 4; ++m)
#pragma unroll
                for (int n = 0; n < NR; ++n)
                    acc[m][n] = __builtin_amdgcn_mfma_f32_16x16x32_bf16(a[m], b[n], acc[m][n], 0, 0, 0);
        }
    }
    int fcol = lane & 15, frow4 = (lane >> 4) * 4;
#pragma unroll
    for (int m = 0; m < 4; ++m) {
#pragma unroll
        for (int i = 0; i < 4; ++i) {
            int gr = gm0 + wm + m * 16 + frow4 + i;
            if (gr >= M) continue;
#pragma unroll
            for (int n = 0; n < NR; ++n) {
                int gc = gn0 + wn + n * 16 + fcol;
                float v = acc[m][n][i];
                if (bias) v += bias[gc];
                if (relu) v = fmaxf(v, 0.f);
                if (Cb) Cb[(size_t)gr * Nc + gc] = f2b(v);
                else    Cf[(size_t)gr * Nc + gc] = v;
            }
        }
    }
    if (BM == 64 && a_s) {
        // wave owns 64 rows x 32 cols = one head
        int head = (gn0 >> 5) + w;
        float as0 = a_s[head * 32 + fcol], as1 = a_s[head * 32 + 16 + fcol];
        float ad0 = a_d[head * 32 + fcol], ad1 = a_d[head * 32 + 16 + fcol];
#pragma unroll
        for (int m = 0; m < 4; ++m) {
#pragma unroll
            for (int i = 0; i < 4; ++i) {
                float vs = acc[m][0][i] * as0 + acc[m][1][i] * as1;
                float vd = acc[m][0][i] * ad0 + acc[m][1][i] * ad1;
#pragma unroll
                for (int o = 1; o < 16; o <<= 1) {
                    vs += __shfl_xor(vs, o);
                    vd += __shfl_xor(vd, o);
                }
                int r = gm0 + m * 16 + frow4 + i;
                if (fcol == 0 && r < M) {
                    asrcO[r * 8 + head] = vs;
                    adstO[r * 8 + head] = vd;
                }
            }
        }
    }
}

// ---------------- FFN2 + LN + leaky + residual, fully fused ----------------
// BM=64 x BN=256 (full row). 4 waves, wave w owns cols w*64..w*64+63, all 64 rows.
__global__ __launch_bounds__(256) void ffn2_ln_kernel(
    const unsigned short* __restrict__ A, const unsigned short* __restrict__ BT,
    const float* __restrict__ bias, const float* __restrict__ nf_in,
    const float* __restrict__ gamma, const float* __restrict__ beta,
    float* __restrict__ out, int M) {
    __shared__ unsigned short As[64 * 64];
    __shared__ unsigned short Bs[256 * 64];
    __shared__ float redS1[4][64], redS2[4][64];
    __shared__ float muS[64], invS[64];
    int t = threadIdx.x, lane = t & 63, w = t >> 6;
    int gm0 = blockIdx.x * 64;
    f32x4 acc[4][4] = {};
    int srow = lane >> 3, scol = (lane & 7) * 8;
    int wn = w * 64;
    int fr = lane & 15, fk = (lane >> 4) * 8;
    for (int k0 = 0; k0 < DF; k0 += 64) {
        __syncthreads();
#pragma unroll
        for (int i = 0; i < 2; ++i) {
            int rb = w * 16 + i * 8;
            const unsigned short* ga = A + (size_t)(gm0 + rb + srow) * DF + k0 + scol;
            __builtin_amdgcn_global_load_lds(
                (const __attribute__((address_space(1))) unsigned int*)ga,
                (__attribute__((address_space(3))) unsigned int*)&As[rb * 64], 16, 0, 0);
        }
#pragma unroll
        for (int i = 0; i < 8; ++i) {
            int rb = w * 64 + i * 8;
            const unsigned short* gb = BT + (size_t)(rb + srow) * DF + k0 + scol;
            __builtin_amdgcn_global_load_lds(
                (const __attribute__((address_space(1))) unsigned int*)gb,
                (__attribute__((address_space(3))) unsigned int*)&Bs[rb * 64], 16, 0, 0);
        }
        __syncthreads();
#pragma unroll
        for (int kk = 0; kk < 64; kk += 32) {
            short8 a[4], b[4];
#pragma unroll
            for (int m = 0; m < 4; ++m)
                a[m] = *(const short8*)&As[(m * 16 + fr) * 64 + kk + fk];
#pragma unroll
            for (int n = 0; n < 4; ++n)
                b[n] = *(const short8*)&Bs[(wn + n * 16 + fr) * 64 + kk + fk];
#pragma unroll
            for (int m = 0; m < 4; ++m)
#pragma unroll
                for (int n = 0; n < 4; ++n)
                    acc[m][n] = __builtin_amdgcn_mfma_f32_16x16x32_bf16(a[m], b[n], acc[m][n], 0, 0, 0);
        }
    }
    int fcol = lane & 15, frow4 = (lane >> 4) * 4;
#pragma unroll
    for (int m = 0; m < 4; ++m) {
#pragma unroll
        for (int i = 0; i < 4; ++i) {
            float vs1 = 0.f, vs2 = 0.f;
#pragma unroll
            for (int n = 0; n < 4; ++n) {
                float vv = acc[m][n][i] + bias[wn + n * 16 + fcol];
                acc[m][n][i] = vv;
                vs1 += vv; vs2 += vv * vv;
            }
#pragma unroll
            for (int o = 1; o < 16; o <<= 1) {
                vs1 += __shfl_xor(vs1, o);
                vs2 += __shfl_xor(vs2, o);
            }
            if (fcol == 0) {
                redS1[w][m * 16 + frow4 + i] = vs1;
                redS2[w][m * 16 + frow4 + i] = vs2;
            }
        }
    }
    __syncthreads();
    if (t < 64) {
        float s1 = redS1[0][t] + redS1[1][t] + redS1[2][t] + redS1[3][t];
        float s2 = redS2[0][t] + redS2[1][t] + redS2[2][t] + redS2[3][t];
        float mu = s1 / 256.f;
        float var = fmaxf((s2 - 256.f * mu * mu) / 255.f, 0.f);
        muS[t] = mu;
        invS[t] = 1.f / (sqrtf(var) + 1e-6f);
    }
    __syncthreads();
#pragma unroll
    for (int m = 0; m < 4; ++m) {
#pragma unroll
        for (int i = 0; i < 4; ++i) {
            int r = m * 16 + frow4 + i;
            int gr = gm0 + r;
            if (gr >= M) continue;
            float mu = muS[r], inv = invS[r];
#pragma unroll
            for (int n = 0; n < 4; ++n) {
                int gc = wn + n * 16 + fcol;
                float y = gamma[gc] * (acc[m][n][i] - mu) * inv + beta[gc];
                y = y > 0.f ? y : 0.01f * y;
                out[(size_t)gr * D + gc] = nf_in[(size_t)gr * D + gc] + y;
            }
        }
    }
}

// ---------------- edge-attention projection ----------------
// eAe[e][16] = ew[e,:] @ MeT^T via MFMA, edge order (coalesced read+write).
__global__ __launch_bounds__(256) void ealpha_mfma_kernel(const float* __restrict__ ew,
                                                          const unsigned short* __restrict__ MeT,
                                                          float* __restrict__ eAe, int E) {
    int t = threadIdx.x;
    int lane = t & 63, w = t >> 6;
    int e0 = blockIdx.x * 64 + w * 16;
    int r = lane & 15, g = lane >> 4;
    int er = e0 + r; if (er > E - 1) er = E - 1;
    const float* rowp = ew + (size_t)er * DE;
    float4 x0 = *(const float4*)&rowp[g * 8];
    float4 x1 = *(const float4*)&rowp[g * 8 + 4];
    float4 y0 = *(const float4*)&rowp[32 + g * 8];
    float4 y1 = *(const float4*)&rowp[32 + g * 8 + 4];
    short8 a0, a1;
    a0[0] = (short)f2b(x0.x); a0[1] = (short)f2b(x0.y); a0[2] = (short)f2b(x0.z); a0[3] = (short)f2b(x0.w);
    a0[4] = (short)f2b(x1.x); a0[5] = (short)f2b(x1.y); a0[6] = (short)f2b(x1.z); a0[7] = (short)f2b(x1.w);
    a1[0] = (short)f2b(y0.x); a1[1] = (short)f2b(y0.y); a1[2] = (short)f2b(y0.z); a1[3] = (short)f2b(y0.w);
    a1[4] = (short)f2b(y1.x); a1[5] = (short)f2b(y1.y); a1[6] = (short)f2b(y1.z); a1[7] = (short)f2b(y1.w);
    short8 b0 = *(const short8*)&MeT[r * 64 + g * 8];
    short8 b1 = *(const short8*)&MeT[r * 64 + 32 + g * 8];
    f32x4 acc = {};
    acc = __builtin_amdgcn_mfma_f32_16x16x32_bf16(a0, b0, acc, 0, 0, 0);
    acc = __builtin_amdgcn_mfma_f32_16x16x32_bf16(a1, b1, acc, 0, 0, 0);
#pragma unroll
    for (int i = 0; i < 4; ++i) {
        int ee = e0 + g * 4 + i;
        if (ee < E) eAe[(size_t)ee * 16 + r] = acc[i];
    }
}

// CSR permute: read eAe[eid[p]] (random 64B from L2/L3), write eA1c/eA2c coalesced
__global__ void permute_ea_kernel(const float* __restrict__ eAe, const int* __restrict__ eid,
                                  float* __restrict__ eA1c, float* __restrict__ eA2c, int E) {
    int p = blockIdx.x * 256 + threadIdx.x;
    if (p >= E) return;
    int e = eid[p];
    const float4* src = (const float4*)&eAe[(size_t)e * 16];
    float4 v0 = src[0], v1 = src[1], v2 = src[2], v3 = src[3];
    float4* d1 = (float4*)&eA1c[(size_t)p * 8];
    float4* d2 = (float4*)&eA2c[(size_t)p * 8];
    d1[0] = v0; d1[1] = v1;
    d2[0] = v2; d2[1] = v3;
}

// ---------------- GAT: wave-per-node gather + softmax + fused LN/leaky/residual ----------------
// 4 nodes/block (1 wave each). Lane owns features lane*4..lane*4+3.
// Producer role: slots hw and hw+8 (16 edges/iter), head h=lane&7; next batch prefetched.
__global__ __launch_bounds__(256) void gat_node_kernel(
    const int* __restrict__ off, const int* __restrict__ src_csr,
    const float* __restrict__ eAc,
    const float* __restrict__ asrc, const float* __restrict__ adst,
    const unsigned short* __restrict__ xsb, const float* __restrict__ nf_in,
    const float* __restrict__ bias, const float* __restrict__ gamma,
    const float* __restrict__ beta, float* __restrict__ nf_out,
    unsigned short* __restrict__ nf_out_b, int N) {
    int lane = threadIdx.x & 63;
    int n = blockIdx.x * 4 + (threadIdx.x >> 6);
    if (n >= N) return;
    int e0 = off[n], e1 = off[n + 1], deg = e1 - e0;
    int h = lane & 7;
    int hw = lane >> 3;

    float adstn = adst[n * 8 + h];

    float acc0 = 0.f, acc1 = 0.f, acc2 = 0.f, acc3 = 0.f;
    float den0 = 0.f, easum = 0.f;
    int nb16 = (deg + 15) >> 4;

    bool actA = hw < deg, actB = (8 + hw) < deg;
    int spA = e0 + hw, spB = e0 + 8 + hw;
    int sA = actA ? src_csr[spA] : n;
    int sB = actB ? src_csr[spB] : n;
    float eaA = actA ? eAc[(size_t)spA * 8 + h] : 0.f;
    float eaB = actB ? eAc[(size_t)spB * 8 + h] : 0.f;
    float asA = actA ? asrc[sA * 8 + h] : 0.f;
    float asB = actB ? asrc[sB * 8 + h] : 0.f;

    for (int it = 0; it < nb16; ++it) {
        int base = it * 16;
        // prefetch next batch
        bool actAn = (base + 16 + hw) < deg, actBn = (base + 24 + hw) < deg;
        int spAn = e0 + base + 16 + hw, spBn = e0 + base + 24 + hw;
        int sAn = actAn ? src_csr[spAn] : n;
        int sBn = actBn ? src_csr[spBn] : n;
        float eaAn = actAn ? eAc[(size_t)spAn * 8 + h] : 0.f;
        float eaBn = actBn ? eAc[(size_t)spBn * 8 + h] : 0.f;
        float asAn = actAn ? asrc[sAn * 8 + h] : 0.f;
        float asBn = actBn ? asrc[sBn * 8 + h] : 0.f;

        float alA = asA + adstn + eaA;
        alA = alA > 0.f ? alA : 0.2f * alA;
        float exA = actA ? expf(alA) : 0.f;
        float alB = asB + adstn + eaB;
        alB = alB > 0.f ? alB : 0.2f * alB;
        float exB = actB ? expf(alB) : 0.f;
        den0 += exA + exB;
        easum += eaA + eaB;

        int lim = deg - base; if (lim > 16) lim = 16;
        if (lim == 16) {
#pragma unroll
            for (int kk = 0; kk < 16; ++kk) {
                int sl = (kk & 7) * 8 + hw;
                float exk = (kk < 8) ? __shfl(exA, sl) : __shfl(exB, sl);
                int sk = (kk < 8) ? __shfl(sA, sl) : __shfl(sB, sl);
                ushort4 u = *(const ushort4*)&xsb[(size_t)sk * D + lane * 4];
                acc0 = fmaf(exk, b2f(u.x), acc0);
                acc1 = fmaf(exk, b2f(u.y), acc1);
                acc2 = fmaf(exk, b2f(u.z), acc2);
                acc3 = fmaf(exk, b2f(u.w), acc3);
            }
        } else {
            for (int kk = 0; kk < lim; ++kk) {
                int sl = (kk & 7) * 8 + hw;
                float exk = (kk < 8) ? __shfl(exA, sl) : __shfl(exB, sl);
                int sk = (kk < 8) ? __shfl(sA, sl) : __shfl(sB, sl);
                ushort4 u = *(const ushort4*)&xsb[(size_t)sk * D + lane * 4];
                acc0 = fmaf(exk, b2f(u.x), acc0);
                acc1 = fmaf(exk, b2f(u.y), acc1);
                acc2 = fmaf(exk, b2f(u.z), acc2);
                acc3 = fmaf(exk, b2f(u.w), acc3);
            }
        }
        sA = sAn; sB = sBn; eaA = eaAn; eaB = eaBn; asA = asAn; asB = asBn;
        actA = actAn; actB = actBn;
    }
    den0  += __shfl_xor(den0, 8);
    den0  += __shfl_xor(den0, 16);
    den0  += __shfl_xor(den0, 32);
    easum += __shfl_xor(easum, 8);
    easum += __shfl_xor(easum, 16);
    easum += __shfl_xor(easum, 32);
    float sa = easum / (float)(deg > 0 ? deg : 1);
    float als = asrc[n * 8 + h] + adstn + sa;
    als = als > 0.f ? als : 0.2f * als;
    float exSelf = expf(als);
    {
        float exs = __shfl(exSelf, hw);
        ushort4 u = *(const ushort4*)&xsb[(size_t)n * D + lane * 4];
        acc0 = fmaf(exs, b2f(u.x), acc0);
        acc1 = fmaf(exs, b2f(u.y), acc1);
        acc2 = fmaf(exs, b2f(u.z), acc2);
        acc3 = fmaf(exs, b2f(u.w), acc3);
    }
    den0 += exSelf;
    float denOwn = __shfl(den0, hw);
    float inv = 1.f / (denOwn + 1e-16f);

    int t0 = lane * 4;
    float4 bi = *(const float4*)&bias[t0];
    float o0 = acc0 * inv + bi.x;
    float o1 = acc1 * inv + bi.y;
    float o2 = acc2 * inv + bi.z;
    float o3 = acc3 * inv + bi.w;

    float s1 = o0 + o1 + o2 + o3;
    float s2 = o0 * o0 + o1 * o1 + o2 * o2 + o3 * o3;
    for (int o = 1; o < 64; o <<= 1) { s1 += __shfl_xor(s1, o); s2 += __shfl_xor(s2, o); }
    float mu = s1 / 256.f;
    float var = fmaxf((s2 - 256.f * mu * mu) / 255.f, 0.f);
    float sdv = sqrtf(var) + 1e-6f;
    float4 ga = *(const float4*)&gamma[t0];
    float4 be = *(const float4*)&beta[t0];
    float4 nin = *(const float4*)&nf_in[(size_t)n * D + t0];
    float y0 = ga.x * (o0 - mu) / sdv + be.x; y0 = y0 > 0.f ? y0 : 0.01f * y0;
    float y1 = ga.y * (o1 - mu) / sdv + be.y; y1 = y1 > 0.f ? y1 : 0.01f * y1;
    float y2 = ga.z * (o2 - mu) / sdv + be.z; y2 = y2 > 0.f ? y2 : 0.01f * y2;
    float y3 = ga.w * (o3 - mu) / sdv + be.w; y3 = y3 > 0.f ? y3 : 0.01f * y3;
    float r0 = nin.x + y0, r1 = nin.y + y1, r2 = nin.z + y2, r3 = nin.w + y3;
    float4 outv; outv.x = r0; outv.y = r1; outv.z = r2; outv.w = r3;
    *(float4*)&nf_out[(size_t)n * D + t0] = outv;
    ushort4 ob; ob.x = f2b(r0); ob.y = f2b(r1); ob.z = f2b(r2); ob.w = f2b(r3);
    *(ushort4*)&nf_out_b[(size_t)n * D + t0] = ob;
}

extern "C" void kernel_launch(void* const* d_in, const int* in_sizes, int n_in,
                              void* d_out, int out_size, void* d_ws, size_t ws_size,
                              hipStream_t stream) {
    const float* nf0    = (const float*)d_in[0];
    const int*   ei     = (const int*)d_in[1];
    const float* ew     = (const float*)d_in[2];
    const float* lin1   = (const float*)d_in[3];
    const float* le1    = (const float*)d_in[4];
    const float* asrc1w = (const float*)d_in[5];
    const float* adst1w = (const float*)d_in[6];
    const float* aedge1 = (const float*)d_in[7];
    const float* b1     = (const float*)d_in[8];
    const float* lin2   = (const float*)d_in[9];
    const float* le2    = (const float*)d_in[10];
    const float* asrc2w = (const float*)d_in[11];
    const float* adst2w = (const float*)d_in[12];
    const float* aedge2 = (const float*)d_in[13];
    const float* b2     = (const float*)d_in[14];
    const float* g1     = (const float*)d_in[15];
    const float* be1    = (const float*)d_in[16];
    const float* g2     = (const float*)d_in[17];
    const float* be2    = (const float*)d_in[18];
    const float* g3     = (const float*)d_in[19];
    const float* be3    = (const float*)d_in[20];
    const float* w1     = (const float*)d_in[21];
    const float* fb1    = (const float*)d_in[22];
    const float* w2     = (const float*)d_in[23];
    const float* fb2    = (const float*)d_in[24];

    const int N = in_sizes[0] / D;
    const int E = in_sizes[1] / 2;
    const int Mpad = ((N + 127) / 128) * 128;
    const int* srcI = ei;
    const int* dstI = ei + E;

    char* ws = (char*)d_ws;
    size_t ob = 0;
    auto alloc = [&](size_t bytes) { void* p = ws + ob; ob = align_up(ob + bytes, 256); return p; };
    // --- arena0: dead after GAT layer 2; start reused as FFN hidden (bf16, Mpad*DF*2 = 20.7MB) ---
    int*   deg     = (int*)alloc((size_t)N * 4);
    int*   csr_off = (int*)alloc((size_t)(N + 1) * 4);
    int*   cursor  = (int*)alloc((size_t)N * 4);
    int*   part    = (int*)alloc(1024);
    int*   eid     = (int*)alloc((size_t)E * 4);
    int*   src_csr = (int*)alloc((size_t)E * 4);
    unsigned short* MeT = (unsigned short*)alloc(16 * 64 * 2);
    float* asrcB   = (float*)alloc((size_t)N * H * 4);
    float* adstB   = (float*)alloc((size_t)N * H * 4);
    float* eAe     = (float*)alloc((size_t)E * 16 * 4);
    float* eA1c    = (float*)alloc((size_t)E * H * 4);
    float* eA2c    = (float*)alloc((size_t)E * H * 4);
    // --- persistent ---
    float* nfw     = (float*)alloc((size_t)N * D * 4);
    unsigned short* xs_b  = (unsigned short*)alloc((size_t)Mpad * D * 2);
    unsigned short* Abf   = (unsigned short*)alloc((size_t)Mpad * D * 2);
    unsigned short* lin1T = (unsigned short*)alloc((size_t)D * D * 2);
    unsigned short* lin2T = (unsigned short*)alloc((size_t)D * D * 2);
    unsigned short* w1T   = (unsigned short*)alloc((size_t)DF * D * 2);
    unsigned short* w2T   = (unsigned short*)alloc((size_t)D * DF * 2);
    unsigned short* hidden = (unsigned short*)ws;  // aliases arena0 (dead by FFN)
    (void)ws_size;
    float* out = (float*)d_out;

    hipMemsetAsync(deg, 0, (size_t)N * 4, stream);

    int eb = (E + 255) / 256;
    int nb = (N + 255) / 256;
    deg_kernel<<<eb, 256, 0, stream>>>(dstI, deg, E);
    partial_sum_kernel<<<nb, 256, 0, stream>>>(deg, part, N);
    scan_part_kernel<<<1, 256, 0, stream>>>(part, nb);
    scan_final_kernel<<<nb, 256, 0, stream>>>(deg, part, csr_off, cursor, N);
    fill_kernel<<<eb, 256, 0, stream>>>(srcI, dstI, cursor, eid, src_csr, E);

    transpose4_bf16_kernel<<<641, 256, 0, stream>>>(lin1, lin2, w1, w2, le1, aedge1, le2, aedge2,
                                                    lin1T, lin2T, w1T, w2T, MeT);
    ealpha_mfma_kernel<<<(E + 63) / 64, 256, 0, stream>>>(ew, MeT, eAe, E);
    permute_ea_kernel<<<eb, 256, 0, stream>>>(eAe, eid, eA1c, eA2c, E);

    const size_t nvalid = (size_t)N * D, ntot = (size_t)Mpad * D;
    int cb = (int)((ntot / 8 + 255) / 256);
    int gatb = (N + 3) / 4;

    // ---- GAT layer 1 ----
    convert_bf16x8_kernel<<<cb, 256, 0, stream>>>(nf0, Abf, nvalid, ntot);
    mfma_gemm_kernel<64><<<dim3(Mpad / 64, 2), 256, 0, stream>>>(
        Abf, lin1T, nullptr, nullptr, xs_b, N, D, D, 0, asrc1w, adst1w, asrcB, adstB);
    gat_node_kernel<<<gatb, 256, 0, stream>>>(csr_off, src_csr, eA1c, asrcB, adstB,
                                              xs_b, nf0, b1, g1, be1, nfw, Abf, N);
    // ---- GAT layer 2 ----
    mfma_gemm_kernel<64><<<dim3(Mpad / 64, 2), 256, 0, stream>>>(
        Abf, lin2T, nullptr, nullptr, xs_b, N, D, D, 0, asrc2w, adst2w, asrcB, adstB);
    gat_node_kernel<<<gatb, 256, 0, stream>>>(csr_off, src_csr, eA2c, asrcB, adstB,
                                              xs_b, nfw, b2, g2, be2, nfw, Abf, N);
    // ---- FFN: hidden = relu(Abf@w1+fb1) for ALL Mpad rows (pad rows are zero -> relu(fb1)) ----
    mfma_gemm_kernel<128><<<dim3(Mpad / 128, 8), 256, 0, stream>>>(
        Abf, w1T, fb1, nullptr, hidden, Mpad, DF, D, 1, nullptr, nullptr, nullptr, nullptr);
    // ---- FFN2 + LN + residual + output, fused ----
    ffn2_ln_kernel<<<(N + 63) / 64, 256, 0, stream>>>(hidden, w2T, fb2, nfw, g3, be3, out, N);
}

// Round 7
// 253.588 us; speedup vs baseline: 2.1339x; 1.0231x over previous
//
#include <hip/hip_runtime.h>
#include <hip/hip_bf16.h>
#include <math.h>

#define D 256
#define H 8
#define C 32
#define DE 64
#define DF 1024

static inline size_t align_up(size_t x, size_t a) { return (x + a - 1) / a * a; }

typedef __attribute__((ext_vector_type(8))) short short8;
typedef __attribute__((ext_vector_type(4))) float f32x4;

__device__ inline unsigned short f2b(float x) {
    __hip_bfloat16 h = __float2bfloat16(x);
    return *reinterpret_cast<unsigned short*>(&h);
}
__device__ inline float b2f(unsigned short u) {
    return __uint_as_float(((unsigned int)u) << 16);
}

// ---------------- CSR build ----------------
__global__ void deg_kernel(const int* __restrict__ dst, int* __restrict__ deg, int E) {
    int e = blockIdx.x * 256 + threadIdx.x;
    if (e < E) atomicAdd(&deg[dst[e]], 1);
}

__global__ void partial_sum_kernel(const int* __restrict__ deg, int* __restrict__ part, int n) {
    int i = blockIdx.x * 256 + threadIdx.x;
    int v = (i < n) ? deg[i] : 0;
    for (int o = 1; o < 64; o <<= 1) v += __shfl_xor(v, o);
    __shared__ int w4[4];
    if ((threadIdx.x & 63) == 0) w4[threadIdx.x >> 6] = v;
    __syncthreads();
    if (threadIdx.x == 0) part[blockIdx.x] = w4[0] + w4[1] + w4[2] + w4[3];
}

__global__ void scan_part_kernel(int* __restrict__ part, int nb) {
    __shared__ int buf[256];
    int t = threadIdx.x;
    buf[t] = (t < nb) ? part[t] : 0;
    __syncthreads();
    for (int s = 1; s < 256; s <<= 1) {
        int v = (t >= s) ? buf[t - s] : 0;
        __syncthreads();
        buf[t] += v;
        __syncthreads();
    }
    int excl = (t == 0) ? 0 : buf[t - 1];
    if (t < nb) part[t] = excl;
}

__global__ void scan_final_kernel(const int* __restrict__ deg, const int* __restrict__ part,
                                  int* __restrict__ off, int* __restrict__ cursor, int n) {
    int b = blockIdx.x, t = threadIdx.x, i = b * 256 + t;
    __shared__ int buf[256];
    int v = (i < n) ? deg[i] : 0;
    buf[t] = v;
    __syncthreads();
    for (int s = 1; s < 256; s <<= 1) {
        int x = (t >= s) ? buf[t - s] : 0;
        __syncthreads();
        buf[t] += x;
        __syncthreads();
    }
    int excl = part[b] + buf[t] - v;
    if (i < n) { off[i] = excl; cursor[i] = excl; }
    if (i == n - 1) off[n] = excl + v;
}

// writes eid[p] (edge at CSR slot p) and src_csr[p] (source node of slot p)
__global__ void fill_kernel(const int* __restrict__ src, const int* __restrict__ dst,
                            int* __restrict__ cursor, int* __restrict__ eid,
                            int* __restrict__ src_csr, int E) {
    int e = blockIdx.x * 256 + threadIdx.x;
    if (e < E) {
        int p = atomicAdd(&cursor[dst[e]], 1);
        eid[p] = e;
        src_csr[p] = src[e];
    }
}

// ---------------- prep: 4 weight transposes + MeT + nf0->bf16 convert, one dispatch ----------------
__global__ void prep_kernel(const float* __restrict__ lin1, const float* __restrict__ lin2,
                            const float* __restrict__ w1, const float* __restrict__ w2,
                            const float* __restrict__ le1, const float* __restrict__ ae1,
                            const float* __restrict__ le2, const float* __restrict__ ae2,
                            const float* __restrict__ nf0,
                            unsigned short* __restrict__ lin1T, unsigned short* __restrict__ lin2T,
                            unsigned short* __restrict__ w1T, unsigned short* __restrict__ w2T,
                            unsigned short* __restrict__ MeT, unsigned short* __restrict__ Abf,
                            size_t n_valid, size_t n_total) {
    int b = blockIdx.x;
    if (b > 640) {  // convert nf0 -> Abf (bf16), pad rows zeroed
        size_t i = ((size_t)(b - 641) * 256 + threadIdx.x) * 8;
        if (i >= n_total) return;
        ushort4 o0, o1;
        if (i < n_valid) {
            float4 a = *(const float4*)&nf0[i];
            float4 bb = *(const float4*)&nf0[i + 4];
            o0.x = f2b(a.x); o0.y = f2b(a.y); o0.z = f2b(a.z); o0.w = f2b(a.w);
            o1.x = f2b(bb.x); o1.y = f2b(bb.y); o1.z = f2b(bb.z); o1.w = f2b(bb.w);
        } else {
            o0.x = o0.y = o0.z = o0.w = 0;
            o1 = o0;
        }
        *(ushort4*)&Abf[i] = o0;
        *(ushort4*)&Abf[i + 4] = o1;
        return;
    }
    if (b == 640) {  // MeT[c][d]: c<8 -> layer1 head c; c>=8 -> layer2 head c-8
        for (int t = threadIdx.x; t < 512; t += 256) {
            int d = t >> 3, h = t & 7;
            float s1 = 0.f, s2 = 0.f;
            for (int c = 0; c < C; ++c) {
                s1 += le1[d * (H * C) + h * C + c] * ae1[h * C + c];
                s2 += le2[d * (H * C) + h * C + c] * ae2[h * C + c];
            }
            MeT[h * 64 + d] = f2b(s1);
            MeT[(8 + h) * 64 + d] = f2b(s2);
        }
        return;
    }
    __shared__ float tile[32][33];
    const float* in; unsigned short* outp; int K, N, tt;
    if (b < 64)       { in = lin1; outp = lin1T; K = D;  N = D;  tt = b; }
    else if (b < 128) { in = lin2; outp = lin2T; K = D;  N = D;  tt = b - 64; }
    else if (b < 384) { in = w1;   outp = w1T;   K = D;  N = DF; tt = b - 128; }
    else              { in = w2;   outp = w2T;   K = DF; N = D;  tt = b - 384; }
    int ntn = N >> 5;
    int bn = (tt % ntn) * 32, bk = (tt / ntn) * 32;
    int tx = threadIdx.x & 31, ty = threadIdx.x >> 5;
    for (int i = ty; i < 32; i += 8)
        tile[i][tx] = in[(size_t)(bk + i) * N + bn + tx];
    __syncthreads();
    for (int i = ty; i < 32; i += 8)
        outp[(size_t)(bn + i) * K + bk + tx] = f2b(tile[tx][i]);
}

// ---------------- bf16 MFMA GEMM: C = A[MxK] @ BT[NxK]^T (+bias)(+relu) ----------------
// BM x 128 tile, BK=64. BM=128: 2x2 waves of 64x64. BM=64: 1x4 waves of 64x32.
// Optional fused per-head attn projections (xs GEMM): asrc/adst written when a_s != null.
template<int BM>
__global__ __launch_bounds__(256) void mfma_gemm_kernel(
    const unsigned short* __restrict__ A, const unsigned short* __restrict__ BT,
    const float* __restrict__ bias, float* __restrict__ Cf, unsigned short* __restrict__ Cb,
    int M, int Nc, int K, int relu,
    const float* __restrict__ a_s, const float* __restrict__ a_d,
    float* __restrict__ asrcO, float* __restrict__ adstO) {
    constexpr int NR = (BM == 128) ? 4 : 2;
    constexpr int AI = BM / 32;
    __shared__ unsigned short As[BM * 64];
    __shared__ unsigned short Bs[128 * 64];
    int t = threadIdx.x;
    int lane = t & 63, w = t >> 6;
    int gm0 = blockIdx.x * BM, gn0 = blockIdx.y * 128;
    f32x4 acc[4][NR] = {};
    int srow = lane >> 3, scol = (lane & 7) * 8;
    int wm = (BM == 128) ? (w >> 1) * 64 : 0;
    int wn = (BM == 128) ? (w & 1) * 64 : w * 32;
    int fr = lane & 15, fk = (lane >> 4) * 8;

    for (int k0 = 0; k0 < K; k0 += 64) {
        __syncthreads();
#pragma unroll
        for (int i = 0; i < AI; ++i) {
            int rb = w * (8 * AI) + i * 8;
            const unsigned short* ga = A + (size_t)(gm0 + rb + srow) * K + k0 + scol;
            __builtin_amdgcn_global_load_lds(
                (const __attribute__((address_space(1))) unsigned int*)ga,
                (__attribute__((address_space(3))) unsigned int*)&As[rb * 64], 16, 0, 0);
        }
#pragma unroll
        for (int i = 0; i < 4; ++i) {
            int rb = w * 32 + i * 8;
            const unsigned short* gb = BT + (size_t)(gn0 + rb + srow) * K + k0 + scol;
            __builtin_amdgcn_global_load_lds(
                (const __attribute__((address_space(1))) unsigned int*)gb,
                (__attribute__((address_space(3))) unsigned int*)&Bs[rb * 64], 16, 0, 0);
        }
        __syncthreads();
#pragma unroll
        for (int kk = 0; kk < 64; kk += 32) {
            short8 a[4], b[NR];
#pragma unroll
            for (int m = 0; m < 4; ++m)
                a[m] = *(const short8*)&As[(wm + m * 16 + fr) * 64 + kk + fk];
#pragma unroll
            for (int n = 0; n < NR; ++n)
                b[n] = *(const short8*)&Bs[(wn + n * 16 + fr) * 64 + kk + fk];
#pragma unroll
            for (int m = 0; m < 4; ++m)
#pragma unroll
                for (int n = 0; n < NR; ++n)
                    acc[m][n] = __builtin_amdgcn_mfma_f32_16x16x32_bf16(a[m], b[n], acc[m][n], 0, 0, 0);
        }
    }
    int fcol = lane & 15, frow4 = (lane >> 4) * 4;
#pragma unroll
    for (int m = 0; m < 4; ++m) {
#pragma unroll
        for (int i = 0; i < 4; ++i) {
            int gr = gm0 + wm + m * 16 + frow4 + i;
            if (gr >= M) continue;
#pragma unroll
            for (int n = 0; n < NR; ++n) {
                int gc = gn0 + wn + n * 16 + fcol;
                float v = acc[m][n][i];
                if (bias) v += bias[gc];
                if (relu) v = fmaxf(v, 0.f);
                if (Cb) Cb[(size_t)gr * Nc + gc] = f2b(v);
                else    Cf[(size_t)gr * Nc + gc] = v;
            }
        }
    }
    if (BM == 64 && a_s) {
        // wave owns 64 rows x 32 cols = one head
        int head = (gn0 >> 5) + w;
        float as0 = a_s[head * 32 + fcol], as1 = a_s[head * 32 + 16 + fcol];
        float ad0 = a_d[head * 32 + fcol], ad1 = a_d[head * 32 + 16 + fcol];
#pragma unroll
        for (int m = 0; m < 4; ++m) {
#pragma unroll
            for (int i = 0; i < 4; ++i) {
                float vs = acc[m][0][i] * as0 + acc[m][1][i] * as1;
                float vd = acc[m][0][i] * ad0 + acc[m][1][i] * ad1;
#pragma unroll
                for (int o = 1; o < 16; o <<= 1) {
                    vs += __shfl_xor(vs, o);
                    vd += __shfl_xor(vd, o);
                }
                int r = gm0 + m * 16 + frow4 + i;
                if (fcol == 0 && r < M) {
                    asrcO[r * 8 + head] = vs;
                    adstO[r * 8 + head] = vd;
                }
            }
        }
    }
}

// ---------------- FFN2 + LN + leaky + residual, fully fused ----------------
// BM=64 x BN=256 (full row). 4 waves, wave w owns cols w*64..w*64+63, all 64 rows.
__global__ __launch_bounds__(256) void ffn2_ln_kernel(
    const unsigned short* __restrict__ A, const unsigned short* __restrict__ BT,
    const float* __restrict__ bias, const float* __restrict__ nf_in,
    const float* __restrict__ gamma, const float* __restrict__ beta,
    float* __restrict__ out, int M) {
    __shared__ unsigned short As[64 * 64];
    __shared__ unsigned short Bs[256 * 64];
    __shared__ float redS1[4][64], redS2[4][64];
    __shared__ float muS[64], invS[64];
    int t = threadIdx.x, lane = t & 63, w = t >> 6;
    int gm0 = blockIdx.x * 64;
    f32x4 acc[4][4] = {};
    int srow = lane >> 3, scol = (lane & 7) * 8;
    int wn = w * 64;
    int fr = lane & 15, fk = (lane >> 4) * 8;
    for (int k0 = 0; k0 < DF; k0 += 64) {
        __syncthreads();
#pragma unroll
        for (int i = 0; i < 2; ++i) {
            int rb = w * 16 + i * 8;
            const unsigned short* ga = A + (size_t)(gm0 + rb + srow) * DF + k0 + scol;
            __builtin_amdgcn_global_load_lds(
                (const __attribute__((address_space(1))) unsigned int*)ga,
                (__attribute__((address_space(3))) unsigned int*)&As[rb * 64], 16, 0, 0);
        }
#pragma unroll
        for (int i = 0; i < 8; ++i) {
            int rb = w * 64 + i * 8;
            const unsigned short* gb = BT + (size_t)(rb + srow) * DF + k0 + scol;
            __builtin_amdgcn_global_load_lds(
                (const __attribute__((address_space(1))) unsigned int*)gb,
                (__attribute__((address_space(3))) unsigned int*)&Bs[rb * 64], 16, 0, 0);
        }
        __syncthreads();
#pragma unroll
        for (int kk = 0; kk < 64; kk += 32) {
            short8 a[4], b[4];
#pragma unroll
            for (int m = 0; m < 4; ++m)
                a[m] = *(const short8*)&As[(m * 16 + fr) * 64 + kk + fk];
#pragma unroll
            for (int n = 0; n < 4; ++n)
                b[n] = *(const short8*)&Bs[(wn + n * 16 + fr) * 64 + kk + fk];
#pragma unroll
            for (int m = 0; m < 4; ++m)
#pragma unroll
                for (int n = 0; n < 4; ++n)
                    acc[m][n] = __builtin_amdgcn_mfma_f32_16x16x32_bf16(a[m], b[n], acc[m][n], 0, 0, 0);
        }
    }
    int fcol = lane & 15, frow4 = (lane >> 4) * 4;
#pragma unroll
    for (int m = 0; m < 4; ++m) {
#pragma unroll
        for (int i = 0; i < 4; ++i) {
            float vs1 = 0.f, vs2 = 0.f;
#pragma unroll
            for (int n = 0; n < 4; ++n) {
                float vv = acc[m][n][i] + bias[wn + n * 16 + fcol];
                acc[m][n][i] = vv;
                vs1 += vv; vs2 += vv * vv;
            }
#pragma unroll
            for (int o = 1; o < 16; o <<= 1) {
                vs1 += __shfl_xor(vs1, o);
                vs2 += __shfl_xor(vs2, o);
            }
            if (fcol == 0) {
                redS1[w][m * 16 + frow4 + i] = vs1;
                redS2[w][m * 16 + frow4 + i] = vs2;
            }
        }
    }
    __syncthreads();
    if (t < 64) {
        float s1 = redS1[0][t] + redS1[1][t] + redS1[2][t] + redS1[3][t];
        float s2 = redS2[0][t] + redS2[1][t] + redS2[2][t] + redS2[3][t];
        float mu = s1 / 256.f;
        float var = fmaxf((s2 - 256.f * mu * mu) / 255.f, 0.f);
        muS[t] = mu;
        invS[t] = 1.f / (sqrtf(var) + 1e-6f);
    }
    __syncthreads();
#pragma unroll
    for (int m = 0; m < 4; ++m) {
#pragma unroll
        for (int i = 0; i < 4; ++i) {
            int r = m * 16 + frow4 + i;
            int gr = gm0 + r;
            if (gr >= M) continue;
            float mu = muS[r], inv = invS[r];
#pragma unroll
            for (int n = 0; n < 4; ++n) {
                int gc = wn + n * 16 + fcol;
                float y = gamma[gc] * (acc[m][n][i] - mu) * inv + beta[gc];
                y = y > 0.f ? y : 0.01f * y;
                out[(size_t)gr * D + gc] = nf_in[(size_t)gr * D + gc] + y;
            }
        }
    }
}

// ---------------- edge-attention projection ----------------
// eAe[e][16] = ew[e,:] @ MeT^T via MFMA, edge order (coalesced read+write).
__global__ __launch_bounds__(256) void ealpha_mfma_kernel(const float* __restrict__ ew,
                                                          const unsigned short* __restrict__ MeT,
                                                          float* __restrict__ eAe, int E) {
    int t = threadIdx.x;
    int lane = t & 63, w = t >> 6;
    int e0 = blockIdx.x * 64 + w * 16;
    int r = lane & 15, g = lane >> 4;
    int er = e0 + r; if (er > E - 1) er = E - 1;
    const float* rowp = ew + (size_t)er * DE;
    float4 x0 = *(const float4*)&rowp[g * 8];
    float4 x1 = *(const float4*)&rowp[g * 8 + 4];
    float4 y0 = *(const float4*)&rowp[32 + g * 8];
    float4 y1 = *(const float4*)&rowp[32 + g * 8 + 4];
    short8 a0, a1;
    a0[0] = (short)f2b(x0.x); a0[1] = (short)f2b(x0.y); a0[2] = (short)f2b(x0.z); a0[3] = (short)f2b(x0.w);
    a0[4] = (short)f2b(x1.x); a0[5] = (short)f2b(x1.y); a0[6] = (short)f2b(x1.z); a0[7] = (short)f2b(x1.w);
    a1[0] = (short)f2b(y0.x); a1[1] = (short)f2b(y0.y); a1[2] = (short)f2b(y0.z); a1[3] = (short)f2b(y0.w);
    a1[4] = (short)f2b(y1.x); a1[5] = (short)f2b(y1.y); a1[6] = (short)f2b(y1.z); a1[7] = (short)f2b(y1.w);
    short8 b0 = *(const short8*)&MeT[r * 64 + g * 8];
    short8 b1 = *(const short8*)&MeT[r * 64 + 32 + g * 8];
    f32x4 acc = {};
    acc = __builtin_amdgcn_mfma_f32_16x16x32_bf16(a0, b0, acc, 0, 0, 0);
    acc = __builtin_amdgcn_mfma_f32_16x16x32_bf16(a1, b1, acc, 0, 0, 0);
#pragma unroll
    for (int i = 0; i < 4; ++i) {
        int ee = e0 + g * 4 + i;
        if (ee < E) eAe[(size_t)ee * 16 + r] = acc[i];
    }
}

// CSR permute: read eAe[eid[p]] (random 64B from L2/L3), write eA1c/eA2c coalesced
__global__ void permute_ea_kernel(const float* __restrict__ eAe, const int* __restrict__ eid,
                                  float* __restrict__ eA1c, float* __restrict__ eA2c, int E) {
    int p = blockIdx.x * 256 + threadIdx.x;
    if (p >= E) return;
    int e = eid[p];
    const float4* src = (const float4*)&eAe[(size_t)e * 16];
    float4 v0 = src[0], v1 = src[1], v2 = src[2], v3 = src[3];
    float4* d1 = (float4*)&eA1c[(size_t)p * 8];
    float4* d2 = (float4*)&eA2c[(size_t)p * 8];
    d1[0] = v0; d1[1] = v1;
    d2[0] = v2; d2[1] = v3;
}

// ---------------- GAT: wave-per-node gather + softmax + fused LN/leaky/residual ----------------
// 4 nodes/block (1 wave each). Lane owns features lane*4..lane*4+3.
// Producer role: slot hw, head h=lane&7; next batch prefetched 1 deep (8 edges/iter).
__global__ __launch_bounds__(256) void gat_node_kernel(
    const int* __restrict__ off, const int* __restrict__ src_csr,
    const float* __restrict__ eAc,
    const float* __restrict__ asrc, const float* __restrict__ adst,
    const unsigned short* __restrict__ xsb, const float* __restrict__ nf_in,
    const float* __restrict__ bias, const float* __restrict__ gamma,
    const float* __restrict__ beta, float* __restrict__ nf_out,
    unsigned short* __restrict__ nf_out_b, int N) {
    int lane = threadIdx.x & 63;
    int n = blockIdx.x * 4 + (threadIdx.x >> 6);
    if (n >= N) return;
    int e0 = off[n], e1 = off[n + 1], deg = e1 - e0;
    int h = lane & 7;
    int hw = lane >> 3;

    float adstn = adst[n * 8 + h];
    float asn = asrc[n * 8 + h];  // hoisted self-loop term

    float acc0 = 0.f, acc1 = 0.f, acc2 = 0.f, acc3 = 0.f;
    float den0 = 0.f, easum = 0.f;
    int nb8 = (deg + 7) >> 3;

    bool act = hw < deg;
    int sp = e0 + hw;
    int s_cur = act ? src_csr[sp] : n;
    float ea_cur = act ? eAc[(size_t)sp * 8 + h] : 0.f;
    float as_cur = act ? asrc[s_cur * 8 + h] : 0.f;

    for (int it = 0; it < nb8; ++it) {
        int base = it * 8;
        // prefetch next batch (dependent chain hidden under this batch's gather)
        bool actn = (base + 8 + hw) < deg;
        int spn = e0 + base + 8 + hw;
        int s_nx = actn ? src_csr[spn] : n;
        float ea_nx = actn ? eAc[(size_t)spn * 8 + h] : 0.f;
        float as_nx = actn ? asrc[s_nx * 8 + h] : 0.f;

        float al = as_cur + adstn + ea_cur;
        al = al > 0.f ? al : 0.2f * al;
        float ex = act ? expf(al) : 0.f;
        den0 += ex;
        easum += ea_cur;

        int lim = deg - base; if (lim > 8) lim = 8;
        if (lim == 8) {
#pragma unroll
            for (int kk = 0; kk < 8; ++kk) {
                int sl = kk * 8 + hw;
                float exk = __shfl(ex, sl);
                int sk = __shfl(s_cur, sl);
                ushort4 u = *(const ushort4*)&xsb[(size_t)sk * D + lane * 4];
                acc0 = fmaf(exk, b2f(u.x), acc0);
                acc1 = fmaf(exk, b2f(u.y), acc1);
                acc2 = fmaf(exk, b2f(u.z), acc2);
                acc3 = fmaf(exk, b2f(u.w), acc3);
            }
        } else {
            for (int kk = 0; kk < lim; ++kk) {
                int sl = kk * 8 + hw;
                float exk = __shfl(ex, sl);
                int sk = __shfl(s_cur, sl);
                ushort4 u = *(const ushort4*)&xsb[(size_t)sk * D + lane * 4];
                acc0 = fmaf(exk, b2f(u.x), acc0);
                acc1 = fmaf(exk, b2f(u.y), acc1);
                acc2 = fmaf(exk, b2f(u.z), acc2);
                acc3 = fmaf(exk, b2f(u.w), acc3);
            }
        }
        s_cur = s_nx; ea_cur = ea_nx; as_cur = as_nx; act = actn;
    }
    den0  += __shfl_xor(den0, 8);
    den0  += __shfl_xor(den0, 16);
    den0  += __shfl_xor(den0, 32);
    easum += __shfl_xor(easum, 8);
    easum += __shfl_xor(easum, 16);
    easum += __shfl_xor(easum, 32);
    float sa = easum / (float)(deg > 0 ? deg : 1);
    float als = asn + adstn + sa;
    als = als > 0.f ? als : 0.2f * als;
    float exSelf = expf(als);
    {
        float exs = __shfl(exSelf, hw);
        ushort4 u = *(const ushort4*)&xsb[(size_t)n * D + lane * 4];
        acc0 = fmaf(exs, b2f(u.x), acc0);
        acc1 = fmaf(exs, b2f(u.y), acc1);
        acc2 = fmaf(exs, b2f(u.z), acc2);
        acc3 = fmaf(exs, b2f(u.w), acc3);
    }
    den0 += exSelf;
    float denOwn = __shfl(den0, hw);
    float inv = 1.f / (denOwn + 1e-16f);

    int t0 = lane * 4;
    float4 bi = *(const float4*)&bias[t0];
    float o0 = acc0 * inv + bi.x;
    float o1 = acc1 * inv + bi.y;
    float o2 = acc2 * inv + bi.z;
    float o3 = acc3 * inv + bi.w;

    float s1 = o0 + o1 + o2 + o3;
    float s2 = o0 * o0 + o1 * o1 + o2 * o2 + o3 * o3;
    for (int o = 1; o < 64; o <<= 1) { s1 += __shfl_xor(s1, o); s2 += __shfl_xor(s2, o); }
    float mu = s1 / 256.f;
    float var = fmaxf((s2 - 256.f * mu * mu) / 255.f, 0.f);
    float sdv = sqrtf(var) + 1e-6f;
    float4 ga = *(const float4*)&gamma[t0];
    float4 be = *(const float4*)&beta[t0];
    float4 nin = *(const float4*)&nf_in[(size_t)n * D + t0];
    float y0 = ga.x * (o0 - mu) / sdv + be.x; y0 = y0 > 0.f ? y0 : 0.01f * y0;
    float y1 = ga.y * (o1 - mu) / sdv + be.y; y1 = y1 > 0.f ? y1 : 0.01f * y1;
    float y2 = ga.z * (o2 - mu) / sdv + be.z; y2 = y2 > 0.f ? y2 : 0.01f * y2;
    float y3 = ga.w * (o3 - mu) / sdv + be.w; y3 = y3 > 0.f ? y3 : 0.01f * y3;
    float r0 = nin.x + y0, r1 = nin.y + y1, r2 = nin.z + y2, r3 = nin.w + y3;
    float4 outv; outv.x = r0; outv.y = r1; outv.z = r2; outv.w = r3;
    *(float4*)&nf_out[(size_t)n * D + t0] = outv;
    ushort4 ob; ob.x = f2b(r0); ob.y = f2b(r1); ob.z = f2b(r2); ob.w = f2b(r3);
    *(ushort4*)&nf_out_b[(size_t)n * D + t0] = ob;
}

extern "C" void kernel_launch(void* const* d_in, const int* in_sizes, int n_in,
                              void* d_out, int out_size, void* d_ws, size_t ws_size,
                              hipStream_t stream) {
    const float* nf0    = (const float*)d_in[0];
    const int*   ei     = (const int*)d_in[1];
    const float* ew     = (const float*)d_in[2];
    const float* lin1   = (const float*)d_in[3];
    const float* le1    = (const float*)d_in[4];
    const float* asrc1w = (const float*)d_in[5];
    const float* adst1w = (const float*)d_in[6];
    const float* aedge1 = (const float*)d_in[7];
    const float* b1     = (const float*)d_in[8];
    const float* lin2   = (const float*)d_in[9];
    const float* le2    = (const float*)d_in[10];
    const float* asrc2w = (const float*)d_in[11];
    const float* adst2w = (const float*)d_in[12];
    const float* aedge2 = (const float*)d_in[13];
    const float* b2     = (const float*)d_in[14];
    const float* g1     = (const float*)d_in[15];
    const float* be1    = (const float*)d_in[16];
    const float* g2     = (const float*)d_in[17];
    const float* be2    = (const float*)d_in[18];
    const float* g3     = (const float*)d_in[19];
    const float* be3    = (const float*)d_in[20];
    const float* w1     = (const float*)d_in[21];
    const float* fb1    = (const float*)d_in[22];
    const float* w2     = (const float*)d_in[23];
    const float* fb2    = (const float*)d_in[24];

    const int N = in_sizes[0] / D;
    const int E = in_sizes[1] / 2;
    const int Mpad = ((N + 127) / 128) * 128;
    const int* srcI = ei;
    const int* dstI = ei + E;

    char* ws = (char*)d_ws;
    size_t ob = 0;
    auto alloc = [&](size_t bytes) { void* p = ws + ob; ob = align_up(ob + bytes, 256); return p; };
    // --- arena0: dead after GAT layer 2; start reused as FFN hidden (bf16, Mpad*DF*2 = 20.7MB) ---
    int*   deg     = (int*)alloc((size_t)N * 4);
    int*   csr_off = (int*)alloc((size_t)(N + 1) * 4);
    int*   cursor  = (int*)alloc((size_t)N * 4);
    int*   part    = (int*)alloc(1024);
    int*   eid     = (int*)alloc((size_t)E * 4);
    int*   src_csr = (int*)alloc((size_t)E * 4);
    unsigned short* MeT = (unsigned short*)alloc(16 * 64 * 2);
    float* asrcB   = (float*)alloc((size_t)N * H * 4);
    float* adstB   = (float*)alloc((size_t)N * H * 4);
    float* eAe     = (float*)alloc((size_t)E * 16 * 4);
    float* eA1c    = (float*)alloc((size_t)E * H * 4);
    float* eA2c    = (float*)alloc((size_t)E * H * 4);
    // --- persistent ---
    float* nfw     = (float*)alloc((size_t)N * D * 4);
    unsigned short* xs_b  = (unsigned short*)alloc((size_t)Mpad * D * 2);
    unsigned short* Abf   = (unsigned short*)alloc((size_t)Mpad * D * 2);
    unsigned short* lin1T = (unsigned short*)alloc((size_t)D * D * 2);
    unsigned short* lin2T = (unsigned short*)alloc((size_t)D * D * 2);
    unsigned short* w1T   = (unsigned short*)alloc((size_t)DF * D * 2);
    unsigned short* w2T   = (unsigned short*)alloc((size_t)D * DF * 2);
    unsigned short* hidden = (unsigned short*)ws;  // aliases arena0 (dead by FFN)
    (void)ws_size;
    float* out = (float*)d_out;

    hipMemsetAsync(deg, 0, (size_t)N * 4, stream);

    int eb = (E + 255) / 256;
    int nb = (N + 255) / 256;
    deg_kernel<<<eb, 256, 0, stream>>>(dstI, deg, E);
    partial_sum_kernel<<<nb, 256, 0, stream>>>(deg, part, N);
    scan_part_kernel<<<1, 256, 0, stream>>>(part, nb);
    scan_final_kernel<<<nb, 256, 0, stream>>>(deg, part, csr_off, cursor, N);
    fill_kernel<<<eb, 256, 0, stream>>>(srcI, dstI, cursor, eid, src_csr, E);

    const size_t nvalid = (size_t)N * D, ntot = (size_t)Mpad * D;
    int cb = (int)((ntot / 8 + 255) / 256);
    prep_kernel<<<641 + cb, 256, 0, stream>>>(lin1, lin2, w1, w2, le1, aedge1, le2, aedge2, nf0,
                                              lin1T, lin2T, w1T, w2T, MeT, Abf, nvalid, ntot);
    ealpha_mfma_kernel<<<(E + 63) / 64, 256, 0, stream>>>(ew, MeT, eAe, E);
    permute_ea_kernel<<<eb, 256, 0, stream>>>(eAe, eid, eA1c, eA2c, E);

    int gatb = (N + 3) / 4;

    // ---- GAT layer 1 ----
    mfma_gemm_kernel<64><<<dim3(Mpad / 64, 2), 256, 0, stream>>>(
        Abf, lin1T, nullptr, nullptr, xs_b, N, D, D, 0, asrc1w, adst1w, asrcB, adstB);
    gat_node_kernel<<<gatb, 256, 0, stream>>>(csr_off, src_csr, eA1c, asrcB, adstB,
                                              xs_b, nf0, b1, g1, be1, nfw, Abf, N);
    // ---- GAT layer 2 ----
    mfma_gemm_kernel<64><<<dim3(Mpad / 64, 2), 256, 0, stream>>>(
        Abf, lin2T, nullptr, nullptr, xs_b, N, D, D, 0, asrc2w, adst2w, asrcB, adstB);
    gat_node_kernel<<<gatb, 256, 0, stream>>>(csr_off, src_csr, eA2c, asrcB, adstB,
                                              xs_b, nfw, b2, g2, be2, nfw, Abf, N);
    // ---- FFN: hidden = relu(Abf@w1+fb1) for ALL Mpad rows (pad rows are zero -> relu(fb1)) ----
    mfma_gemm_kernel<128><<<dim3(Mpad / 128, 8), 256, 0, stream>>>(
        Abf, w1T, fb1, nullptr, hidden, Mpad, DF, D, 1, nullptr, nullptr, nullptr, nullptr);
    // ---- FFN2 + LN + residual + output, fused ----
    ffn2_ln_kernel<<<(N + 63) / 64, 256, 0, stream>>>(hidden, w2T, fb2, nfw, g3, be3, out, N);
}

// Round 8
// 238.953 us; speedup vs baseline: 2.2646x; 1.0612x over previous
//
#include <hip/hip_runtime.h>
#include <hip/hip_bf16.h>
#include <math.h>

#define D 256
#define H 8
#define C 32
#define DE 64
#define DF 1024

static inline size_t align_up(size_t x, size_t a) { return (x + a - 1) / a * a; }

typedef __attribute__((ext_vector_type(8))) short short8;
typedef __attribute__((ext_vector_type(4))) float f32x4;

__device__ inline unsigned short f2b(float x) {
    __hip_bfloat16 h = __float2bfloat16(x);
    return *reinterpret_cast<unsigned short*>(&h);
}
__device__ inline float b2f(unsigned short u) {
    return __uint_as_float(((unsigned int)u) << 16);
}

// ---------------- CSR build ----------------
__global__ void deg_kernel(const int* __restrict__ dst, int* __restrict__ deg, int E) {
    int e = blockIdx.x * 256 + threadIdx.x;
    if (e < E) atomicAdd(&deg[dst[e]], 1);
}

__global__ void partial_sum_kernel(const int* __restrict__ deg, int* __restrict__ part, int n) {
    int i = blockIdx.x * 256 + threadIdx.x;
    int v = (i < n) ? deg[i] : 0;
    for (int o = 1; o < 64; o <<= 1) v += __shfl_xor(v, o);
    __shared__ int w4[4];
    if ((threadIdx.x & 63) == 0) w4[threadIdx.x >> 6] = v;
    __syncthreads();
    if (threadIdx.x == 0) part[blockIdx.x] = w4[0] + w4[1] + w4[2] + w4[3];
}

__global__ void scan_part_kernel(int* __restrict__ part, int nb) {
    __shared__ int buf[256];
    int t = threadIdx.x;
    buf[t] = (t < nb) ? part[t] : 0;
    __syncthreads();
    for (int s = 1; s < 256; s <<= 1) {
        int v = (t >= s) ? buf[t - s] : 0;
        __syncthreads();
        buf[t] += v;
        __syncthreads();
    }
    int excl = (t == 0) ? 0 : buf[t - 1];
    if (t < nb) part[t] = excl;
}

__global__ void scan_final_kernel(const int* __restrict__ deg, const int* __restrict__ part,
                                  int* __restrict__ off, int* __restrict__ cursor, int n) {
    int b = blockIdx.x, t = threadIdx.x, i = b * 256 + t;
    __shared__ int buf[256];
    int v = (i < n) ? deg[i] : 0;
    buf[t] = v;
    __syncthreads();
    for (int s = 1; s < 256; s <<= 1) {
        int x = (t >= s) ? buf[t - s] : 0;
        __syncthreads();
        buf[t] += x;
        __syncthreads();
    }
    int excl = part[b] + buf[t] - v;
    if (i < n) { off[i] = excl; cursor[i] = excl; }
    if (i == n - 1) off[n] = excl + v;
}

// writes eid[p] (edge at CSR slot p) and src_csr[p] (source node of slot p)
__global__ void fill_kernel(const int* __restrict__ src, const int* __restrict__ dst,
                            int* __restrict__ cursor, int* __restrict__ eid,
                            int* __restrict__ src_csr, int E) {
    int e = blockIdx.x * 256 + threadIdx.x;
    if (e < E) {
        int p = atomicAdd(&cursor[dst[e]], 1);
        eid[p] = e;
        src_csr[p] = src[e];
    }
}

// ---------------- prep: 4 weight transposes + MeT + nf0->bf16 convert, one dispatch ----------------
__global__ void prep_kernel(const float* __restrict__ lin1, const float* __restrict__ lin2,
                            const float* __restrict__ w1, const float* __restrict__ w2,
                            const float* __restrict__ le1, const float* __restrict__ ae1,
                            const float* __restrict__ le2, const float* __restrict__ ae2,
                            const float* __restrict__ nf0,
                            unsigned short* __restrict__ lin1T, unsigned short* __restrict__ lin2T,
                            unsigned short* __restrict__ w1T, unsigned short* __restrict__ w2T,
                            unsigned short* __restrict__ MeT, unsigned short* __restrict__ Abf,
                            size_t n_valid, size_t n_total) {
    int b = blockIdx.x;
    if (b > 640) {  // convert nf0 -> Abf (bf16), pad rows zeroed
        size_t i = ((size_t)(b - 641) * 256 + threadIdx.x) * 8;
        if (i >= n_total) return;
        ushort4 o0, o1;
        if (i < n_valid) {
            float4 a = *(const float4*)&nf0[i];
            float4 bb = *(const float4*)&nf0[i + 4];
            o0.x = f2b(a.x); o0.y = f2b(a.y); o0.z = f2b(a.z); o0.w = f2b(a.w);
            o1.x = f2b(bb.x); o1.y = f2b(bb.y); o1.z = f2b(bb.z); o1.w = f2b(bb.w);
        } else {
            o0.x = o0.y = o0.z = o0.w = 0;
            o1 = o0;
        }
        *(ushort4*)&Abf[i] = o0;
        *(ushort4*)&Abf[i + 4] = o1;
        return;
    }
    if (b == 640) {  // MeT[c][d]: c<8 -> layer1 head c; c>=8 -> layer2 head c-8
        for (int t = threadIdx.x; t < 512; t += 256) {
            int d = t >> 3, h = t & 7;
            float s1 = 0.f, s2 = 0.f;
            for (int c = 0; c < C; ++c) {
                s1 += le1[d * (H * C) + h * C + c] * ae1[h * C + c];
                s2 += le2[d * (H * C) + h * C + c] * ae2[h * C + c];
            }
            MeT[h * 64 + d] = f2b(s1);
            MeT[(8 + h) * 64 + d] = f2b(s2);
        }
        return;
    }
    __shared__ float tile[32][33];
    const float* in; unsigned short* outp; int K, N, tt;
    if (b < 64)       { in = lin1; outp = lin1T; K = D;  N = D;  tt = b; }
    else if (b < 128) { in = lin2; outp = lin2T; K = D;  N = D;  tt = b - 64; }
    else if (b < 384) { in = w1;   outp = w1T;   K = D;  N = DF; tt = b - 128; }
    else              { in = w2;   outp = w2T;   K = DF; N = D;  tt = b - 384; }
    int ntn = N >> 5;
    int bn = (tt % ntn) * 32, bk = (tt / ntn) * 32;
    int tx = threadIdx.x & 31, ty = threadIdx.x >> 5;
    for (int i = ty; i < 32; i += 8)
        tile[i][tx] = in[(size_t)(bk + i) * N + bn + tx];
    __syncthreads();
    for (int i = ty; i < 32; i += 8)
        outp[(size_t)(bn + i) * K + bk + tx] = f2b(tile[tx][i]);
}

// ---------------- bf16 MFMA GEMM: C = A[MxK] @ BT[NxK]^T (+bias)(+relu) ----------------
// BM x 128 tile, BK=64. BM=128: 2x2 waves of 64x64. BM=64: 1x4 waves of 64x32.
// Optional fused per-head attn projections (xs GEMM): asrc/adst written when a_s != null.
template<int BM>
__global__ __launch_bounds__(256) void mfma_gemm_kernel(
    const unsigned short* __restrict__ A, const unsigned short* __restrict__ BT,
    const float* __restrict__ bias, float* __restrict__ Cf, unsigned short* __restrict__ Cb,
    int M, int Nc, int K, int relu,
    const float* __restrict__ a_s, const float* __restrict__ a_d,
    float* __restrict__ asrcO, float* __restrict__ adstO) {
    constexpr int NR = (BM == 128) ? 4 : 2;
    constexpr int AI = BM / 32;
    __shared__ unsigned short As[BM * 64];
    __shared__ unsigned short Bs[128 * 64];
    int t = threadIdx.x;
    int lane = t & 63, w = t >> 6;
    int gm0 = blockIdx.x * BM, gn0 = blockIdx.y * 128;
    f32x4 acc[4][NR] = {};
    int srow = lane >> 3, scol = (lane & 7) * 8;
    int wm = (BM == 128) ? (w >> 1) * 64 : 0;
    int wn = (BM == 128) ? (w & 1) * 64 : w * 32;
    int fr = lane & 15, fk = (lane >> 4) * 8;

    for (int k0 = 0; k0 < K; k0 += 64) {
        __syncthreads();
#pragma unroll
        for (int i = 0; i < AI; ++i) {
            int rb = w * (8 * AI) + i * 8;
            const unsigned short* ga = A + (size_t)(gm0 + rb + srow) * K + k0 + scol;
            __builtin_amdgcn_global_load_lds(
                (const __attribute__((address_space(1))) unsigned int*)ga,
                (__attribute__((address_space(3))) unsigned int*)&As[rb * 64], 16, 0, 0);
        }
#pragma unroll
        for (int i = 0; i < 4; ++i) {
            int rb = w * 32 + i * 8;
            const unsigned short* gb = BT + (size_t)(gn0 + rb + srow) * K + k0 + scol;
            __builtin_amdgcn_global_load_lds(
                (const __attribute__((address_space(1))) unsigned int*)gb,
                (__attribute__((address_space(3))) unsigned int*)&Bs[rb * 64], 16, 0, 0);
        }
        __syncthreads();
#pragma unroll
        for (int kk = 0; kk < 64; kk += 32) {
            short8 a[4], b[NR];
#pragma unroll
            for (int m = 0; m < 4; ++m)
                a[m] = *(const short8*)&As[(wm + m * 16 + fr) * 64 + kk + fk];
#pragma unroll
            for (int n = 0; n < NR; ++n)
                b[n] = *(const short8*)&Bs[(wn + n * 16 + fr) * 64 + kk + fk];
#pragma unroll
            for (int m = 0; m < 4; ++m)
#pragma unroll
                for (int n = 0; n < NR; ++n)
                    acc[m][n] = __builtin_amdgcn_mfma_f32_16x16x32_bf16(a[m], b[n], acc[m][n], 0, 0, 0);
        }
    }
    int fcol = lane & 15, frow4 = (lane >> 4) * 4;
#pragma unroll
    for (int m = 0; m < 4; ++m) {
#pragma unroll
        for (int i = 0; i < 4; ++i) {
            int gr = gm0 + wm + m * 16 + frow4 + i;
            if (gr >= M) continue;
#pragma unroll
            for (int n = 0; n < NR; ++n) {
                int gc = gn0 + wn + n * 16 + fcol;
                float v = acc[m][n][i];
                if (bias) v += bias[gc];
                if (relu) v = fmaxf(v, 0.f);
                if (Cb) Cb[(size_t)gr * Nc + gc] = f2b(v);
                else    Cf[(size_t)gr * Nc + gc] = v;
            }
        }
    }
    if (BM == 64 && a_s) {
        // wave owns 64 rows x 32 cols = one head
        int head = (gn0 >> 5) + w;
        float as0 = a_s[head * 32 + fcol], as1 = a_s[head * 32 + 16 + fcol];
        float ad0 = a_d[head * 32 + fcol], ad1 = a_d[head * 32 + 16 + fcol];
#pragma unroll
        for (int m = 0; m < 4; ++m) {
#pragma unroll
            for (int i = 0; i < 4; ++i) {
                float vs = acc[m][0][i] * as0 + acc[m][1][i] * as1;
                float vd = acc[m][0][i] * ad0 + acc[m][1][i] * ad1;
#pragma unroll
                for (int o = 1; o < 16; o <<= 1) {
                    vs += __shfl_xor(vs, o);
                    vd += __shfl_xor(vd, o);
                }
                int r = gm0 + m * 16 + frow4 + i;
                if (fcol == 0 && r < M) {
                    asrcO[r * 8 + head] = vs;
                    adstO[r * 8 + head] = vd;
                }
            }
        }
    }
}

// ---------------- FFN2 + LN + leaky + residual, fully fused ----------------
// BM=64 x BN=256 (full row). 4 waves, wave w owns cols w*64..w*64+63, all 64 rows.
__global__ __launch_bounds__(256) void ffn2_ln_kernel(
    const unsigned short* __restrict__ A, const unsigned short* __restrict__ BT,
    const float* __restrict__ bias, const float* __restrict__ nf_in,
    const float* __restrict__ gamma, const float* __restrict__ beta,
    float* __restrict__ out, int M) {
    __shared__ unsigned short As[64 * 64];
    __shared__ unsigned short Bs[256 * 64];
    __shared__ float redS1[4][64], redS2[4][64];
    __shared__ float muS[64], invS[64];
    int t = threadIdx.x, lane = t & 63, w = t >> 6;
    int gm0 = blockIdx.x * 64;
    f32x4 acc[4][4] = {};
    int srow = lane >> 3, scol = (lane & 7) * 8;
    int wn = w * 64;
    int fr = lane & 15, fk = (lane >> 4) * 8;
    for (int k0 = 0; k0 < DF; k0 += 64) {
        __syncthreads();
#pragma unroll
        for (int i = 0; i < 2; ++i) {
            int rb = w * 16 + i * 8;
            const unsigned short* ga = A + (size_t)(gm0 + rb + srow) * DF + k0 + scol;
            __builtin_amdgcn_global_load_lds(
                (const __attribute__((address_space(1))) unsigned int*)ga,
                (__attribute__((address_space(3))) unsigned int*)&As[rb * 64], 16, 0, 0);
        }
#pragma unroll
        for (int i = 0; i < 8; ++i) {
            int rb = w * 64 + i * 8;
            const unsigned short* gb = BT + (size_t)(rb + srow) * DF + k0 + scol;
            __builtin_amdgcn_global_load_lds(
                (const __attribute__((address_space(1))) unsigned int*)gb,
                (__attribute__((address_space(3))) unsigned int*)&Bs[rb * 64], 16, 0, 0);
        }
        __syncthreads();
#pragma unroll
        for (int kk = 0; kk < 64; kk += 32) {
            short8 a[4], b[4];
#pragma unroll
            for (int m = 0; m < 4; ++m)
                a[m] = *(const short8*)&As[(m * 16 + fr) * 64 + kk + fk];
#pragma unroll
            for (int n = 0; n < 4; ++n)
                b[n] = *(const short8*)&Bs[(wn + n * 16 + fr) * 64 + kk + fk];
#pragma unroll
            for (int m = 0; m < 4; ++m)
#pragma unroll
                for (int n = 0; n < 4; ++n)
                    acc[m][n] = __builtin_amdgcn_mfma_f32_16x16x32_bf16(a[m], b[n], acc[m][n], 0, 0, 0);
        }
    }
    int fcol = lane & 15, frow4 = (lane >> 4) * 4;
#pragma unroll
    for (int m = 0; m < 4; ++m) {
#pragma unroll
        for (int i = 0; i < 4; ++i) {
            float vs1 = 0.f, vs2 = 0.f;
#pragma unroll
            for (int n = 0; n < 4; ++n) {
                float vv = acc[m][n][i] + bias[wn + n * 16 + fcol];
                acc[m][n][i] = vv;
                vs1 += vv; vs2 += vv * vv;
            }
#pragma unroll
            for (int o = 1; o < 16; o <<= 1) {
                vs1 += __shfl_xor(vs1, o);
                vs2 += __shfl_xor(vs2, o);
            }
            if (fcol == 0) {
                redS1[w][m * 16 + frow4 + i] = vs1;
                redS2[w][m * 16 + frow4 + i] = vs2;
            }
        }
    }
    __syncthreads();
    if (t < 64) {
        float s1 = redS1[0][t] + redS1[1][t] + redS1[2][t] + redS1[3][t];
        float s2 = redS2[0][t] + redS2[1][t] + redS2[2][t] + redS2[3][t];
        float mu = s1 / 256.f;
        float var = fmaxf((s2 - 256.f * mu * mu) / 255.f, 0.f);
        muS[t] = mu;
        invS[t] = 1.f / (sqrtf(var) + 1e-6f);
    }
    __syncthreads();
#pragma unroll
    for (int m = 0; m < 4; ++m) {
#pragma unroll
        for (int i = 0; i < 4; ++i) {
            int r = m * 16 + frow4 + i;
            int gr = gm0 + r;
            if (gr >= M) continue;
            float mu = muS[r], inv = invS[r];
#pragma unroll
            for (int n = 0; n < 4; ++n) {
                int gc = wn + n * 16 + fcol;
                float y = gamma[gc] * (acc[m][n][i] - mu) * inv + beta[gc];
                y = y > 0.f ? y : 0.01f * y;
                out[(size_t)gr * D + gc] = nf_in[(size_t)gr * D + gc] + y;
            }
        }
    }
}

// ---------------- edge-attention projection, CSR-ordered output ----------------
// wave = 16 CSR slots; A row r = ew row of edge eid[p0+r] (random 256B, read once);
// writes eA1c/eA2c directly in CSR order (no intermediate, no permute pass).
__global__ __launch_bounds__(256) void ealpha_mfma_kernel(
    const float* __restrict__ ew, const int* __restrict__ eid,
    const unsigned short* __restrict__ MeT,
    float* __restrict__ eA1c, float* __restrict__ eA2c, int E) {
    int t = threadIdx.x;
    int lane = t & 63, w = t >> 6;
    int p0 = blockIdx.x * 64 + w * 16;
    int r = lane & 15, g = lane >> 4;
    int pr = p0 + r; if (pr > E - 1) pr = E - 1;
    int er = eid[pr];
    const float* rowp = ew + (size_t)er * DE;
    float4 x0 = *(const float4*)&rowp[g * 8];
    float4 x1 = *(const float4*)&rowp[g * 8 + 4];
    float4 y0 = *(const float4*)&rowp[32 + g * 8];
    float4 y1 = *(const float4*)&rowp[32 + g * 8 + 4];
    short8 a0, a1;
    a0[0] = (short)f2b(x0.x); a0[1] = (short)f2b(x0.y); a0[2] = (short)f2b(x0.z); a0[3] = (short)f2b(x0.w);
    a0[4] = (short)f2b(x1.x); a0[5] = (short)f2b(x1.y); a0[6] = (short)f2b(x1.z); a0[7] = (short)f2b(x1.w);
    a1[0] = (short)f2b(y0.x); a1[1] = (short)f2b(y0.y); a1[2] = (short)f2b(y0.z); a1[3] = (short)f2b(y0.w);
    a1[4] = (short)f2b(y1.x); a1[5] = (short)f2b(y1.y); a1[6] = (short)f2b(y1.z); a1[7] = (short)f2b(y1.w);
    short8 b0 = *(const short8*)&MeT[r * 64 + g * 8];
    short8 b1 = *(const short8*)&MeT[r * 64 + 32 + g * 8];
    f32x4 acc = {};
    acc = __builtin_amdgcn_mfma_f32_16x16x32_bf16(a0, b0, acc, 0, 0, 0);
    acc = __builtin_amdgcn_mfma_f32_16x16x32_bf16(a1, b1, acc, 0, 0, 0);
    // lane (r,g) holds results for head r, slots p0+g*4+i
#pragma unroll
    for (int i = 0; i < 4; ++i) {
        int p = p0 + g * 4 + i;
        if (p < E) {
            if (r < 8) eA1c[(size_t)p * 8 + r] = acc[i];
            else       eA2c[(size_t)p * 8 + (r - 8)] = acc[i];
        }
    }
}

// ---------------- GAT: wave-per-node gather + softmax + fused LN/leaky/residual ----------------
// 4 nodes/block (1 wave each). Lane owns features lane*4..lane*4+3.
// Producer role: slot hw, head h=lane&7; metadata prefetched 1 deep.
// Per batch: shfl all 8 src, ISSUE all 8 row loads, then exp, then fma (max MLP).
__global__ __launch_bounds__(256) void gat_node_kernel(
    const int* __restrict__ off, const int* __restrict__ src_csr,
    const float* __restrict__ eAc,
    const float* __restrict__ asrc, const float* __restrict__ adst,
    const unsigned short* __restrict__ xsb, const float* __restrict__ nf_in,
    const float* __restrict__ bias, const float* __restrict__ gamma,
    const float* __restrict__ beta, float* __restrict__ nf_out,
    unsigned short* __restrict__ nf_out_b, int N) {
    int lane = threadIdx.x & 63;
    int n = blockIdx.x * 4 + (threadIdx.x >> 6);
    if (n >= N) return;
    int e0 = off[n], e1 = off[n + 1], deg = e1 - e0;
    int h = lane & 7;
    int hw = lane >> 3;

    float adstn = adst[n * 8 + h];
    float asn = asrc[n * 8 + h];

    float acc0 = 0.f, acc1 = 0.f, acc2 = 0.f, acc3 = 0.f;
    float den0 = 0.f, easum = 0.f;
    int nb8 = (deg + 7) >> 3;

    bool act = hw < deg;
    int sp = e0 + hw;
    int s_cur = act ? src_csr[sp] : n;
    float ea_cur = act ? eAc[(size_t)sp * 8 + h] : 0.f;
    float as_cur = act ? asrc[s_cur * 8 + h] : 0.f;

    for (int it = 0; it < nb8; ++it) {
        int base = it * 8;
        int lim = deg - base; if (lim > 8) lim = 8;

        if (lim == 8) {
            // 1) broadcast src indices, issue all 8 row loads
            int sk[8];
#pragma unroll
            for (int kk = 0; kk < 8; ++kk) sk[kk] = __shfl(s_cur, kk * 8 + hw);
            ushort4 u[8];
#pragma unroll
            for (int kk = 0; kk < 8; ++kk)
                u[kk] = *(const ushort4*)&xsb[(size_t)sk[kk] * D + lane * 4];
            // 2) metadata prefetch for next batch (independent of loads above)
            bool actn = (base + 8 + hw) < deg;
            int spn = e0 + base + 8 + hw;
            int s_nx = actn ? src_csr[spn] : n;
            float ea_nx = actn ? eAc[(size_t)spn * 8 + h] : 0.f;
            float as_nx = actn ? asrc[s_nx * 8 + h] : 0.f;
            // 3) alpha -> exp
            float al = as_cur + adstn + ea_cur;
            al = al > 0.f ? al : 0.2f * al;
            float ex = act ? expf(al) : 0.f;
            den0 += ex;
            easum += ea_cur;
            float exk[8];
#pragma unroll
            for (int kk = 0; kk < 8; ++kk) exk[kk] = __shfl(ex, kk * 8 + hw);
            // 4) fma (waits on row loads here)
#pragma unroll
            for (int kk = 0; kk < 8; ++kk) {
                acc0 = fmaf(exk[kk], b2f(u[kk].x), acc0);
                acc1 = fmaf(exk[kk], b2f(u[kk].y), acc1);
                acc2 = fmaf(exk[kk], b2f(u[kk].z), acc2);
                acc3 = fmaf(exk[kk], b2f(u[kk].w), acc3);
            }
            s_cur = s_nx; ea_cur = ea_nx; as_cur = as_nx; act = actn;
        } else {
            float al = as_cur + adstn + ea_cur;
            al = al > 0.f ? al : 0.2f * al;
            float ex = act ? expf(al) : 0.f;
            den0 += ex;
            easum += ea_cur;
            for (int kk = 0; kk < lim; ++kk) {
                int sl = kk * 8 + hw;
                float exk = __shfl(ex, sl);
                int skk = __shfl(s_cur, sl);
                ushort4 u = *(const ushort4*)&xsb[(size_t)skk * D + lane * 4];
                acc0 = fmaf(exk, b2f(u.x), acc0);
                acc1 = fmaf(exk, b2f(u.y), acc1);
                acc2 = fmaf(exk, b2f(u.z), acc2);
                acc3 = fmaf(exk, b2f(u.w), acc3);
            }
            act = false;
        }
    }
    den0  += __shfl_xor(den0, 8);
    den0  += __shfl_xor(den0, 16);
    den0  += __shfl_xor(den0, 32);
    easum += __shfl_xor(easum, 8);
    easum += __shfl_xor(easum, 16);
    easum += __shfl_xor(easum, 32);
    float sa = easum / (float)(deg > 0 ? deg : 1);
    float als = asn + adstn + sa;
    als = als > 0.f ? als : 0.2f * als;
    float exSelf = expf(als);
    {
        float exs = __shfl(exSelf, hw);
        ushort4 u = *(const ushort4*)&xsb[(size_t)n * D + lane * 4];
        acc0 = fmaf(exs, b2f(u.x), acc0);
        acc1 = fmaf(exs, b2f(u.y), acc1);
        acc2 = fmaf(exs, b2f(u.z), acc2);
        acc3 = fmaf(exs, b2f(u.w), acc3);
    }
    den0 += exSelf;
    float denOwn = __shfl(den0, hw);
    float inv = 1.f / (denOwn + 1e-16f);

    int t0 = lane * 4;
    float4 bi = *(const float4*)&bias[t0];
    float o0 = acc0 * inv + bi.x;
    float o1 = acc1 * inv + bi.y;
    float o2 = acc2 * inv + bi.z;
    float o3 = acc3 * inv + bi.w;

    float s1 = o0 + o1 + o2 + o3;
    float s2 = o0 * o0 + o1 * o1 + o2 * o2 + o3 * o3;
    for (int o = 1; o < 64; o <<= 1) { s1 += __shfl_xor(s1, o); s2 += __shfl_xor(s2, o); }
    float mu = s1 / 256.f;
    float var = fmaxf((s2 - 256.f * mu * mu) / 255.f, 0.f);
    float sdv = sqrtf(var) + 1e-6f;
    float4 ga = *(const float4*)&gamma[t0];
    float4 be = *(const float4*)&beta[t0];
    float4 nin = *(const float4*)&nf_in[(size_t)n * D + t0];
    float y0 = ga.x * (o0 - mu) / sdv + be.x; y0 = y0 > 0.f ? y0 : 0.01f * y0;
    float y1 = ga.y * (o1 - mu) / sdv + be.y; y1 = y1 > 0.f ? y1 : 0.01f * y1;
    float y2 = ga.z * (o2 - mu) / sdv + be.z; y2 = y2 > 0.f ? y2 : 0.01f * y2;
    float y3 = ga.w * (o3 - mu) / sdv + be.w; y3 = y3 > 0.f ? y3 : 0.01f * y3;
    float r0 = nin.x + y0, r1 = nin.y + y1, r2 = nin.z + y2, r3 = nin.w + y3;
    float4 outv; outv.x = r0; outv.y = r1; outv.z = r2; outv.w = r3;
    *(float4*)&nf_out[(size_t)n * D + t0] = outv;
    ushort4 ob; ob.x = f2b(r0); ob.y = f2b(r1); ob.z = f2b(r2); ob.w = f2b(r3);
    *(ushort4*)&nf_out_b[(size_t)n * D + t0] = ob;
}

extern "C" void kernel_launch(void* const* d_in, const int* in_sizes, int n_in,
                              void* d_out, int out_size, void* d_ws, size_t ws_size,
                              hipStream_t stream) {
    const float* nf0    = (const float*)d_in[0];
    const int*   ei     = (const int*)d_in[1];
    const float* ew     = (const float*)d_in[2];
    const float* lin1   = (const float*)d_in[3];
    const float* le1    = (const float*)d_in[4];
    const float* asrc1w = (const float*)d_in[5];
    const float* adst1w = (const float*)d_in[6];
    const float* aedge1 = (const float*)d_in[7];
    const float* b1     = (const float*)d_in[8];
    const float* lin2   = (const float*)d_in[9];
    const float* le2    = (const float*)d_in[10];
    const float* asrc2w = (const float*)d_in[11];
    const float* adst2w = (const float*)d_in[12];
    const float* aedge2 = (const float*)d_in[13];
    const float* b2     = (const float*)d_in[14];
    const float* g1     = (const float*)d_in[15];
    const float* be1    = (const float*)d_in[16];
    const float* g2     = (const float*)d_in[17];
    const float* be2    = (const float*)d_in[18];
    const float* g3     = (const float*)d_in[19];
    const float* be3    = (const float*)d_in[20];
    const float* w1     = (const float*)d_in[21];
    const float* fb1    = (const float*)d_in[22];
    const float* w2     = (const float*)d_in[23];
    const float* fb2    = (const float*)d_in[24];

    const int N = in_sizes[0] / D;
    const int E = in_sizes[1] / 2;
    const int Mpad = ((N + 127) / 128) * 128;
    const int* srcI = ei;
    const int* dstI = ei + E;

    char* ws = (char*)d_ws;
    size_t ob = 0;
    auto alloc = [&](size_t bytes) { void* p = ws + ob; ob = align_up(ob + bytes, 256); return p; };
    // --- arena0: dead after GAT layer 2; start reused as FFN hidden (bf16, Mpad*DF*2 = 20.7MB) ---
    int*   deg     = (int*)alloc((size_t)N * 4);
    int*   csr_off = (int*)alloc((size_t)(N + 1) * 4);
    int*   cursor  = (int*)alloc((size_t)N * 4);
    int*   part    = (int*)alloc(1024);
    int*   eid     = (int*)alloc((size_t)E * 4);
    int*   src_csr = (int*)alloc((size_t)E * 4);
    unsigned short* MeT = (unsigned short*)alloc(16 * 64 * 2);
    float* asrcB   = (float*)alloc((size_t)N * H * 4);
    float* adstB   = (float*)alloc((size_t)N * H * 4);
    float* eA1c    = (float*)alloc((size_t)E * H * 4);
    float* eA2c    = (float*)alloc((size_t)E * H * 4);
    // --- persistent ---
    float* nfw     = (float*)alloc((size_t)N * D * 4);
    unsigned short* xs_b  = (unsigned short*)alloc((size_t)Mpad * D * 2);
    unsigned short* Abf   = (unsigned short*)alloc((size_t)Mpad * D * 2);
    unsigned short* lin1T = (unsigned short*)alloc((size_t)D * D * 2);
    unsigned short* lin2T = (unsigned short*)alloc((size_t)D * D * 2);
    unsigned short* w1T   = (unsigned short*)alloc((size_t)DF * D * 2);
    unsigned short* w2T   = (unsigned short*)alloc((size_t)D * DF * 2);
    unsigned short* hidden = (unsigned short*)ws;  // aliases arena0 (dead by FFN)
    (void)ws_size;
    float* out = (float*)d_out;

    hipMemsetAsync(deg, 0, (size_t)N * 4, stream);

    int eb = (E + 255) / 256;
    int nb = (N + 255) / 256;
    deg_kernel<<<eb, 256, 0, stream>>>(dstI, deg, E);
    partial_sum_kernel<<<nb, 256, 0, stream>>>(deg, part, N);
    scan_part_kernel<<<1, 256, 0, stream>>>(part, nb);
    scan_final_kernel<<<nb, 256, 0, stream>>>(deg, part, csr_off, cursor, N);
    fill_kernel<<<eb, 256, 0, stream>>>(srcI, dstI, cursor, eid, src_csr, E);

    const size_t nvalid = (size_t)N * D, ntot = (size_t)Mpad * D;
    int cb = (int)((ntot / 8 + 255) / 256);
    prep_kernel<<<641 + cb, 256, 0, stream>>>(lin1, lin2, w1, w2, le1, aedge1, le2, aedge2, nf0,
                                              lin1T, lin2T, w1T, w2T, MeT, Abf, nvalid, ntot);
    ealpha_mfma_kernel<<<(E + 63) / 64, 256, 0, stream>>>(ew, eid, MeT, eA1c, eA2c, E);

    int gatb = (N + 3) / 4;

    // ---- GAT layer 1 ----
    mfma_gemm_kernel<64><<<dim3(Mpad / 64, 2), 256, 0, stream>>>(
        Abf, lin1T, nullptr, nullptr, xs_b, N, D, D, 0, asrc1w, adst1w, asrcB, adstB);
    gat_node_kernel<<<gatb, 256, 0, stream>>>(csr_off, src_csr, eA1c, asrcB, adstB,
                                              xs_b, nf0, b1, g1, be1, nfw, Abf, N);
    // ---- GAT layer 2 ----
    mfma_gemm_kernel<64><<<dim3(Mpad / 64, 2), 256, 0, stream>>>(
        Abf, lin2T, nullptr, nullptr, xs_b, N, D, D, 0, asrc2w, adst2w, asrcB, adstB);
    gat_node_kernel<<<gatb, 256, 0, stream>>>(csr_off, src_csr, eA2c, asrcB, adstB,
                                              xs_b, nfw, b2, g2, be2, nfw, Abf, N);
    // ---- FFN: hidden = relu(Abf@w1+fb1) for ALL Mpad rows (pad rows are zero -> relu(fb1)) ----
    mfma_gemm_kernel<128><<<dim3(Mpad / 128, 8), 256, 0, stream>>>(
        Abf, w1T, fb1, nullptr, hidden, Mpad, DF, D, 1, nullptr, nullptr, nullptr, nullptr);
    // ---- FFN2 + LN + residual + output, fused ----
    ffn2_ln_kernel<<<(N + 63) / 64, 256, 0, stream>>>(hidden, w2T, fb2, nfw, g3, be3, out, N);
}

// Round 9
// 238.377 us; speedup vs baseline: 2.2701x; 1.0024x over previous
//
#include <hip/hip_runtime.h>
#include <hip/hip_bf16.h>
#include <math.h>

#define D 256
#define H 8
#define C 32
#define DE 64
#define DF 1024

static inline size_t align_up(size_t x, size_t a) { return (x + a - 1) / a * a; }

typedef __attribute__((ext_vector_type(8))) short short8;
typedef __attribute__((ext_vector_type(4))) float f32x4;

__device__ inline unsigned short f2b(float x) {
    __hip_bfloat16 h = __float2bfloat16(x);
    return *reinterpret_cast<unsigned short*>(&h);
}
__device__ inline float b2f(unsigned short u) {
    return __uint_as_float(((unsigned int)u) << 16);
}

// ---------------- CSR build ----------------
__global__ void deg_kernel(const int* __restrict__ dst, int* __restrict__ deg, int E) {
    int e = blockIdx.x * 256 + threadIdx.x;
    if (e < E) atomicAdd(&deg[dst[e]], 1);
}

__global__ void partial_sum_kernel(const int* __restrict__ deg, int* __restrict__ part, int n) {
    int i = blockIdx.x * 256 + threadIdx.x;
    int v = (i < n) ? deg[i] : 0;
    for (int o = 1; o < 64; o <<= 1) v += __shfl_xor(v, o);
    __shared__ int w4[4];
    if ((threadIdx.x & 63) == 0) w4[threadIdx.x >> 6] = v;
    __syncthreads();
    if (threadIdx.x == 0) part[blockIdx.x] = w4[0] + w4[1] + w4[2] + w4[3];
}

__global__ void scan_part_kernel(int* __restrict__ part, int nb) {
    __shared__ int buf[256];
    int t = threadIdx.x;
    buf[t] = (t < nb) ? part[t] : 0;
    __syncthreads();
    for (int s = 1; s < 256; s <<= 1) {
        int v = (t >= s) ? buf[t - s] : 0;
        __syncthreads();
        buf[t] += v;
        __syncthreads();
    }
    int excl = (t == 0) ? 0 : buf[t - 1];
    if (t < nb) part[t] = excl;
}

__global__ void scan_final_kernel(const int* __restrict__ deg, const int* __restrict__ part,
                                  int* __restrict__ off, int* __restrict__ cursor, int n) {
    int b = blockIdx.x, t = threadIdx.x, i = b * 256 + t;
    __shared__ int buf[256];
    int v = (i < n) ? deg[i] : 0;
    buf[t] = v;
    __syncthreads();
    for (int s = 1; s < 256; s <<= 1) {
        int x = (t >= s) ? buf[t - s] : 0;
        __syncthreads();
        buf[t] += x;
        __syncthreads();
    }
    int excl = part[b] + buf[t] - v;
    if (i < n) { off[i] = excl; cursor[i] = excl; }
    if (i == n - 1) off[n] = excl + v;
}

// writes eid[p] (edge at CSR slot p) and src_csr[p] (source node of slot p)
__global__ void fill_kernel(const int* __restrict__ src, const int* __restrict__ dst,
                            int* __restrict__ cursor, int* __restrict__ eid,
                            int* __restrict__ src_csr, int E) {
    int e = blockIdx.x * 256 + threadIdx.x;
    if (e < E) {
        int p = atomicAdd(&cursor[dst[e]], 1);
        eid[p] = e;
        src_csr[p] = src[e];
    }
}

// ---------------- prep: 4 weight transposes + MeT + nf0->bf16 convert, one dispatch ----------------
__global__ void prep_kernel(const float* __restrict__ lin1, const float* __restrict__ lin2,
                            const float* __restrict__ w1, const float* __restrict__ w2,
                            const float* __restrict__ le1, const float* __restrict__ ae1,
                            const float* __restrict__ le2, const float* __restrict__ ae2,
                            const float* __restrict__ nf0,
                            unsigned short* __restrict__ lin1T, unsigned short* __restrict__ lin2T,
                            unsigned short* __restrict__ w1T, unsigned short* __restrict__ w2T,
                            unsigned short* __restrict__ MeT, unsigned short* __restrict__ Abf,
                            size_t n_valid, size_t n_total) {
    int b = blockIdx.x;
    if (b > 640) {  // convert nf0 -> Abf (bf16), pad rows zeroed
        size_t i = ((size_t)(b - 641) * 256 + threadIdx.x) * 8;
        if (i >= n_total) return;
        ushort4 o0, o1;
        if (i < n_valid) {
            float4 a = *(const float4*)&nf0[i];
            float4 bb = *(const float4*)&nf0[i + 4];
            o0.x = f2b(a.x); o0.y = f2b(a.y); o0.z = f2b(a.z); o0.w = f2b(a.w);
            o1.x = f2b(bb.x); o1.y = f2b(bb.y); o1.z = f2b(bb.z); o1.w = f2b(bb.w);
        } else {
            o0.x = o0.y = o0.z = o0.w = 0;
            o1 = o0;
        }
        *(ushort4*)&Abf[i] = o0;
        *(ushort4*)&Abf[i + 4] = o1;
        return;
    }
    if (b == 640) {  // MeT[c][d]: c<8 -> layer1 head c; c>=8 -> layer2 head c-8
        for (int t = threadIdx.x; t < 512; t += 256) {
            int d = t >> 3, h = t & 7;
            float s1 = 0.f, s2 = 0.f;
            for (int c = 0; c < C; ++c) {
                s1 += le1[d * (H * C) + h * C + c] * ae1[h * C + c];
                s2 += le2[d * (H * C) + h * C + c] * ae2[h * C + c];
            }
            MeT[h * 64 + d] = f2b(s1);
            MeT[(8 + h) * 64 + d] = f2b(s2);
        }
        return;
    }
    __shared__ float tile[32][33];
    const float* in; unsigned short* outp; int K, N, tt;
    if (b < 64)       { in = lin1; outp = lin1T; K = D;  N = D;  tt = b; }
    else if (b < 128) { in = lin2; outp = lin2T; K = D;  N = D;  tt = b - 64; }
    else if (b < 384) { in = w1;   outp = w1T;   K = D;  N = DF; tt = b - 128; }
    else              { in = w2;   outp = w2T;   K = DF; N = D;  tt = b - 384; }
    int ntn = N >> 5;
    int bn = (tt % ntn) * 32, bk = (tt / ntn) * 32;
    int tx = threadIdx.x & 31, ty = threadIdx.x >> 5;
    for (int i = ty; i < 32; i += 8)
        tile[i][tx] = in[(size_t)(bk + i) * N + bn + tx];
    __syncthreads();
    for (int i = ty; i < 32; i += 8)
        outp[(size_t)(bn + i) * K + bk + tx] = f2b(tile[tx][i]);
}

// ---------------- bf16 MFMA GEMM: C = A[MxK] @ BT[NxK]^T (+bias)(+relu) ----------------
template<int BM>
__global__ __launch_bounds__(256) void mfma_gemm_kernel(
    const unsigned short* __restrict__ A, const unsigned short* __restrict__ BT,
    const float* __restrict__ bias, float* __restrict__ Cf, unsigned short* __restrict__ Cb,
    int M, int Nc, int K, int relu,
    const float* __restrict__ a_s, const float* __restrict__ a_d,
    float* __restrict__ asrcO, float* __restrict__ adstO) {
    constexpr int NR = (BM == 128) ? 4 : 2;
    constexpr int AI = BM / 32;
    __shared__ unsigned short As[BM * 64];
    __shared__ unsigned short Bs[128 * 64];
    int t = threadIdx.x;
    int lane = t & 63, w = t >> 6;
    int gm0 = blockIdx.x * BM, gn0 = blockIdx.y * 128;
    f32x4 acc[4][NR] = {};
    int srow = lane >> 3, scol = (lane & 7) * 8;
    int wm = (BM == 128) ? (w >> 1) * 64 : 0;
    int wn = (BM == 128) ? (w & 1) * 64 : w * 32;
    int fr = lane & 15, fk = (lane >> 4) * 8;

    for (int k0 = 0; k0 < K; k0 += 64) {
        __syncthreads();
#pragma unroll
        for (int i = 0; i < AI; ++i) {
            int rb = w * (8 * AI) + i * 8;
            const unsigned short* ga = A + (size_t)(gm0 + rb + srow) * K + k0 + scol;
            __builtin_amdgcn_global_load_lds(
                (const __attribute__((address_space(1))) unsigned int*)ga,
                (__attribute__((address_space(3))) unsigned int*)&As[rb * 64], 16, 0, 0);
        }
#pragma unroll
        for (int i = 0; i < 4; ++i) {
            int rb = w * 32 + i * 8;
            const unsigned short* gb = BT + (size_t)(gn0 + rb + srow) * K + k0 + scol;
            __builtin_amdgcn_global_load_lds(
                (const __attribute__((address_space(1))) unsigned int*)gb,
                (__attribute__((address_space(3))) unsigned int*)&Bs[rb * 64], 16, 0, 0);
        }
        __syncthreads();
#pragma unroll
        for (int kk = 0; kk < 64; kk += 32) {
            short8 a[4], b[NR];
#pragma unroll
            for (int m = 0; m < 4; ++m)
                a[m] = *(const short8*)&As[(wm + m * 16 + fr) * 64 + kk + fk];
#pragma unroll
            for (int n = 0; n < NR; ++n)
                b[n] = *(const short8*)&Bs[(wn + n * 16 + fr) * 64 + kk + fk];
#pragma unroll
            for (int m = 0; m < 4; ++m)
#pragma unroll
                for (int n = 0; n < NR; ++n)
                    acc[m][n] = __builtin_amdgcn_mfma_f32_16x16x32_bf16(a[m], b[n], acc[m][n], 0, 0, 0);
        }
    }
    int fcol = lane & 15, frow4 = (lane >> 4) * 4;
#pragma unroll
    for (int m = 0; m < 4; ++m) {
#pragma unroll
        for (int i = 0; i < 4; ++i) {
            int gr = gm0 + wm + m * 16 + frow4 + i;
            if (gr >= M) continue;
#pragma unroll
            for (int n = 0; n < NR; ++n) {
                int gc = gn0 + wn + n * 16 + fcol;
                float v = acc[m][n][i];
                if (bias) v += bias[gc];
                if (relu) v = fmaxf(v, 0.f);
                if (Cb) Cb[(size_t)gr * Nc + gc] = f2b(v);
                else    Cf[(size_t)gr * Nc + gc] = v;
            }
        }
    }
    if (BM == 64 && a_s) {
        int head = (gn0 >> 5) + w;
        float as0 = a_s[head * 32 + fcol], as1 = a_s[head * 32 + 16 + fcol];
        float ad0 = a_d[head * 32 + fcol], ad1 = a_d[head * 32 + 16 + fcol];
#pragma unroll
        for (int m = 0; m < 4; ++m) {
#pragma unroll
            for (int i = 0; i < 4; ++i) {
                float vs = acc[m][0][i] * as0 + acc[m][1][i] * as1;
                float vd = acc[m][0][i] * ad0 + acc[m][1][i] * ad1;
#pragma unroll
                for (int o = 1; o < 16; o <<= 1) {
                    vs += __shfl_xor(vs, o);
                    vd += __shfl_xor(vd, o);
                }
                int r = gm0 + m * 16 + frow4 + i;
                if (fcol == 0 && r < M) {
                    asrcO[r * 8 + head] = vs;
                    adstO[r * 8 + head] = vd;
                }
            }
        }
    }
}

// ---------------- FFN2 + LN + leaky + residual, fully fused ----------------
__global__ __launch_bounds__(256) void ffn2_ln_kernel(
    const unsigned short* __restrict__ A, const unsigned short* __restrict__ BT,
    const float* __restrict__ bias, const float* __restrict__ nf_in,
    const float* __restrict__ gamma, const float* __restrict__ beta,
    float* __restrict__ out, int M) {
    __shared__ unsigned short As[64 * 64];
    __shared__ unsigned short Bs[256 * 64];
    __shared__ float redS1[4][64], redS2[4][64];
    __shared__ float muS[64], invS[64];
    int t = threadIdx.x, lane = t & 63, w = t >> 6;
    int gm0 = blockIdx.x * 64;
    f32x4 acc[4][4] = {};
    int srow = lane >> 3, scol = (lane & 7) * 8;
    int wn = w * 64;
    int fr = lane & 15, fk = (lane >> 4) * 8;
    for (int k0 = 0; k0 < DF; k0 += 64) {
        __syncthreads();
#pragma unroll
        for (int i = 0; i < 2; ++i) {
            int rb = w * 16 + i * 8;
            const unsigned short* ga = A + (size_t)(gm0 + rb + srow) * DF + k0 + scol;
            __builtin_amdgcn_global_load_lds(
                (const __attribute__((address_space(1))) unsigned int*)ga,
                (__attribute__((address_space(3))) unsigned int*)&As[rb * 64], 16, 0, 0);
        }
#pragma unroll
        for (int i = 0; i < 8; ++i) {
            int rb = w * 64 + i * 8;
            const unsigned short* gb = BT + (size_t)(rb + srow) * DF + k0 + scol;
            __builtin_amdgcn_global_load_lds(
                (const __attribute__((address_space(1))) unsigned int*)gb,
                (__attribute__((address_space(3))) unsigned int*)&Bs[rb * 64], 16, 0, 0);
        }
        __syncthreads();
#pragma unroll
        for (int kk = 0; kk < 64; kk += 32) {
            short8 a[4], b[4];
#pragma unroll
            for (int m = 0; m < 4; ++m)
                a[m] = *(const short8*)&As[(m * 16 + fr) * 64 + kk + fk];
#pragma unroll
            for (int n = 0; n < 4; ++n)
                b[n] = *(const short8*)&Bs[(wn + n * 16 + fr) * 64 + kk + fk];
#pragma unroll
            for (int m = 0; m < 4; ++m)
#pragma unroll
                for (int n = 0; n < 4; ++n)
                    acc[m][n] = __builtin_amdgcn_mfma_f32_16x16x32_bf16(a[m], b[n], acc[m][n], 0, 0, 0);
        }
    }
    int fcol = lane & 15, frow4 = (lane >> 4) * 4;
#pragma unroll
    for (int m = 0; m < 4; ++m) {
#pragma unroll
        for (int i = 0; i < 4; ++i) {
            float vs1 = 0.f, vs2 = 0.f;
#pragma unroll
            for (int n = 0; n < 4; ++n) {
                float vv = acc[m][n][i] + bias[wn + n * 16 + fcol];
                acc[m][n][i] = vv;
                vs1 += vv; vs2 += vv * vv;
            }
#pragma unroll
            for (int o = 1; o < 16; o <<= 1) {
                vs1 += __shfl_xor(vs1, o);
                vs2 += __shfl_xor(vs2, o);
            }
            if (fcol == 0) {
                redS1[w][m * 16 + frow4 + i] = vs1;
                redS2[w][m * 16 + frow4 + i] = vs2;
            }
        }
    }
    __syncthreads();
    if (t < 64) {
        float s1 = redS1[0][t] + redS1[1][t] + redS1[2][t] + redS1[3][t];
        float s2 = redS2[0][t] + redS2[1][t] + redS2[2][t] + redS2[3][t];
        float mu = s1 / 256.f;
        float var = fmaxf((s2 - 256.f * mu * mu) / 255.f, 0.f);
        muS[t] = mu;
        invS[t] = 1.f / (sqrtf(var) + 1e-6f);
    }
    __syncthreads();
#pragma unroll
    for (int m = 0; m < 4; ++m) {
#pragma unroll
        for (int i = 0; i < 4; ++i) {
            int r = m * 16 + frow4 + i;
            int gr = gm0 + r;
            if (gr >= M) continue;
            float mu = muS[r], inv = invS[r];
#pragma unroll
            for (int n = 0; n < 4; ++n) {
                int gc = wn + n * 16 + fcol;
                float y = gamma[gc] * (acc[m][n][i] - mu) * inv + beta[gc];
                y = y > 0.f ? y : 0.01f * y;
                out[(size_t)gr * D + gc] = nf_in[(size_t)gr * D + gc] + y;
            }
        }
    }
}

// ---------------- edge-attention projection, CSR-ordered output ----------------
__global__ __launch_bounds__(256) void ealpha_mfma_kernel(
    const float* __restrict__ ew, const int* __restrict__ eid,
    const unsigned short* __restrict__ MeT,
    float* __restrict__ eA1c, float* __restrict__ eA2c, int E) {
    int t = threadIdx.x;
    int lane = t & 63, w = t >> 6;
    int p0 = blockIdx.x * 64 + w * 16;
    int r = lane & 15, g = lane >> 4;
    int pr = p0 + r; if (pr > E - 1) pr = E - 1;
    int er = eid[pr];
    const float* rowp = ew + (size_t)er * DE;
    float4 x0 = *(const float4*)&rowp[g * 8];
    float4 x1 = *(const float4*)&rowp[g * 8 + 4];
    float4 y0 = *(const float4*)&rowp[32 + g * 8];
    float4 y1 = *(const float4*)&rowp[32 + g * 8 + 4];
    short8 a0, a1;
    a0[0] = (short)f2b(x0.x); a0[1] = (short)f2b(x0.y); a0[2] = (short)f2b(x0.z); a0[3] = (short)f2b(x0.w);
    a0[4] = (short)f2b(x1.x); a0[5] = (short)f2b(x1.y); a0[6] = (short)f2b(x1.z); a0[7] = (short)f2b(x1.w);
    a1[0] = (short)f2b(y0.x); a1[1] = (short)f2b(y0.y); a1[2] = (short)f2b(y0.z); a1[3] = (short)f2b(y0.w);
    a1[4] = (short)f2b(y1.x); a1[5] = (short)f2b(y1.y); a1[6] = (short)f2b(y1.z); a1[7] = (short)f2b(y1.w);
    short8 b0 = *(const short8*)&MeT[r * 64 + g * 8];
    short8 b1 = *(const short8*)&MeT[r * 64 + 32 + g * 8];
    f32x4 acc = {};
    acc = __builtin_amdgcn_mfma_f32_16x16x32_bf16(a0, b0, acc, 0, 0, 0);
    acc = __builtin_amdgcn_mfma_f32_16x16x32_bf16(a1, b1, acc, 0, 0, 0);
#pragma unroll
    for (int i = 0; i < 4; ++i) {
        int p = p0 + g * 4 + i;
        if (p < E) {
            if (r < 8) eA1c[(size_t)p * 8 + r] = acc[i];
            else       eA2c[(size_t)p * 8 + (r - 8)] = acc[i];
        }
    }
}

// ---------------- GAT: wave-per-node, 3-gen pipelined gather + fused LN ----------------
// 4 nodes/block (1 wave each). Lane owns features lane*4..lane*4+3.
// Pipeline: src/eA meta 2 batches ahead; dependent asrc 1 ahead; row loads 1 ahead (uA/uB).
// Inactive slots (tail) load row n with weight 0 — uniform path, no divergence.
__global__ __launch_bounds__(256) void gat_node_kernel(
    const int* __restrict__ off, const int* __restrict__ src_csr,
    const float* __restrict__ eAc,
    const float* __restrict__ asrc, const float* __restrict__ adst,
    const unsigned short* __restrict__ xsb, const float* __restrict__ nf_in,
    const float* __restrict__ bias, const float* __restrict__ gamma,
    const float* __restrict__ beta, float* __restrict__ nf_out,
    unsigned short* __restrict__ nf_out_b, int N) {
    int lane = threadIdx.x & 63;
    int n = blockIdx.x * 4 + (threadIdx.x >> 6);
    if (n >= N) return;
    int e0 = off[n], e1 = off[n + 1], deg = e1 - e0;
    int h = lane & 7;
    int hw = lane >> 3;

    float adstn = adst[n * 8 + h];
    float asn = asrc[n * 8 + h];

    float acc0 = 0.f, acc1 = 0.f, acc2 = 0.f, acc3 = 0.f;
    float den0 = 0.f, easum = 0.f;
    int nb8 = (deg + 7) >> 3;

#define LOAD_SE(b, S, EA, A) { A = ((b) * 8 + hw) < deg; int sp_ = e0 + (b) * 8 + hw; \
    S = A ? src_csr[sp_] : n; EA = A ? eAc[(size_t)sp_ * 8 + h] : 0.f; }

    if (nb8 > 0) {
        // ---- prologue: meta gens 0,1,2; asrc 0,1; rows batch0 -> uA ----
        int s0, s1, s2; float ea0, ea1, ea2; bool a0, a1, a2;
        LOAD_SE(0, s0, ea0, a0);
        LOAD_SE(1, s1, ea1, a1);
        LOAD_SE(2, s2, ea2, a2);
        float as0 = a0 ? asrc[s0 * 8 + h] : 0.f;
        float as1 = a1 ? asrc[s1 * 8 + h] : 0.f;
        ushort4 uA[8], uB[8];
#pragma unroll
        for (int kk = 0; kk < 8; ++kk) {
            int sk = __shfl(s0, kk * 8 + hw);
            uA[kk] = *(const ushort4*)&xsb[(size_t)sk * D + lane * 4];
        }
        int it = 0;
        while (true) {
            // ==== sub-iter A: compute batch it from uA; rows it+1 -> uB ====
            if (it + 1 < nb8) {
#pragma unroll
                for (int kk = 0; kk < 8; ++kk) {
                    int sk = __shfl(s1, kk * 8 + hw);
                    uB[kk] = *(const ushort4*)&xsb[(size_t)sk * D + lane * 4];
                }
            }
            {
                float as2 = a2 ? asrc[s2 * 8 + h] : 0.f;  // 1-iter slack on s2
                int s3; float ea3; bool a3;
                LOAD_SE(it + 3, s3, ea3, a3);
                float al = as0 + adstn + ea0;
                al = al > 0.f ? al : 0.2f * al;
                float ex = a0 ? expf(al) : 0.f;
                den0 += ex; easum += ea0;
#pragma unroll
                for (int kk = 0; kk < 8; ++kk) {
                    float exk = __shfl(ex, kk * 8 + hw);
                    acc0 = fmaf(exk, b2f(uA[kk].x), acc0);
                    acc1 = fmaf(exk, b2f(uA[kk].y), acc1);
                    acc2 = fmaf(exk, b2f(uA[kk].z), acc2);
                    acc3 = fmaf(exk, b2f(uA[kk].w), acc3);
                }
                s0 = s1; ea0 = ea1; as0 = as1; a0 = a1;
                s1 = s2; ea1 = ea2; as1 = as2; a1 = a2;
                s2 = s3; ea2 = ea3; a2 = a3;
            }
            if (++it >= nb8) break;
            // ==== sub-iter B: compute batch it from uB; rows it+1 -> uA ====
            if (it + 1 < nb8) {
#pragma unroll
                for (int kk = 0; kk < 8; ++kk) {
                    int sk = __shfl(s1, kk * 8 + hw);
                    uA[kk] = *(const ushort4*)&xsb[(size_t)sk * D + lane * 4];
                }
            }
            {
                float as2 = a2 ? asrc[s2 * 8 + h] : 0.f;
                int s3; float ea3; bool a3;
                LOAD_SE(it + 3, s3, ea3, a3);
                float al = as0 + adstn + ea0;
                al = al > 0.f ? al : 0.2f * al;
                float ex = a0 ? expf(al) : 0.f;
                den0 += ex; easum += ea0;
#pragma unroll
                for (int kk = 0; kk < 8; ++kk) {
                    float exk = __shfl(ex, kk * 8 + hw);
                    acc0 = fmaf(exk, b2f(uB[kk].x), acc0);
                    acc1 = fmaf(exk, b2f(uB[kk].y), acc1);
                    acc2 = fmaf(exk, b2f(uB[kk].z), acc2);
                    acc3 = fmaf(exk, b2f(uB[kk].w), acc3);
                }
                s0 = s1; ea0 = ea1; as0 = as1; a0 = a1;
                s1 = s2; ea1 = ea2; as1 = as2; a1 = a2;
                s2 = s3; ea2 = ea3; a2 = a3;
            }
            if (++it >= nb8) break;
        }
    }
#undef LOAD_SE
    den0  += __shfl_xor(den0, 8);
    den0  += __shfl_xor(den0, 16);
    den0  += __shfl_xor(den0, 32);
    easum += __shfl_xor(easum, 8);
    easum += __shfl_xor(easum, 16);
    easum += __shfl_xor(easum, 32);
    float sa = easum / (float)(deg > 0 ? deg : 1);
    float als = asn + adstn + sa;
    als = als > 0.f ? als : 0.2f * als;
    float exSelf = expf(als);
    {
        float exs = __shfl(exSelf, hw);
        ushort4 u = *(const ushort4*)&xsb[(size_t)n * D + lane * 4];
        acc0 = fmaf(exs, b2f(u.x), acc0);
        acc1 = fmaf(exs, b2f(u.y), acc1);
        acc2 = fmaf(exs, b2f(u.z), acc2);
        acc3 = fmaf(exs, b2f(u.w), acc3);
    }
    den0 += exSelf;
    float denOwn = __shfl(den0, hw);
    float inv = 1.f / (denOwn + 1e-16f);

    int t0 = lane * 4;
    float4 bi = *(const float4*)&bias[t0];
    float o0 = acc0 * inv + bi.x;
    float o1 = acc1 * inv + bi.y;
    float o2 = acc2 * inv + bi.z;
    float o3 = acc3 * inv + bi.w;

    float s1r = o0 + o1 + o2 + o3;
    float s2r = o0 * o0 + o1 * o1 + o2 * o2 + o3 * o3;
    for (int o = 1; o < 64; o <<= 1) { s1r += __shfl_xor(s1r, o); s2r += __shfl_xor(s2r, o); }
    float mu = s1r / 256.f;
    float var = fmaxf((s2r - 256.f * mu * mu) / 255.f, 0.f);
    float sdv = sqrtf(var) + 1e-6f;
    float4 ga = *(const float4*)&gamma[t0];
    float4 be = *(const float4*)&beta[t0];
    float4 nin = *(const float4*)&nf_in[(size_t)n * D + t0];
    float y0 = ga.x * (o0 - mu) / sdv + be.x; y0 = y0 > 0.f ? y0 : 0.01f * y0;
    float y1 = ga.y * (o1 - mu) / sdv + be.y; y1 = y1 > 0.f ? y1 : 0.01f * y1;
    float y2 = ga.z * (o2 - mu) / sdv + be.z; y2 = y2 > 0.f ? y2 : 0.01f * y2;
    float y3 = ga.w * (o3 - mu) / sdv + be.w; y3 = y3 > 0.f ? y3 : 0.01f * y3;
    float r0 = nin.x + y0, r1 = nin.y + y1, r2 = nin.z + y2, r3 = nin.w + y3;
    float4 outv; outv.x = r0; outv.y = r1; outv.z = r2; outv.w = r3;
    *(float4*)&nf_out[(size_t)n * D + t0] = outv;
    ushort4 ob; ob.x = f2b(r0); ob.y = f2b(r1); ob.z = f2b(r2); ob.w = f2b(r3);
    *(ushort4*)&nf_out_b[(size_t)n * D + t0] = ob;
}

extern "C" void kernel_launch(void* const* d_in, const int* in_sizes, int n_in,
                              void* d_out, int out_size, void* d_ws, size_t ws_size,
                              hipStream_t stream) {
    const float* nf0    = (const float*)d_in[0];
    const int*   ei     = (const int*)d_in[1];
    const float* ew     = (const float*)d_in[2];
    const float* lin1   = (const float*)d_in[3];
    const float* le1    = (const float*)d_in[4];
    const float* asrc1w = (const float*)d_in[5];
    const float* adst1w = (const float*)d_in[6];
    const float* aedge1 = (const float*)d_in[7];
    const float* b1     = (const float*)d_in[8];
    const float* lin2   = (const float*)d_in[9];
    const float* le2    = (const float*)d_in[10];
    const float* asrc2w = (const float*)d_in[11];
    const float* adst2w = (const float*)d_in[12];
    const float* aedge2 = (const float*)d_in[13];
    const float* b2     = (const float*)d_in[14];
    const float* g1     = (const float*)d_in[15];
    const float* be1    = (const float*)d_in[16];
    const float* g2     = (const float*)d_in[17];
    const float* be2    = (const float*)d_in[18];
    const float* g3     = (const float*)d_in[19];
    const float* be3    = (const float*)d_in[20];
    const float* w1     = (const float*)d_in[21];
    const float* fb1    = (const float*)d_in[22];
    const float* w2     = (const float*)d_in[23];
    const float* fb2    = (const float*)d_in[24];

    const int N = in_sizes[0] / D;
    const int E = in_sizes[1] / 2;
    const int Mpad = ((N + 127) / 128) * 128;
    const int* srcI = ei;
    const int* dstI = ei + E;

    char* ws = (char*)d_ws;
    size_t ob = 0;
    auto alloc = [&](size_t bytes) { void* p = ws + ob; ob = align_up(ob + bytes, 256); return p; };
    // --- arena0: dead after GAT layer 2; start reused as FFN hidden (bf16, Mpad*DF*2 = 20.7MB) ---
    int*   deg     = (int*)alloc((size_t)N * 4);
    int*   csr_off = (int*)alloc((size_t)(N + 1) * 4);
    int*   cursor  = (int*)alloc((size_t)N * 4);
    int*   part    = (int*)alloc(1024);
    int*   eid     = (int*)alloc((size_t)E * 4);
    int*   src_csr = (int*)alloc((size_t)E * 4);
    unsigned short* MeT = (unsigned short*)alloc(16 * 64 * 2);
    float* asrcB   = (float*)alloc((size_t)N * H * 4);
    float* adstB   = (float*)alloc((size_t)N * H * 4);
    float* eA1c    = (float*)alloc((size_t)E * H * 4);
    float* eA2c    = (float*)alloc((size_t)E * H * 4);
    // --- persistent ---
    float* nfw     = (float*)alloc((size_t)N * D * 4);
    unsigned short* xs_b  = (unsigned short*)alloc((size_t)Mpad * D * 2);
    unsigned short* Abf   = (unsigned short*)alloc((size_t)Mpad * D * 2);
    unsigned short* lin1T = (unsigned short*)alloc((size_t)D * D * 2);
    unsigned short* lin2T = (unsigned short*)alloc((size_t)D * D * 2);
    unsigned short* w1T   = (unsigned short*)alloc((size_t)DF * D * 2);
    unsigned short* w2T   = (unsigned short*)alloc((size_t)D * DF * 2);
    unsigned short* hidden = (unsigned short*)ws;  // aliases arena0 (dead by FFN)
    (void)ws_size;
    float* out = (float*)d_out;

    hipMemsetAsync(deg, 0, (size_t)N * 4, stream);

    int eb = (E + 255) / 256;
    int nb = (N + 255) / 256;
    deg_kernel<<<eb, 256, 0, stream>>>(dstI, deg, E);
    partial_sum_kernel<<<nb, 256, 0, stream>>>(deg, part, N);
    scan_part_kernel<<<1, 256, 0, stream>>>(part, nb);
    scan_final_kernel<<<nb, 256, 0, stream>>>(deg, part, csr_off, cursor, N);
    fill_kernel<<<eb, 256, 0, stream>>>(srcI, dstI, cursor, eid, src_csr, E);

    const size_t nvalid = (size_t)N * D, ntot = (size_t)Mpad * D;
    int cb = (int)((ntot / 8 + 255) / 256);
    prep_kernel<<<641 + cb, 256, 0, stream>>>(lin1, lin2, w1, w2, le1, aedge1, le2, aedge2, nf0,
                                              lin1T, lin2T, w1T, w2T, MeT, Abf, nvalid, ntot);
    ealpha_mfma_kernel<<<(E + 63) / 64, 256, 0, stream>>>(ew, eid, MeT, eA1c, eA2c, E);

    int gatb = (N + 3) / 4;

    // ---- GAT layer 1 ----
    mfma_gemm_kernel<64><<<dim3(Mpad / 64, 2), 256, 0, stream>>>(
        Abf, lin1T, nullptr, nullptr, xs_b, N, D, D, 0, asrc1w, adst1w, asrcB, adstB);
    gat_node_kernel<<<gatb, 256, 0, stream>>>(csr_off, src_csr, eA1c, asrcB, adstB,
                                              xs_b, nf0, b1, g1, be1, nfw, Abf, N);
    // ---- GAT layer 2 ----
    mfma_gemm_kernel<64><<<dim3(Mpad / 64, 2), 256, 0, stream>>>(
        Abf, lin2T, nullptr, nullptr, xs_b, N, D, D, 0, asrc2w, adst2w, asrcB, adstB);
    gat_node_kernel<<<gatb, 256, 0, stream>>>(csr_off, src_csr, eA2c, asrcB, adstB,
                                              xs_b, nfw, b2, g2, be2, nfw, Abf, N);
    // ---- FFN: hidden = relu(Abf@w1+fb1) for ALL Mpad rows (pad rows are zero -> relu(fb1)) ----
    mfma_gemm_kernel<128><<<dim3(Mpad / 128, 8), 256, 0, stream>>>(
        Abf, w1T, fb1, nullptr, hidden, Mpad, DF, D, 1, nullptr, nullptr, nullptr, nullptr);
    // ---- FFN2 + LN + residual + output, fused ----
    ffn2_ln_kernel<<<(N + 63) / 64, 256, 0, stream>>>(hidden, w2T, fb2, nfw, g3, be3, out, N);
}

// Round 10
// 234.742 us; speedup vs baseline: 2.3052x; 1.0155x over previous
//
#include <hip/hip_runtime.h>
#include <hip/hip_bf16.h>
#include <hip/hip_fp8.h>
#include <math.h>

#define D 256
#define H 8
#define C 32
#define DE 64
#define DF 1024

static inline size_t align_up(size_t x, size_t a) { return (x + a - 1) / a * a; }

typedef __attribute__((ext_vector_type(8))) short short8;
typedef __attribute__((ext_vector_type(4))) float f32x4;

__device__ inline unsigned short f2b(float x) {
    __hip_bfloat16 h = __float2bfloat16(x);
    return *reinterpret_cast<unsigned short*>(&h);
}
__device__ inline float b2f(unsigned short u) {
    return __uint_as_float(((unsigned int)u) << 16);
}
__device__ inline unsigned char f2f8(float x) {
    __hip_fp8_e4m3 h(x);
    return h.__x;
}
__device__ inline float f82f(unsigned char u) {
    __hip_fp8_e4m3 h; h.__x = u;
    return (float)h;
}

// ---------------- CSR build ----------------
__global__ void deg_kernel(const int* __restrict__ dst, int* __restrict__ deg, int E) {
    int e = blockIdx.x * 256 + threadIdx.x;
    if (e < E) atomicAdd(&deg[dst[e]], 1);
}

__global__ void partial_sum_kernel(const int* __restrict__ deg, int* __restrict__ part, int n) {
    int i = blockIdx.x * 256 + threadIdx.x;
    int v = (i < n) ? deg[i] : 0;
    for (int o = 1; o < 64; o <<= 1) v += __shfl_xor(v, o);
    __shared__ int w4[4];
    if ((threadIdx.x & 63) == 0) w4[threadIdx.x >> 6] = v;
    __syncthreads();
    if (threadIdx.x == 0) part[blockIdx.x] = w4[0] + w4[1] + w4[2] + w4[3];
}

__global__ void scan_part_kernel(int* __restrict__ part, int nb) {
    __shared__ int buf[256];
    int t = threadIdx.x;
    buf[t] = (t < nb) ? part[t] : 0;
    __syncthreads();
    for (int s = 1; s < 256; s <<= 1) {
        int v = (t >= s) ? buf[t - s] : 0;
        __syncthreads();
        buf[t] += v;
        __syncthreads();
    }
    int excl = (t == 0) ? 0 : buf[t - 1];
    if (t < nb) part[t] = excl;
}

__global__ void scan_final_kernel(const int* __restrict__ deg, const int* __restrict__ part,
                                  int* __restrict__ off, int* __restrict__ cursor, int n) {
    int b = blockIdx.x, t = threadIdx.x, i = b * 256 + t;
    __shared__ int buf[256];
    int v = (i < n) ? deg[i] : 0;
    buf[t] = v;
    __syncthreads();
    for (int s = 1; s < 256; s <<= 1) {
        int x = (t >= s) ? buf[t - s] : 0;
        __syncthreads();
        buf[t] += x;
        __syncthreads();
    }
    int excl = part[b] + buf[t] - v;
    if (i < n) { off[i] = excl; cursor[i] = excl; }
    if (i == n - 1) off[n] = excl + v;
}

// writes eid[p] (edge at CSR slot p) and src_csr[p] (source node of slot p)
__global__ void fill_kernel(const int* __restrict__ src, const int* __restrict__ dst,
                            int* __restrict__ cursor, int* __restrict__ eid,
                            int* __restrict__ src_csr, int E) {
    int e = blockIdx.x * 256 + threadIdx.x;
    if (e < E) {
        int p = atomicAdd(&cursor[dst[e]], 1);
        eid[p] = e;
        src_csr[p] = src[e];
    }
}

// ---------------- prep: 4 weight transposes + MeT + nf0->bf16 convert, one dispatch ----------------
__global__ void prep_kernel(const float* __restrict__ lin1, const float* __restrict__ lin2,
                            const float* __restrict__ w1, const float* __restrict__ w2,
                            const float* __restrict__ le1, const float* __restrict__ ae1,
                            const float* __restrict__ le2, const float* __restrict__ ae2,
                            const float* __restrict__ nf0,
                            unsigned short* __restrict__ lin1T, unsigned short* __restrict__ lin2T,
                            unsigned short* __restrict__ w1T, unsigned short* __restrict__ w2T,
                            unsigned short* __restrict__ MeT, unsigned short* __restrict__ Abf,
                            size_t n_valid, size_t n_total) {
    int b = blockIdx.x;
    if (b > 640) {  // convert nf0 -> Abf (bf16), pad rows zeroed
        size_t i = ((size_t)(b - 641) * 256 + threadIdx.x) * 8;
        if (i >= n_total) return;
        ushort4 o0, o1;
        if (i < n_valid) {
            float4 a = *(const float4*)&nf0[i];
            float4 bb = *(const float4*)&nf0[i + 4];
            o0.x = f2b(a.x); o0.y = f2b(a.y); o0.z = f2b(a.z); o0.w = f2b(a.w);
            o1.x = f2b(bb.x); o1.y = f2b(bb.y); o1.z = f2b(bb.z); o1.w = f2b(bb.w);
        } else {
            o0.x = o0.y = o0.z = o0.w = 0;
            o1 = o0;
        }
        *(ushort4*)&Abf[i] = o0;
        *(ushort4*)&Abf[i + 4] = o1;
        return;
    }
    if (b == 640) {  // MeT[c][d]: c<8 -> layer1 head c; c>=8 -> layer2 head c-8
        for (int t = threadIdx.x; t < 512; t += 256) {
            int d = t >> 3, h = t & 7;
            float s1 = 0.f, s2 = 0.f;
            for (int c = 0; c < C; ++c) {
                s1 += le1[d * (H * C) + h * C + c] * ae1[h * C + c];
                s2 += le2[d * (H * C) + h * C + c] * ae2[h * C + c];
            }
            MeT[h * 64 + d] = f2b(s1);
            MeT[(8 + h) * 64 + d] = f2b(s2);
        }
        return;
    }
    __shared__ float tile[32][33];
    const float* in; unsigned short* outp; int K, N, tt;
    if (b < 64)       { in = lin1; outp = lin1T; K = D;  N = D;  tt = b; }
    else if (b < 128) { in = lin2; outp = lin2T; K = D;  N = D;  tt = b - 64; }
    else if (b < 384) { in = w1;   outp = w1T;   K = D;  N = DF; tt = b - 128; }
    else              { in = w2;   outp = w2T;   K = DF; N = D;  tt = b - 384; }
    int ntn = N >> 5;
    int bn = (tt % ntn) * 32, bk = (tt / ntn) * 32;
    int tx = threadIdx.x & 31, ty = threadIdx.x >> 5;
    for (int i = ty; i < 32; i += 8)
        tile[i][tx] = in[(size_t)(bk + i) * N + bn + tx];
    __syncthreads();
    for (int i = ty; i < 32; i += 8)
        outp[(size_t)(bn + i) * K + bk + tx] = f2b(tile[tx][i]);
}

// ---------------- bf16 MFMA GEMM: C = A[MxK] @ BT[NxK]^T (+bias)(+relu) ----------------
// Output: C8 (fp8) if non-null, else Cb (bf16) if non-null, else Cf (fp32).
template<int BM>
__global__ __launch_bounds__(256) void mfma_gemm_kernel(
    const unsigned short* __restrict__ A, const unsigned short* __restrict__ BT,
    const float* __restrict__ bias, float* __restrict__ Cf, unsigned short* __restrict__ Cb,
    unsigned char* __restrict__ C8,
    int M, int Nc, int K, int relu,
    const float* __restrict__ a_s, const float* __restrict__ a_d,
    float* __restrict__ asrcO, float* __restrict__ adstO) {
    constexpr int NR = (BM == 128) ? 4 : 2;
    constexpr int AI = BM / 32;
    __shared__ unsigned short As[BM * 64];
    __shared__ unsigned short Bs[128 * 64];
    int t = threadIdx.x;
    int lane = t & 63, w = t >> 6;
    int gm0 = blockIdx.x * BM, gn0 = blockIdx.y * 128;
    f32x4 acc[4][NR] = {};
    int srow = lane >> 3, scol = (lane & 7) * 8;
    int wm = (BM == 128) ? (w >> 1) * 64 : 0;
    int wn = (BM == 128) ? (w & 1) * 64 : w * 32;
    int fr = lane & 15, fk = (lane >> 4) * 8;

    for (int k0 = 0; k0 < K; k0 += 64) {
        __syncthreads();
#pragma unroll
        for (int i = 0; i < AI; ++i) {
            int rb = w * (8 * AI) + i * 8;
            const unsigned short* ga = A + (size_t)(gm0 + rb + srow) * K + k0 + scol;
            __builtin_amdgcn_global_load_lds(
                (const __attribute__((address_space(1))) unsigned int*)ga,
                (__attribute__((address_space(3))) unsigned int*)&As[rb * 64], 16, 0, 0);
        }
#pragma unroll
        for (int i = 0; i < 4; ++i) {
            int rb = w * 32 + i * 8;
            const unsigned short* gb = BT + (size_t)(gn0 + rb + srow) * K + k0 + scol;
            __builtin_amdgcn_global_load_lds(
                (const __attribute__((address_space(1))) unsigned int*)gb,
                (__attribute__((address_space(3))) unsigned int*)&Bs[rb * 64], 16, 0, 0);
        }
        __syncthreads();
#pragma unroll
        for (int kk = 0; kk < 64; kk += 32) {
            short8 a[4], b[NR];
#pragma unroll
            for (int m = 0; m < 4; ++m)
                a[m] = *(const short8*)&As[(wm + m * 16 + fr) * 64 + kk + fk];
#pragma unroll
            for (int n = 0; n < NR; ++n)
                b[n] = *(const short8*)&Bs[(wn + n * 16 + fr) * 64 + kk + fk];
#pragma unroll
            for (int m = 0; m < 4; ++m)
#pragma unroll
                for (int n = 0; n < NR; ++n)
                    acc[m][n] = __builtin_amdgcn_mfma_f32_16x16x32_bf16(a[m], b[n], acc[m][n], 0, 0, 0);
        }
    }
    int fcol = lane & 15, frow4 = (lane >> 4) * 4;
#pragma unroll
    for (int m = 0; m < 4; ++m) {
#pragma unroll
        for (int i = 0; i < 4; ++i) {
            int gr = gm0 + wm + m * 16 + frow4 + i;
            if (gr >= M) continue;
#pragma unroll
            for (int n = 0; n < NR; ++n) {
                int gc = gn0 + wn + n * 16 + fcol;
                float v = acc[m][n][i];
                if (bias) v += bias[gc];
                if (relu) v = fmaxf(v, 0.f);
                if (C8)      C8[(size_t)gr * Nc + gc] = f2f8(v);
                else if (Cb) Cb[(size_t)gr * Nc + gc] = f2b(v);
                else         Cf[(size_t)gr * Nc + gc] = v;
            }
        }
    }
    if (BM == 64 && a_s) {
        int head = (gn0 >> 5) + w;
        float as0 = a_s[head * 32 + fcol], as1 = a_s[head * 32 + 16 + fcol];
        float ad0 = a_d[head * 32 + fcol], ad1 = a_d[head * 32 + 16 + fcol];
#pragma unroll
        for (int m = 0; m < 4; ++m) {
#pragma unroll
            for (int i = 0; i < 4; ++i) {
                float vs = acc[m][0][i] * as0 + acc[m][1][i] * as1;
                float vd = acc[m][0][i] * ad0 + acc[m][1][i] * ad1;
#pragma unroll
                for (int o = 1; o < 16; o <<= 1) {
                    vs += __shfl_xor(vs, o);
                    vd += __shfl_xor(vd, o);
                }
                int r = gm0 + m * 16 + frow4 + i;
                if (fcol == 0 && r < M) {
                    asrcO[r * 8 + head] = vs;
                    adstO[r * 8 + head] = vd;
                }
            }
        }
    }
}

// ---------------- FFN2 + LN + leaky + residual, fully fused ----------------
__global__ __launch_bounds__(256) void ffn2_ln_kernel(
    const unsigned short* __restrict__ A, const unsigned short* __restrict__ BT,
    const float* __restrict__ bias, const float* __restrict__ nf_in,
    const float* __restrict__ gamma, const float* __restrict__ beta,
    float* __restrict__ out, int M) {
    __shared__ unsigned short As[64 * 64];
    __shared__ unsigned short Bs[256 * 64];
    __shared__ float redS1[4][64], redS2[4][64];
    __shared__ float muS[64], invS[64];
    int t = threadIdx.x, lane = t & 63, w = t >> 6;
    int gm0 = blockIdx.x * 64;
    f32x4 acc[4][4] = {};
    int srow = lane >> 3, scol = (lane & 7) * 8;
    int wn = w * 64;
    int fr = lane & 15, fk = (lane >> 4) * 8;
    for (int k0 = 0; k0 < DF; k0 += 64) {
        __syncthreads();
#pragma unroll
        for (int i = 0; i < 2; ++i) {
            int rb = w * 16 + i * 8;
            const unsigned short* ga = A + (size_t)(gm0 + rb + srow) * DF + k0 + scol;
            __builtin_amdgcn_global_load_lds(
                (const __attribute__((address_space(1))) unsigned int*)ga,
                (__attribute__((address_space(3))) unsigned int*)&As[rb * 64], 16, 0, 0);
        }
#pragma unroll
        for (int i = 0; i < 8; ++i) {
            int rb = w * 64 + i * 8;
            const unsigned short* gb = BT + (size_t)(rb + srow) * DF + k0 + scol;
            __builtin_amdgcn_global_load_lds(
                (const __attribute__((address_space(1))) unsigned int*)gb,
                (__attribute__((address_space(3))) unsigned int*)&Bs[rb * 64], 16, 0, 0);
        }
        __syncthreads();
#pragma unroll
        for (int kk = 0; kk < 64; kk += 32) {
            short8 a[4], b[4];
#pragma unroll
            for (int m = 0; m < 4; ++m)
                a[m] = *(const short8*)&As[(m * 16 + fr) * 64 + kk + fk];
#pragma unroll
            for (int n = 0; n < 4; ++n)
                b[n] = *(const short8*)&Bs[(wn + n * 16 + fr) * 64 + kk + fk];
#pragma unroll
            for (int m = 0; m < 4; ++m)
#pragma unroll
                for (int n = 0; n < 4; ++n)
                    acc[m][n] = __builtin_amdgcn_mfma_f32_16x16x32_bf16(a[m], b[n], acc[m][n], 0, 0, 0);
        }
    }
    int fcol = lane & 15, frow4 = (lane >> 4) * 4;
#pragma unroll
    for (int m = 0; m < 4; ++m) {
#pragma unroll
        for (int i = 0; i < 4; ++i) {
            float vs1 = 0.f, vs2 = 0.f;
#pragma unroll
            for (int n = 0; n < 4; ++n) {
                float vv = acc[m][n][i] + bias[wn + n * 16 + fcol];
                acc[m][n][i] = vv;
                vs1 += vv; vs2 += vv * vv;
            }
#pragma unroll
            for (int o = 1; o < 16; o <<= 1) {
                vs1 += __shfl_xor(vs1, o);
                vs2 += __shfl_xor(vs2, o);
            }
            if (fcol == 0) {
                redS1[w][m * 16 + frow4 + i] = vs1;
                redS2[w][m * 16 + frow4 + i] = vs2;
            }
        }
    }
    __syncthreads();
    if (t < 64) {
        float s1 = redS1[0][t] + redS1[1][t] + redS1[2][t] + redS1[3][t];
        float s2 = redS2[0][t] + redS2[1][t] + redS2[2][t] + redS2[3][t];
        float mu = s1 / 256.f;
        float var = fmaxf((s2 - 256.f * mu * mu) / 255.f, 0.f);
        muS[t] = mu;
        invS[t] = 1.f / (sqrtf(var) + 1e-6f);
    }
    __syncthreads();
#pragma unroll
    for (int m = 0; m < 4; ++m) {
#pragma unroll
        for (int i = 0; i < 4; ++i) {
            int r = m * 16 + frow4 + i;
            int gr = gm0 + r;
            if (gr >= M) continue;
            float mu = muS[r], inv = invS[r];
#pragma unroll
            for (int n = 0; n < 4; ++n) {
                int gc = wn + n * 16 + fcol;
                float y = gamma[gc] * (acc[m][n][i] - mu) * inv + beta[gc];
                y = y > 0.f ? y : 0.01f * y;
                out[(size_t)gr * D + gc] = nf_in[(size_t)gr * D + gc] + y;
            }
        }
    }
}

// ---------------- edge-attention projection, CSR-ordered output ----------------
__global__ __launch_bounds__(256) void ealpha_mfma_kernel(
    const float* __restrict__ ew, const int* __restrict__ eid,
    const unsigned short* __restrict__ MeT,
    float* __restrict__ eA1c, float* __restrict__ eA2c, int E) {
    int t = threadIdx.x;
    int lane = t & 63, w = t >> 6;
    int p0 = blockIdx.x * 64 + w * 16;
    int r = lane & 15, g = lane >> 4;
    int pr = p0 + r; if (pr > E - 1) pr = E - 1;
    int er = eid[pr];
    const float* rowp = ew + (size_t)er * DE;
    float4 x0 = *(const float4*)&rowp[g * 8];
    float4 x1 = *(const float4*)&rowp[g * 8 + 4];
    float4 y0 = *(const float4*)&rowp[32 + g * 8];
    float4 y1 = *(const float4*)&rowp[32 + g * 8 + 4];
    short8 a0, a1;
    a0[0] = (short)f2b(x0.x); a0[1] = (short)f2b(x0.y); a0[2] = (short)f2b(x0.z); a0[3] = (short)f2b(x0.w);
    a0[4] = (short)f2b(x1.x); a0[5] = (short)f2b(x1.y); a0[6] = (short)f2b(x1.z); a0[7] = (short)f2b(x1.w);
    a1[0] = (short)f2b(y0.x); a1[1] = (short)f2b(y0.y); a1[2] = (short)f2b(y0.z); a1[3] = (short)f2b(y0.w);
    a1[4] = (short)f2b(y1.x); a1[5] = (short)f2b(y1.y); a1[6] = (short)f2b(y1.z); a1[7] = (short)f2b(y1.w);
    short8 b0 = *(const short8*)&MeT[r * 64 + g * 8];
    short8 b1 = *(const short8*)&MeT[r * 64 + 32 + g * 8];
    f32x4 acc = {};
    acc = __builtin_amdgcn_mfma_f32_16x16x32_bf16(a0, b0, acc, 0, 0, 0);
    acc = __builtin_amdgcn_mfma_f32_16x16x32_bf16(a1, b1, acc, 0, 0, 0);
#pragma unroll
    for (int i = 0; i < 4; ++i) {
        int p = p0 + g * 4 + i;
        if (p < E) {
            if (r < 8) eA1c[(size_t)p * 8 + r] = acc[i];
            else       eA2c[(size_t)p * 8 + (r - 8)] = acc[i];
        }
    }
}

// ---------------- GAT: wave-per-node, 3-gen pipelined fp8 gather + fused LN ----------------
// 4 nodes/block (1 wave each). Lane owns features lane*4..lane*4+3 (fp8 rows, 256B each).
__global__ __launch_bounds__(256) void gat_node_kernel(
    const int* __restrict__ off, const int* __restrict__ src_csr,
    const float* __restrict__ eAc,
    const float* __restrict__ asrc, const float* __restrict__ adst,
    const unsigned char* __restrict__ xs8, const float* __restrict__ nf_in,
    const float* __restrict__ bias, const float* __restrict__ gamma,
    const float* __restrict__ beta, float* __restrict__ nf_out,
    unsigned short* __restrict__ nf_out_b, int N) {
    int lane = threadIdx.x & 63;
    int n = blockIdx.x * 4 + (threadIdx.x >> 6);
    if (n >= N) return;
    int e0 = off[n], e1 = off[n + 1], deg = e1 - e0;
    int h = lane & 7;
    int hw = lane >> 3;

    float adstn = adst[n * 8 + h];
    float asn = asrc[n * 8 + h];

    float acc0 = 0.f, acc1 = 0.f, acc2 = 0.f, acc3 = 0.f;
    float den0 = 0.f, easum = 0.f;
    int nb8 = (deg + 7) >> 3;

#define LOAD_SE(b, S, EA, A) { A = ((b) * 8 + hw) < deg; int sp_ = e0 + (b) * 8 + hw; \
    S = A ? src_csr[sp_] : n; EA = A ? eAc[(size_t)sp_ * 8 + h] : 0.f; }

    if (nb8 > 0) {
        int s0, s1, s2; float ea0, ea1, ea2; bool a0, a1, a2;
        LOAD_SE(0, s0, ea0, a0);
        LOAD_SE(1, s1, ea1, a1);
        LOAD_SE(2, s2, ea2, a2);
        float as0 = a0 ? asrc[s0 * 8 + h] : 0.f;
        float as1 = a1 ? asrc[s1 * 8 + h] : 0.f;
        uchar4 uA[8], uB[8];
#pragma unroll
        for (int kk = 0; kk < 8; ++kk) {
            int sk = __shfl(s0, kk * 8 + hw);
            uA[kk] = *(const uchar4*)&xs8[(size_t)sk * D + lane * 4];
        }
        int it = 0;
        while (true) {
            // ==== sub-iter A: compute batch it from uA; rows it+1 -> uB ====
            if (it + 1 < nb8) {
#pragma unroll
                for (int kk = 0; kk < 8; ++kk) {
                    int sk = __shfl(s1, kk * 8 + hw);
                    uB[kk] = *(const uchar4*)&xs8[(size_t)sk * D + lane * 4];
                }
            }
            {
                float as2 = a2 ? asrc[s2 * 8 + h] : 0.f;
                int s3; float ea3; bool a3;
                LOAD_SE(it + 3, s3, ea3, a3);
                float al = as0 + adstn + ea0;
                al = al > 0.f ? al : 0.2f * al;
                float ex = a0 ? expf(al) : 0.f;
                den0 += ex; easum += ea0;
#pragma unroll
                for (int kk = 0; kk < 8; ++kk) {
                    float exk = __shfl(ex, kk * 8 + hw);
                    acc0 = fmaf(exk, f82f(uA[kk].x), acc0);
                    acc1 = fmaf(exk, f82f(uA[kk].y), acc1);
                    acc2 = fmaf(exk, f82f(uA[kk].z), acc2);
                    acc3 = fmaf(exk, f82f(uA[kk].w), acc3);
                }
                s0 = s1; ea0 = ea1; as0 = as1; a0 = a1;
                s1 = s2; ea1 = ea2; as1 = as2; a1 = a2;
                s2 = s3; ea2 = ea3; a2 = a3;
            }
            if (++it >= nb8) break;
            // ==== sub-iter B: compute batch it from uB; rows it+1 -> uA ====
            if (it + 1 < nb8) {
#pragma unroll
                for (int kk = 0; kk < 8; ++kk) {
                    int sk = __shfl(s1, kk * 8 + hw);
                    uA[kk] = *(const uchar4*)&xs8[(size_t)sk * D + lane * 4];
                }
            }
            {
                float as2 = a2 ? asrc[s2 * 8 + h] : 0.f;
                int s3; float ea3; bool a3;
                LOAD_SE(it + 3, s3, ea3, a3);
                float al = as0 + adstn + ea0;
                al = al > 0.f ? al : 0.2f * al;
                float ex = a0 ? expf(al) : 0.f;
                den0 += ex; easum += ea0;
#pragma unroll
                for (int kk = 0; kk < 8; ++kk) {
                    float exk = __shfl(ex, kk * 8 + hw);
                    acc0 = fmaf(exk, f82f(uB[kk].x), acc0);
                    acc1 = fmaf(exk, f82f(uB[kk].y), acc1);
                    acc2 = fmaf(exk, f82f(uB[kk].z), acc2);
                    acc3 = fmaf(exk, f82f(uB[kk].w), acc3);
                }
                s0 = s1; ea0 = ea1; as0 = as1; a0 = a1;
                s1 = s2; ea1 = ea2; as1 = as2; a1 = a2;
                s2 = s3; ea2 = ea3; a2 = a3;
            }
            if (++it >= nb8) break;
        }
    }
#undef LOAD_SE
    den0  += __shfl_xor(den0, 8);
    den0  += __shfl_xor(den0, 16);
    den0  += __shfl_xor(den0, 32);
    easum += __shfl_xor(easum, 8);
    easum += __shfl_xor(easum, 16);
    easum += __shfl_xor(easum, 32);
    float sa = easum / (float)(deg > 0 ? deg : 1);
    float als = asn + adstn + sa;
    als = als > 0.f ? als : 0.2f * als;
    float exSelf = expf(als);
    {
        float exs = __shfl(exSelf, hw);
        uchar4 u = *(const uchar4*)&xs8[(size_t)n * D + lane * 4];
        acc0 = fmaf(exs, f82f(u.x), acc0);
        acc1 = fmaf(exs, f82f(u.y), acc1);
        acc2 = fmaf(exs, f82f(u.z), acc2);
        acc3 = fmaf(exs, f82f(u.w), acc3);
    }
    den0 += exSelf;
    float denOwn = __shfl(den0, hw);
    float inv = 1.f / (denOwn + 1e-16f);

    int t0 = lane * 4;
    float4 bi = *(const float4*)&bias[t0];
    float o0 = acc0 * inv + bi.x;
    float o1 = acc1 * inv + bi.y;
    float o2 = acc2 * inv + bi.z;
    float o3 = acc3 * inv + bi.w;

    float s1r = o0 + o1 + o2 + o3;
    float s2r = o0 * o0 + o1 * o1 + o2 * o2 + o3 * o3;
    for (int o = 1; o < 64; o <<= 1) { s1r += __shfl_xor(s1r, o); s2r += __shfl_xor(s2r, o); }
    float mu = s1r / 256.f;
    float var = fmaxf((s2r - 256.f * mu * mu) / 255.f, 0.f);
    float sdv = sqrtf(var) + 1e-6f;
    float4 ga = *(const float4*)&gamma[t0];
    float4 be = *(const float4*)&beta[t0];
    float4 nin = *(const float4*)&nf_in[(size_t)n * D + t0];
    float y0 = ga.x * (o0 - mu) / sdv + be.x; y0 = y0 > 0.f ? y0 : 0.01f * y0;
    float y1 = ga.y * (o1 - mu) / sdv + be.y; y1 = y1 > 0.f ? y1 : 0.01f * y1;
    float y2 = ga.z * (o2 - mu) / sdv + be.z; y2 = y2 > 0.f ? y2 : 0.01f * y2;
    float y3 = ga.w * (o3 - mu) / sdv + be.w; y3 = y3 > 0.f ? y3 : 0.01f * y3;
    float r0 = nin.x + y0, r1 = nin.y + y1, r2 = nin.z + y2, r3 = nin.w + y3;
    float4 outv; outv.x = r0; outv.y = r1; outv.z = r2; outv.w = r3;
    *(float4*)&nf_out[(size_t)n * D + t0] = outv;
    ushort4 ob; ob.x = f2b(r0); ob.y = f2b(r1); ob.z = f2b(r2); ob.w = f2b(r3);
    *(ushort4*)&nf_out_b[(size_t)n * D + t0] = ob;
}

extern "C" void kernel_launch(void* const* d_in, const int* in_sizes, int n_in,
                              void* d_out, int out_size, void* d_ws, size_t ws_size,
                              hipStream_t stream) {
    const float* nf0    = (const float*)d_in[0];
    const int*   ei     = (const int*)d_in[1];
    const float* ew     = (const float*)d_in[2];
    const float* lin1   = (const float*)d_in[3];
    const float* le1    = (const float*)d_in[4];
    const float* asrc1w = (const float*)d_in[5];
    const float* adst1w = (const float*)d_in[6];
    const float* aedge1 = (const float*)d_in[7];
    const float* b1     = (const float*)d_in[8];
    const float* lin2   = (const float*)d_in[9];
    const float* le2    = (const float*)d_in[10];
    const float* asrc2w = (const float*)d_in[11];
    const float* adst2w = (const float*)d_in[12];
    const float* aedge2 = (const float*)d_in[13];
    const float* b2     = (const float*)d_in[14];
    const float* g1     = (const float*)d_in[15];
    const float* be1    = (const float*)d_in[16];
    const float* g2     = (const float*)d_in[17];
    const float* be2    = (const float*)d_in[18];
    const float* g3     = (const float*)d_in[19];
    const float* be3    = (const float*)d_in[20];
    const float* w1     = (const float*)d_in[21];
    const float* fb1    = (const float*)d_in[22];
    const float* w2     = (const float*)d_in[23];
    const float* fb2    = (const float*)d_in[24];

    const int N = in_sizes[0] / D;
    const int E = in_sizes[1] / 2;
    const int Mpad = ((N + 127) / 128) * 128;
    const int* srcI = ei;
    const int* dstI = ei + E;

    char* ws = (char*)d_ws;
    size_t ob = 0;
    auto alloc = [&](size_t bytes) { void* p = ws + ob; ob = align_up(ob + bytes, 256); return p; };
    // --- arena0: dead after GAT layer 2; start reused as FFN hidden (bf16, Mpad*DF*2 = 20.7MB) ---
    int*   deg     = (int*)alloc((size_t)N * 4);
    int*   csr_off = (int*)alloc((size_t)(N + 1) * 4);
    int*   cursor  = (int*)alloc((size_t)N * 4);
    int*   part    = (int*)alloc(1024);
    int*   eid     = (int*)alloc((size_t)E * 4);
    int*   src_csr = (int*)alloc((size_t)E * 4);
    unsigned short* MeT = (unsigned short*)alloc(16 * 64 * 2);
    float* asrcB   = (float*)alloc((size_t)N * H * 4);
    float* adstB   = (float*)alloc((size_t)N * H * 4);
    float* eA1c    = (float*)alloc((size_t)E * H * 4);
    float* eA2c    = (float*)alloc((size_t)E * H * 4);
    // --- persistent ---
    float* nfw     = (float*)alloc((size_t)N * D * 4);
    unsigned char*  xs_8  = (unsigned char*)alloc((size_t)Mpad * D);
    unsigned short* Abf   = (unsigned short*)alloc((size_t)Mpad * D * 2);
    unsigned short* lin1T = (unsigned short*)alloc((size_t)D * D * 2);
    unsigned short* lin2T = (unsigned short*)alloc((size_t)D * D * 2);
    unsigned short* w1T   = (unsigned short*)alloc((size_t)DF * D * 2);
    unsigned short* w2T   = (unsigned short*)alloc((size_t)D * DF * 2);
    unsigned short* hidden = (unsigned short*)ws;  // aliases arena0 (dead by FFN)
    (void)ws_size;
    float* out = (float*)d_out;

    hipMemsetAsync(deg, 0, (size_t)N * 4, stream);

    int eb = (E + 255) / 256;
    int nb = (N + 255) / 256;
    deg_kernel<<<eb, 256, 0, stream>>>(dstI, deg, E);
    partial_sum_kernel<<<nb, 256, 0, stream>>>(deg, part, N);
    scan_part_kernel<<<1, 256, 0, stream>>>(part, nb);
    scan_final_kernel<<<nb, 256, 0, stream>>>(deg, part, csr_off, cursor, N);
    fill_kernel<<<eb, 256, 0, stream>>>(srcI, dstI, cursor, eid, src_csr, E);

    const size_t nvalid = (size_t)N * D, ntot = (size_t)Mpad * D;
    int cb = (int)((ntot / 8 + 255) / 256);
    prep_kernel<<<641 + cb, 256, 0, stream>>>(lin1, lin2, w1, w2, le1, aedge1, le2, aedge2, nf0,
                                              lin1T, lin2T, w1T, w2T, MeT, Abf, nvalid, ntot);
    ealpha_mfma_kernel<<<(E + 63) / 64, 256, 0, stream>>>(ew, eid, MeT, eA1c, eA2c, E);

    int gatb = (N + 3) / 4;

    // ---- GAT layer 1 ----
    mfma_gemm_kernel<64><<<dim3(Mpad / 64, 2), 256, 0, stream>>>(
        Abf, lin1T, nullptr, nullptr, nullptr, xs_8, N, D, D, 0, asrc1w, adst1w, asrcB, adstB);
    gat_node_kernel<<<gatb, 256, 0, stream>>>(csr_off, src_csr, eA1c, asrcB, adstB,
                                              xs_8, nf0, b1, g1, be1, nfw, Abf, N);
    // ---- GAT layer 2 ----
    mfma_gemm_kernel<64><<<dim3(Mpad / 64, 2), 256, 0, stream>>>(
        Abf, lin2T, nullptr, nullptr, nullptr, xs_8, N, D, D, 0, asrc2w, adst2w, asrcB, adstB);
    gat_node_kernel<<<gatb, 256, 0, stream>>>(csr_off, src_csr, eA2c, asrcB, adstB,
                                              xs_8, nfw, b2, g2, be2, nfw, Abf, N);
    // ---- FFN: hidden = relu(Abf@w1+fb1) for ALL Mpad rows (pad rows are zero -> relu(fb1)) ----
    mfma_gemm_kernel<128><<<dim3(Mpad / 128, 8), 256, 0, stream>>>(
        Abf, w1T, fb1, nullptr, hidden, nullptr, Mpad, DF, D, 1, nullptr, nullptr, nullptr, nullptr);
    // ---- FFN2 + LN + residual + output, fused ----
    ffn2_ln_kernel<<<(N + 63) / 64, 256, 0, stream>>>(hidden, w2T, fb2, nfw, g3, be3, out, N);
}

// Round 11
// 228.865 us; speedup vs baseline: 2.3644x; 1.0257x over previous
//
#include <hip/hip_runtime.h>
#include <hip/hip_bf16.h>
#include <math.h>

#define D 256
#define H 8
#define C 32
#define DE 64
#define DF 1024

static inline size_t align_up(size_t x, size_t a) { return (x + a - 1) / a * a; }

typedef __attribute__((ext_vector_type(8))) short short8;
typedef __attribute__((ext_vector_type(4))) float f32x4;

__device__ inline unsigned short f2b(float x) {
    __hip_bfloat16 h = __float2bfloat16(x);
    return *reinterpret_cast<unsigned short*>(&h);
}
__device__ inline float b2f(unsigned short u) {
    return __uint_as_float(((unsigned int)u) << 16);
}

// ---------------- mega-prep: weight transposes + MeT + nf0 convert + deg count ----------------
// blocks [0,640): transposes; 640: MeT; (640, 640+cb]: convert; rest: deg atomics.
__global__ void prep_deg_kernel(const float* __restrict__ lin1, const float* __restrict__ lin2,
                                const float* __restrict__ w1, const float* __restrict__ w2,
                                const float* __restrict__ le1, const float* __restrict__ ae1,
                                const float* __restrict__ le2, const float* __restrict__ ae2,
                                const float* __restrict__ nf0, const int* __restrict__ dst,
                                unsigned short* __restrict__ lin1T, unsigned short* __restrict__ lin2T,
                                unsigned short* __restrict__ w1T, unsigned short* __restrict__ w2T,
                                unsigned short* __restrict__ MeT, unsigned short* __restrict__ Abf,
                                int* __restrict__ deg,
                                size_t n_valid, size_t n_total, int cb, int E) {
    int b = blockIdx.x;
    if (b >= 641 + cb) {  // deg count
        int e = (b - 641 - cb) * 256 + threadIdx.x;
        if (e < E) atomicAdd(&deg[dst[e]], 1);
        return;
    }
    if (b > 640) {  // convert nf0 -> Abf (bf16), pad rows zeroed
        size_t i = ((size_t)(b - 641) * 256 + threadIdx.x) * 8;
        if (i >= n_total) return;
        ushort4 o0, o1;
        if (i < n_valid) {
            float4 a = *(const float4*)&nf0[i];
            float4 bb = *(const float4*)&nf0[i + 4];
            o0.x = f2b(a.x); o0.y = f2b(a.y); o0.z = f2b(a.z); o0.w = f2b(a.w);
            o1.x = f2b(bb.x); o1.y = f2b(bb.y); o1.z = f2b(bb.z); o1.w = f2b(bb.w);
        } else {
            o0.x = o0.y = o0.z = o0.w = 0;
            o1 = o0;
        }
        *(ushort4*)&Abf[i] = o0;
        *(ushort4*)&Abf[i + 4] = o1;
        return;
    }
    if (b == 640) {  // MeT[c][d]: c<8 -> layer1 head c; c>=8 -> layer2 head c-8
        for (int t = threadIdx.x; t < 512; t += 256) {
            int d = t >> 3, h = t & 7;
            float s1 = 0.f, s2 = 0.f;
            for (int c = 0; c < C; ++c) {
                s1 += le1[d * (H * C) + h * C + c] * ae1[h * C + c];
                s2 += le2[d * (H * C) + h * C + c] * ae2[h * C + c];
            }
            MeT[h * 64 + d] = f2b(s1);
            MeT[(8 + h) * 64 + d] = f2b(s2);
        }
        return;
    }
    __shared__ float tile[32][33];
    const float* in; unsigned short* outp; int K, N, tt;
    if (b < 64)       { in = lin1; outp = lin1T; K = D;  N = D;  tt = b; }
    else if (b < 128) { in = lin2; outp = lin2T; K = D;  N = D;  tt = b - 64; }
    else if (b < 384) { in = w1;   outp = w1T;   K = D;  N = DF; tt = b - 128; }
    else              { in = w2;   outp = w2T;   K = DF; N = D;  tt = b - 384; }
    int ntn = N >> 5;
    int bn = (tt % ntn) * 32, bk = (tt / ntn) * 32;
    int tx = threadIdx.x & 31, ty = threadIdx.x >> 5;
    for (int i = ty; i < 32; i += 8)
        tile[i][tx] = in[(size_t)(bk + i) * N + bn + tx];
    __syncthreads();
    for (int i = ty; i < 32; i += 8)
        outp[(size_t)(bn + i) * K + bk + tx] = f2b(tile[tx][i]);
}

// ---------------- CSR scan ----------------
__global__ void partial_sum_kernel(const int* __restrict__ deg, int* __restrict__ part, int n) {
    int i = blockIdx.x * 256 + threadIdx.x;
    int v = (i < n) ? deg[i] : 0;
    for (int o = 1; o < 64; o <<= 1) v += __shfl_xor(v, o);
    __shared__ int w4[4];
    if ((threadIdx.x & 63) == 0) w4[threadIdx.x >> 6] = v;
    __syncthreads();
    if (threadIdx.x == 0) part[blockIdx.x] = w4[0] + w4[1] + w4[2] + w4[3];
}

// scan of raw block sums folded in: each block sums part[0..b) itself (<=40 adds)
__global__ void scan_final_kernel(const int* __restrict__ deg, const int* __restrict__ part,
                                  int* __restrict__ off, int* __restrict__ cursor, int n) {
    int b = blockIdx.x, t = threadIdx.x, i = b * 256 + t;
    __shared__ int buf[256];
    __shared__ int baseS;
    if (t == 0) {
        int base = 0;
        for (int j = 0; j < b; ++j) base += part[j];
        baseS = base;
    }
    int v = (i < n) ? deg[i] : 0;
    buf[t] = v;
    __syncthreads();
    for (int s = 1; s < 256; s <<= 1) {
        int x = (t >= s) ? buf[t - s] : 0;
        __syncthreads();
        buf[t] += x;
        __syncthreads();
    }
    int excl = baseS + buf[t] - v;
    if (i < n) { off[i] = excl; cursor[i] = excl; }
    if (i == n - 1) off[n] = excl + v;
}

// writes eid[p] (edge at CSR slot p) and src_csr[p] (source node of slot p)
__global__ void fill_kernel(const int* __restrict__ src, const int* __restrict__ dst,
                            int* __restrict__ cursor, int* __restrict__ eid,
                            int* __restrict__ src_csr, int E) {
    int e = blockIdx.x * 256 + threadIdx.x;
    if (e < E) {
        int p = atomicAdd(&cursor[dst[e]], 1);
        eid[p] = e;
        src_csr[p] = src[e];
    }
}

// ---------------- bf16 MFMA GEMM: C = A[MxK] @ BT[NxK]^T (+bias)(+relu) ----------------
template<int BM>
__global__ __launch_bounds__(256) void mfma_gemm_kernel(
    const unsigned short* __restrict__ A, const unsigned short* __restrict__ BT,
    const float* __restrict__ bias, float* __restrict__ Cf, unsigned short* __restrict__ Cb,
    int M, int Nc, int K, int relu,
    const float* __restrict__ a_s, const float* __restrict__ a_d,
    float* __restrict__ asrcO, float* __restrict__ adstO) {
    constexpr int NR = (BM == 128) ? 4 : 2;
    constexpr int AI = BM / 32;
    __shared__ unsigned short As[BM * 64];
    __shared__ unsigned short Bs[128 * 64];
    int t = threadIdx.x;
    int lane = t & 63, w = t >> 6;
    int gm0 = blockIdx.x * BM, gn0 = blockIdx.y * 128;
    f32x4 acc[4][NR] = {};
    int srow = lane >> 3, scol = (lane & 7) * 8;
    int wm = (BM == 128) ? (w >> 1) * 64 : 0;
    int wn = (BM == 128) ? (w & 1) * 64 : w * 32;
    int fr = lane & 15, fk = (lane >> 4) * 8;

    for (int k0 = 0; k0 < K; k0 += 64) {
        __syncthreads();
#pragma unroll
        for (int i = 0; i < AI; ++i) {
            int rb = w * (8 * AI) + i * 8;
            const unsigned short* ga = A + (size_t)(gm0 + rb + srow) * K + k0 + scol;
            __builtin_amdgcn_global_load_lds(
                (const __attribute__((address_space(1))) unsigned int*)ga,
                (__attribute__((address_space(3))) unsigned int*)&As[rb * 64], 16, 0, 0);
        }
#pragma unroll
        for (int i = 0; i < 4; ++i) {
            int rb = w * 32 + i * 8;
            const unsigned short* gb = BT + (size_t)(gn0 + rb + srow) * K + k0 + scol;
            __builtin_amdgcn_global_load_lds(
                (const __attribute__((address_space(1))) unsigned int*)gb,
                (__attribute__((address_space(3))) unsigned int*)&Bs[rb * 64], 16, 0, 0);
        }
        __syncthreads();
#pragma unroll
        for (int kk = 0; kk < 64; kk += 32) {
            short8 a[4], b[NR];
#pragma unroll
            for (int m = 0; m < 4; ++m)
                a[m] = *(const short8*)&As[(wm + m * 16 + fr) * 64 + kk + fk];
#pragma unroll
            for (int n = 0; n < NR; ++n)
                b[n] = *(const short8*)&Bs[(wn + n * 16 + fr) * 64 + kk + fk];
#pragma unroll
            for (int m = 0; m < 4; ++m)
#pragma unroll
                for (int n = 0; n < NR; ++n)
                    acc[m][n] = __builtin_amdgcn_mfma_f32_16x16x32_bf16(a[m], b[n], acc[m][n], 0, 0, 0);
        }
    }
    int fcol = lane & 15, frow4 = (lane >> 4) * 4;
#pragma unroll
    for (int m = 0; m < 4; ++m) {
#pragma unroll
        for (int i = 0; i < 4; ++i) {
            int gr = gm0 + wm + m * 16 + frow4 + i;
            if (gr >= M) continue;
#pragma unroll
            for (int n = 0; n < NR; ++n) {
                int gc = gn0 + wn + n * 16 + fcol;
                float v = acc[m][n][i];
                if (bias) v += bias[gc];
                if (relu) v = fmaxf(v, 0.f);
                if (Cb) Cb[(size_t)gr * Nc + gc] = f2b(v);
                else    Cf[(size_t)gr * Nc + gc] = v;
            }
        }
    }
    if (BM == 64 && a_s) {
        int head = (gn0 >> 5) + w;
        float as0 = a_s[head * 32 + fcol], as1 = a_s[head * 32 + 16 + fcol];
        float ad0 = a_d[head * 32 + fcol], ad1 = a_d[head * 32 + 16 + fcol];
#pragma unroll
        for (int m = 0; m < 4; ++m) {
#pragma unroll
            for (int i = 0; i < 4; ++i) {
                float vs = acc[m][0][i] * as0 + acc[m][1][i] * as1;
                float vd = acc[m][0][i] * ad0 + acc[m][1][i] * ad1;
#pragma unroll
                for (int o = 1; o < 16; o <<= 1) {
                    vs += __shfl_xor(vs, o);
                    vd += __shfl_xor(vd, o);
                }
                int r = gm0 + m * 16 + frow4 + i;
                if (fcol == 0 && r < M) {
                    asrcO[r * 8 + head] = vs;
                    adstO[r * 8 + head] = vd;
                }
            }
        }
    }
}

// ---------------- fused: ealpha (blocks [0,EAB)) + xs-GEMM layer1 (blocks [EAB, EAB+nbx*2)) ----------------
__global__ __launch_bounds__(256) void fused_ea_gemm1_kernel(
    const float* __restrict__ ew, const int* __restrict__ eid,
    const unsigned short* __restrict__ MeT,
    float* __restrict__ eA1c, float* __restrict__ eA2c, int E, int EAB,
    const unsigned short* __restrict__ A, const unsigned short* __restrict__ BT,
    unsigned short* __restrict__ Cb, int M, int nbx,
    const float* __restrict__ a_s, const float* __restrict__ a_d,
    float* __restrict__ asrcO, float* __restrict__ adstO) {
    __shared__ unsigned short As[64 * 64];
    __shared__ unsigned short Bs[128 * 64];
    int t = threadIdx.x;
    int lane = t & 63, w = t >> 6;

    if ((int)blockIdx.x < EAB) {
        // ---------- ealpha path ----------
        int p0 = blockIdx.x * 64 + w * 16;
        int r = lane & 15, g = lane >> 4;
        int pr = p0 + r; if (pr > E - 1) pr = E - 1;
        int er = eid[pr];
        const float* rowp = ew + (size_t)er * DE;
        float4 x0 = *(const float4*)&rowp[g * 8];
        float4 x1 = *(const float4*)&rowp[g * 8 + 4];
        float4 y0 = *(const float4*)&rowp[32 + g * 8];
        float4 y1 = *(const float4*)&rowp[32 + g * 8 + 4];
        short8 a0, a1;
        a0[0] = (short)f2b(x0.x); a0[1] = (short)f2b(x0.y); a0[2] = (short)f2b(x0.z); a0[3] = (short)f2b(x0.w);
        a0[4] = (short)f2b(x1.x); a0[5] = (short)f2b(x1.y); a0[6] = (short)f2b(x1.z); a0[7] = (short)f2b(x1.w);
        a1[0] = (short)f2b(y0.x); a1[1] = (short)f2b(y0.y); a1[2] = (short)f2b(y0.z); a1[3] = (short)f2b(y0.w);
        a1[4] = (short)f2b(y1.x); a1[5] = (short)f2b(y1.y); a1[6] = (short)f2b(y1.z); a1[7] = (short)f2b(y1.w);
        short8 b0 = *(const short8*)&MeT[r * 64 + g * 8];
        short8 b1 = *(const short8*)&MeT[r * 64 + 32 + g * 8];
        f32x4 acc = {};
        acc = __builtin_amdgcn_mfma_f32_16x16x32_bf16(a0, b0, acc, 0, 0, 0);
        acc = __builtin_amdgcn_mfma_f32_16x16x32_bf16(a1, b1, acc, 0, 0, 0);
#pragma unroll
        for (int i = 0; i < 4; ++i) {
            int p = p0 + g * 4 + i;
            if (p < E) {
                if (r < 8) eA1c[(size_t)p * 8 + r] = acc[i];
                else       eA2c[(size_t)p * 8 + (r - 8)] = acc[i];
            }
        }
        return;
    }
    // ---------- GEMM path (BM=64, NR=2) ----------
    int id = blockIdx.x - EAB;
    int bx = id % nbx, by = id / nbx;
    int gm0 = bx * 64, gn0 = by * 128;
    f32x4 acc[4][2] = {};
    int srow = lane >> 3, scol = (lane & 7) * 8;
    int wn = w * 32;
    int fr = lane & 15, fk = (lane >> 4) * 8;

    for (int k0 = 0; k0 < D; k0 += 64) {
        __syncthreads();
#pragma unroll
        for (int i = 0; i < 2; ++i) {
            int rb = w * 16 + i * 8;
            const unsigned short* ga = A + (size_t)(gm0 + rb + srow) * D + k0 + scol;
            __builtin_amdgcn_global_load_lds(
                (const __attribute__((address_space(1))) unsigned int*)ga,
                (__attribute__((address_space(3))) unsigned int*)&As[rb * 64], 16, 0, 0);
        }
#pragma unroll
        for (int i = 0; i < 4; ++i) {
            int rb = w * 32 + i * 8;
            const unsigned short* gb = BT + (size_t)(gn0 + rb + srow) * D + k0 + scol;
            __builtin_amdgcn_global_load_lds(
                (const __attribute__((address_space(1))) unsigned int*)gb,
                (__attribute__((address_space(3))) unsigned int*)&Bs[rb * 64], 16, 0, 0);
        }
        __syncthreads();
#pragma unroll
        for (int kk = 0; kk < 64; kk += 32) {
            short8 a[4], b[2];
#pragma unroll
            for (int m = 0; m < 4; ++m)
                a[m] = *(const short8*)&As[(m * 16 + fr) * 64 + kk + fk];
#pragma unroll
            for (int n = 0; n < 2; ++n)
                b[n] = *(const short8*)&Bs[(wn + n * 16 + fr) * 64 + kk + fk];
#pragma unroll
            for (int m = 0; m < 4; ++m)
#pragma unroll
                for (int n = 0; n < 2; ++n)
                    acc[m][n] = __builtin_amdgcn_mfma_f32_16x16x32_bf16(a[m], b[n], acc[m][n], 0, 0, 0);
        }
    }
    int fcol = lane & 15, frow4 = (lane >> 4) * 4;
#pragma unroll
    for (int m = 0; m < 4; ++m) {
#pragma unroll
        for (int i = 0; i < 4; ++i) {
            int gr = gm0 + m * 16 + frow4 + i;
            if (gr >= M) continue;
#pragma unroll
            for (int n = 0; n < 2; ++n) {
                int gc = gn0 + wn + n * 16 + fcol;
                Cb[(size_t)gr * D + gc] = f2b(acc[m][n][i]);
            }
        }
    }
    {
        int head = (gn0 >> 5) + w;
        float as0 = a_s[head * 32 + fcol], as1 = a_s[head * 32 + 16 + fcol];
        float ad0 = a_d[head * 32 + fcol], ad1 = a_d[head * 32 + 16 + fcol];
#pragma unroll
        for (int m = 0; m < 4; ++m) {
#pragma unroll
            for (int i = 0; i < 4; ++i) {
                float vs = acc[m][0][i] * as0 + acc[m][1][i] * as1;
                float vd = acc[m][0][i] * ad0 + acc[m][1][i] * ad1;
#pragma unroll
                for (int o = 1; o < 16; o <<= 1) {
                    vs += __shfl_xor(vs, o);
                    vd += __shfl_xor(vd, o);
                }
                int r = gm0 + m * 16 + frow4 + i;
                if (fcol == 0 && r < M) {
                    asrcO[r * 8 + head] = vs;
                    adstO[r * 8 + head] = vd;
                }
            }
        }
    }
}

// ---------------- FFN2 + LN + leaky + residual, fully fused ----------------
__global__ __launch_bounds__(256) void ffn2_ln_kernel(
    const unsigned short* __restrict__ A, const unsigned short* __restrict__ BT,
    const float* __restrict__ bias, const float* __restrict__ nf_in,
    const float* __restrict__ gamma, const float* __restrict__ beta,
    float* __restrict__ out, int M) {
    __shared__ unsigned short As[64 * 64];
    __shared__ unsigned short Bs[256 * 64];
    __shared__ float redS1[4][64], redS2[4][64];
    __shared__ float muS[64], invS[64];
    int t = threadIdx.x, lane = t & 63, w = t >> 6;
    int gm0 = blockIdx.x * 64;
    f32x4 acc[4][4] = {};
    int srow = lane >> 3, scol = (lane & 7) * 8;
    int wn = w * 64;
    int fr = lane & 15, fk = (lane >> 4) * 8;
    for (int k0 = 0; k0 < DF; k0 += 64) {
        __syncthreads();
#pragma unroll
        for (int i = 0; i < 2; ++i) {
            int rb = w * 16 + i * 8;
            const unsigned short* ga = A + (size_t)(gm0 + rb + srow) * DF + k0 + scol;
            __builtin_amdgcn_global_load_lds(
                (const __attribute__((address_space(1))) unsigned int*)ga,
                (__attribute__((address_space(3))) unsigned int*)&As[rb * 64], 16, 0, 0);
        }
#pragma unroll
        for (int i = 0; i < 8; ++i) {
            int rb = w * 64 + i * 8;
            const unsigned short* gb = BT + (size_t)(rb + srow) * DF + k0 + scol;
            __builtin_amdgcn_global_load_lds(
                (const __attribute__((address_space(1))) unsigned int*)gb,
                (__attribute__((address_space(3))) unsigned int*)&Bs[rb * 64], 16, 0, 0);
        }
        __syncthreads();
#pragma unroll
        for (int kk = 0; kk < 64; kk += 32) {
            short8 a[4], b[4];
#pragma unroll
            for (int m = 0; m < 4; ++m)
                a[m] = *(const short8*)&As[(m * 16 + fr) * 64 + kk + fk];
#pragma unroll
            for (int n = 0; n < 4; ++n)
                b[n] = *(const short8*)&Bs[(wn + n * 16 + fr) * 64 + kk + fk];
#pragma unroll
            for (int m = 0; m < 4; ++m)
#pragma unroll
                for (int n = 0; n < 4; ++n)
                    acc[m][n] = __builtin_amdgcn_mfma_f32_16x16x32_bf16(a[m], b[n], acc[m][n], 0, 0, 0);
        }
    }
    int fcol = lane & 15, frow4 = (lane >> 4) * 4;
#pragma unroll
    for (int m = 0; m < 4; ++m) {
#pragma unroll
        for (int i = 0; i < 4; ++i) {
            float vs1 = 0.f, vs2 = 0.f;
#pragma unroll
            for (int n = 0; n < 4; ++n) {
                float vv = acc[m][n][i] + bias[wn + n * 16 + fcol];
                acc[m][n][i] = vv;
                vs1 += vv; vs2 += vv * vv;
            }
#pragma unroll
            for (int o = 1; o < 16; o <<= 1) {
                vs1 += __shfl_xor(vs1, o);
                vs2 += __shfl_xor(vs2, o);
            }
            if (fcol == 0) {
                redS1[w][m * 16 + frow4 + i] = vs1;
                redS2[w][m * 16 + frow4 + i] = vs2;
            }
        }
    }
    __syncthreads();
    if (t < 64) {
        float s1 = redS1[0][t] + redS1[1][t] + redS1[2][t] + redS1[3][t];
        float s2 = redS2[0][t] + redS2[1][t] + redS2[2][t] + redS2[3][t];
        float mu = s1 / 256.f;
        float var = fmaxf((s2 - 256.f * mu * mu) / 255.f, 0.f);
        muS[t] = mu;
        invS[t] = 1.f / (sqrtf(var) + 1e-6f);
    }
    __syncthreads();
#pragma unroll
    for (int m = 0; m < 4; ++m) {
#pragma unroll
        for (int i = 0; i < 4; ++i) {
            int r = m * 16 + frow4 + i;
            int gr = gm0 + r;
            if (gr >= M) continue;
            float mu = muS[r], inv = invS[r];
#pragma unroll
            for (int n = 0; n < 4; ++n) {
                int gc = wn + n * 16 + fcol;
                float y = gamma[gc] * (acc[m][n][i] - mu) * inv + beta[gc];
                y = y > 0.f ? y : 0.01f * y;
                out[(size_t)gr * D + gc] = nf_in[(size_t)gr * D + gc] + y;
            }
        }
    }
}

// ---------------- GAT: wave-per-node, 3-gen pipelined gather + fused LN ----------------
__global__ __launch_bounds__(256) void gat_node_kernel(
    const int* __restrict__ off, const int* __restrict__ src_csr,
    const float* __restrict__ eAc,
    const float* __restrict__ asrc, const float* __restrict__ adst,
    const unsigned short* __restrict__ xsb, const float* __restrict__ nf_in,
    const float* __restrict__ bias, const float* __restrict__ gamma,
    const float* __restrict__ beta, float* __restrict__ nf_out,
    unsigned short* __restrict__ nf_out_b, int N) {
    int lane = threadIdx.x & 63;
    int n = blockIdx.x * 4 + (threadIdx.x >> 6);
    if (n >= N) return;
    int e0 = off[n], e1 = off[n + 1], deg = e1 - e0;
    int h = lane & 7;
    int hw = lane >> 3;

    float adstn = adst[n * 8 + h];
    float asn = asrc[n * 8 + h];

    float acc0 = 0.f, acc1 = 0.f, acc2 = 0.f, acc3 = 0.f;
    float den0 = 0.f, easum = 0.f;
    int nb8 = (deg + 7) >> 3;

#define LOAD_SE(b, S, EA, A) { A = ((b) * 8 + hw) < deg; int sp_ = e0 + (b) * 8 + hw; \
    S = A ? src_csr[sp_] : n; EA = A ? eAc[(size_t)sp_ * 8 + h] : 0.f; }

    if (nb8 > 0) {
        int s0, s1, s2; float ea0, ea1, ea2; bool a0, a1, a2;
        LOAD_SE(0, s0, ea0, a0);
        LOAD_SE(1, s1, ea1, a1);
        LOAD_SE(2, s2, ea2, a2);
        float as0 = a0 ? asrc[s0 * 8 + h] : 0.f;
        float as1 = a1 ? asrc[s1 * 8 + h] : 0.f;
        ushort4 uA[8], uB[8];
#pragma unroll
        for (int kk = 0; kk < 8; ++kk) {
            int sk = __shfl(s0, kk * 8 + hw);
            uA[kk] = *(const ushort4*)&xsb[(size_t)sk * D + lane * 4];
        }
        int it = 0;
        while (true) {
            // ==== sub-iter A: compute batch it from uA; rows it+1 -> uB ====
            if (it + 1 < nb8) {
#pragma unroll
                for (int kk = 0; kk < 8; ++kk) {
                    int sk = __shfl(s1, kk * 8 + hw);
                    uB[kk] = *(const ushort4*)&xsb[(size_t)sk * D + lane * 4];
                }
            }
            {
                float as2 = a2 ? asrc[s2 * 8 + h] : 0.f;
                int s3; float ea3; bool a3;
                LOAD_SE(it + 3, s3, ea3, a3);
                float al = as0 + adstn + ea0;
                al = al > 0.f ? al : 0.2f * al;
                float ex = a0 ? expf(al) : 0.f;
                den0 += ex; easum += ea0;
#pragma unroll
                for (int kk = 0; kk < 8; ++kk) {
                    float exk = __shfl(ex, kk * 8 + hw);
                    acc0 = fmaf(exk, b2f(uA[kk].x), acc0);
                    acc1 = fmaf(exk, b2f(uA[kk].y), acc1);
                    acc2 = fmaf(exk, b2f(uA[kk].z), acc2);
                    acc3 = fmaf(exk, b2f(uA[kk].w), acc3);
                }
                s0 = s1; ea0 = ea1; as0 = as1; a0 = a1;
                s1 = s2; ea1 = ea2; as1 = as2; a1 = a2;
                s2 = s3; ea2 = ea3; a2 = a3;
            }
            if (++it >= nb8) break;
            // ==== sub-iter B: compute batch it from uB; rows it+1 -> uA ====
            if (it + 1 < nb8) {
#pragma unroll
                for (int kk = 0; kk < 8; ++kk) {
                    int sk = __shfl(s1, kk * 8 + hw);
                    uA[kk] = *(const ushort4*)&xsb[(size_t)sk * D + lane * 4];
                }
            }
            {
                float as2 = a2 ? asrc[s2 * 8 + h] : 0.f;
                int s3; float ea3; bool a3;
                LOAD_SE(it + 3, s3, ea3, a3);
                float al = as0 + adstn + ea0;
                al = al > 0.f ? al : 0.2f * al;
                float ex = a0 ? expf(al) : 0.f;
                den0 += ex; easum += ea0;
#pragma unroll
                for (int kk = 0; kk < 8; ++kk) {
                    float exk = __shfl(ex, kk * 8 + hw);
                    acc0 = fmaf(exk, b2f(uB[kk].x), acc0);
                    acc1 = fmaf(exk, b2f(uB[kk].y), acc1);
                    acc2 = fmaf(exk, b2f(uB[kk].z), acc2);
                    acc3 = fmaf(exk, b2f(uB[kk].w), acc3);
                }
                s0 = s1; ea0 = ea1; as0 = as1; a0 = a1;
                s1 = s2; ea1 = ea2; as1 = as2; a1 = a2;
                s2 = s3; ea2 = ea3; a2 = a3;
            }
            if (++it >= nb8) break;
        }
    }
#undef LOAD_SE
    den0  += __shfl_xor(den0, 8);
    den0  += __shfl_xor(den0, 16);
    den0  += __shfl_xor(den0, 32);
    easum += __shfl_xor(easum, 8);
    easum += __shfl_xor(easum, 16);
    easum += __shfl_xor(easum, 32);
    float sa = easum / (float)(deg > 0 ? deg : 1);
    float als = asn + adstn + sa;
    als = als > 0.f ? als : 0.2f * als;
    float exSelf = expf(als);
    {
        float exs = __shfl(exSelf, hw);
        ushort4 u = *(const ushort4*)&xsb[(size_t)n * D + lane * 4];
        acc0 = fmaf(exs, b2f(u.x), acc0);
        acc1 = fmaf(exs, b2f(u.y), acc1);
        acc2 = fmaf(exs, b2f(u.z), acc2);
        acc3 = fmaf(exs, b2f(u.w), acc3);
    }
    den0 += exSelf;
    float denOwn = __shfl(den0, hw);
    float inv = 1.f / (denOwn + 1e-16f);

    int t0 = lane * 4;
    float4 bi = *(const float4*)&bias[t0];
    float o0 = acc0 * inv + bi.x;
    float o1 = acc1 * inv + bi.y;
    float o2 = acc2 * inv + bi.z;
    float o3 = acc3 * inv + bi.w;

    float s1r = o0 + o1 + o2 + o3;
    float s2r = o0 * o0 + o1 * o1 + o2 * o2 + o3 * o3;
    for (int o = 1; o < 64; o <<= 1) { s1r += __shfl_xor(s1r, o); s2r += __shfl_xor(s2r, o); }
    float mu = s1r / 256.f;
    float var = fmaxf((s2r - 256.f * mu * mu) / 255.f, 0.f);
    float sdv = sqrtf(var) + 1e-6f;
    float4 ga = *(const float4*)&gamma[t0];
    float4 be = *(const float4*)&beta[t0];
    float4 nin = *(const float4*)&nf_in[(size_t)n * D + t0];
    float y0 = ga.x * (o0 - mu) / sdv + be.x; y0 = y0 > 0.f ? y0 : 0.01f * y0;
    float y1 = ga.y * (o1 - mu) / sdv + be.y; y1 = y1 > 0.f ? y1 : 0.01f * y1;
    float y2 = ga.z * (o2 - mu) / sdv + be.z; y2 = y2 > 0.f ? y2 : 0.01f * y2;
    float y3 = ga.w * (o3 - mu) / sdv + be.w; y3 = y3 > 0.f ? y3 : 0.01f * y3;
    float r0 = nin.x + y0, r1 = nin.y + y1, r2 = nin.z + y2, r3 = nin.w + y3;
    float4 outv; outv.x = r0; outv.y = r1; outv.z = r2; outv.w = r3;
    *(float4*)&nf_out[(size_t)n * D + t0] = outv;
    ushort4 ob; ob.x = f2b(r0); ob.y = f2b(r1); ob.z = f2b(r2); ob.w = f2b(r3);
    *(ushort4*)&nf_out_b[(size_t)n * D + t0] = ob;
}

extern "C" void kernel_launch(void* const* d_in, const int* in_sizes, int n_in,
                              void* d_out, int out_size, void* d_ws, size_t ws_size,
                              hipStream_t stream) {
    const float* nf0    = (const float*)d_in[0];
    const int*   ei     = (const int*)d_in[1];
    const float* ew     = (const float*)d_in[2];
    const float* lin1   = (const float*)d_in[3];
    const float* le1    = (const float*)d_in[4];
    const float* asrc1w = (const float*)d_in[5];
    const float* adst1w = (const float*)d_in[6];
    const float* aedge1 = (const float*)d_in[7];
    const float* b1     = (const float*)d_in[8];
    const float* lin2   = (const float*)d_in[9];
    const float* le2    = (const float*)d_in[10];
    const float* asrc2w = (const float*)d_in[11];
    const float* adst2w = (const float*)d_in[12];
    const float* aedge2 = (const float*)d_in[13];
    const float* b2     = (const float*)d_in[14];
    const float* g1     = (const float*)d_in[15];
    const float* be1    = (const float*)d_in[16];
    const float* g2     = (const float*)d_in[17];
    const float* be2    = (const float*)d_in[18];
    const float* g3     = (const float*)d_in[19];
    const float* be3    = (const float*)d_in[20];
    const float* w1     = (const float*)d_in[21];
    const float* fb1    = (const float*)d_in[22];
    const float* w2     = (const float*)d_in[23];
    const float* fb2    = (const float*)d_in[24];

    const int N = in_sizes[0] / D;
    const int E = in_sizes[1] / 2;
    const int Mpad = ((N + 127) / 128) * 128;
    const int* srcI = ei;
    const int* dstI = ei + E;

    char* ws = (char*)d_ws;
    size_t ob = 0;
    auto alloc = [&](size_t bytes) { void* p = ws + ob; ob = align_up(ob + bytes, 256); return p; };
    // --- arena0: dead after GAT layer 2; start reused as FFN hidden (bf16, Mpad*DF*2 = 20.7MB) ---
    int*   deg     = (int*)alloc((size_t)N * 4);
    int*   csr_off = (int*)alloc((size_t)(N + 1) * 4);
    int*   cursor  = (int*)alloc((size_t)N * 4);
    int*   part    = (int*)alloc(1024);
    int*   eid     = (int*)alloc((size_t)E * 4);
    int*   src_csr = (int*)alloc((size_t)E * 4);
    unsigned short* MeT = (unsigned short*)alloc(16 * 64 * 2);
    float* asrcB   = (float*)alloc((size_t)N * H * 4);
    float* adstB   = (float*)alloc((size_t)N * H * 4);
    float* eA1c    = (float*)alloc((size_t)E * H * 4);
    float* eA2c    = (float*)alloc((size_t)E * H * 4);
    // --- persistent ---
    float* nfw     = (float*)alloc((size_t)N * D * 4);
    unsigned short* xs_b  = (unsigned short*)alloc((size_t)Mpad * D * 2);
    unsigned short* Abf   = (unsigned short*)alloc((size_t)Mpad * D * 2);
    unsigned short* lin1T = (unsigned short*)alloc((size_t)D * D * 2);
    unsigned short* lin2T = (unsigned short*)alloc((size_t)D * D * 2);
    unsigned short* w1T   = (unsigned short*)alloc((size_t)DF * D * 2);
    unsigned short* w2T   = (unsigned short*)alloc((size_t)D * DF * 2);
    unsigned short* hidden = (unsigned short*)ws;  // aliases arena0 (dead by FFN)
    (void)ws_size;
    float* out = (float*)d_out;

    hipMemsetAsync(deg, 0, (size_t)N * 4, stream);

    int eb = (E + 255) / 256;
    int nb = (N + 255) / 256;
    const size_t nvalid = (size_t)N * D, ntot = (size_t)Mpad * D;
    int cb = (int)((ntot / 8 + 255) / 256);

    // prep (transposes + MeT + convert) + deg count, one dispatch
    prep_deg_kernel<<<641 + cb + eb, 256, 0, stream>>>(
        lin1, lin2, w1, w2, le1, aedge1, le2, aedge2, nf0, dstI,
        lin1T, lin2T, w1T, w2T, MeT, Abf, deg, nvalid, ntot, cb, E);
    partial_sum_kernel<<<nb, 256, 0, stream>>>(deg, part, N);
    scan_final_kernel<<<nb, 256, 0, stream>>>(deg, part, csr_off, cursor, N);
    fill_kernel<<<eb, 256, 0, stream>>>(srcI, dstI, cursor, eid, src_csr, E);

    int EAB = (E + 63) / 64;
    int nbx = Mpad / 64;
    int gatb = (N + 3) / 4;

    // ---- ealpha + GAT-1 xs-GEMM fused in one dispatch ----
    fused_ea_gemm1_kernel<<<EAB + nbx * 2, 256, 0, stream>>>(
        ew, eid, MeT, eA1c, eA2c, E, EAB,
        Abf, lin1T, xs_b, N, nbx, asrc1w, adst1w, asrcB, adstB);
    gat_node_kernel<<<gatb, 256, 0, stream>>>(csr_off, src_csr, eA1c, asrcB, adstB,
                                              xs_b, nf0, b1, g1, be1, nfw, Abf, N);
    // ---- GAT layer 2 ----
    mfma_gemm_kernel<64><<<dim3(nbx, 2), 256, 0, stream>>>(
        Abf, lin2T, nullptr, nullptr, xs_b, N, D, D, 0, asrc2w, adst2w, asrcB, adstB);
    gat_node_kernel<<<gatb, 256, 0, stream>>>(csr_off, src_csr, eA2c, asrcB, adstB,
                                              xs_b, nfw, b2, g2, be2, nfw, Abf, N);
    // ---- FFN: hidden = relu(Abf@w1+fb1) for ALL Mpad rows (pad rows zero -> relu(fb1)) ----
    mfma_gemm_kernel<128><<<dim3(Mpad / 128, 8), 256, 0, stream>>>(
        Abf, w1T, fb1, nullptr, hidden, Mpad, DF, D, 1, nullptr, nullptr, nullptr, nullptr);
    // ---- FFN2 + LN + residual + output, fused ----
    ffn2_ln_kernel<<<(N + 63) / 64, 256, 0, stream>>>(hidden, w2T, fb2, nfw, g3, be3, out, N);
}